// Round 3
// baseline (1009.147 us; speedup 1.0000x reference)
//
#include <hip/hip_runtime.h>
#include <hip/hip_bf16.h>
#include <math.h>

using bf16 = __hip_bfloat16;
#define DI __device__ __forceinline__

namespace {
constexpr int B = 8, C = 48, H = 128, W = 128;
constexpr int HW = H * W;                 // 16384
constexpr int NCHW = B * C * HW;          // 6,291,456
constexpr int C2 = 96;
constexpr int WF = 65;                    // rfft width
constexpr int SPECHW = H * WF;            // 8320 (divisible by 64)
constexpr int SPECN = B * C2 * SPECHW;    // 6,389,760 floats
// spec (fp32) overlays the T+Q+K bf16 region = 3*NCHW bf16 slots
static_assert((size_t)SPECN * 4 <= (size_t)3 * NCHW * 2, "spec must fit in T+Q+K overlay");
static_assert(SPECHW % 64 == 0, "freq_gate 64-pixel blocks must not straddle batches");

// fp32 param header offsets (in floats), base = ws + 8192
constexpr int O_FDW = 0,    O_BNG = 3456, O_BNB = 3528, O_BNM = 3600, O_BNV = 3672;
constexpr int O_FHW1 = 3744, O_FHB1 = 3888, O_FHW2 = 3936, O_FHB2 = 3984;
constexpr int O_FLW = 4032,  O_FLB = 13248;
constexpr int O_HQW = 13344, O_HKVW = 15648, O_HQDW = 20256, O_HKVDW = 20688, O_HPW = 21552, O_HT = 23856;
constexpr int O_LQW = 23860, O_LKVW = 26164, O_LQDW = 30772, O_LKVDW = 31204, O_LPW = 32068, O_LT = 34372;
constexpr int O_FPW = 34376, O_FPB = 38984;  // end 39032

constexpr int NCHUNK = 64;                // L split for attn gram
}

DI float ldf(const float* p, int i) { return p[i]; }
DI float ldf(const bf16* p, int i) { return __bfloat162float(p[i]); }
DI bf16 tob(float x) { return __float2bfloat16(x); }
DI unsigned short b2u(bf16 v) { union { bf16 b; unsigned short u; } x; x.b = v; return x.u; }
DI float u2f(unsigned short u) { return __uint_as_float((unsigned)u << 16); }
DI float ldx(const void* p, int i, int bf) {
  return bf ? __bfloat162float(((const bf16*)p)[i]) : ((const float*)p)[i];
}
DI float geluf(float x) { return 0.5f * x * (1.f + erff(x * 0.70710678118654752f)); }
DI int refl(int i, int n) { return i < 0 ? -i : (i >= n ? 2 * n - 2 - i : i); }

// ---- dtype detector: bf16 data -> even u16 slots have sane exponents ----
__global__ void detect_k(const void* x, int* flagp) {
  const unsigned short* u = (const unsigned short*)x;
  int t = threadIdx.x;
  int good = 0;
  for (int i = t; i < 1024; i += 256) {
    unsigned short v = u[2 * i];
    int e = (v >> 7) & 0xFF;
    if (e >= 100 && e <= 140) good++;
  }
  __shared__ int cnt;
  if (t == 0) cnt = 0;
  __syncthreads();
  atomicAdd(&cnt, good);
  __syncthreads();
  if (t == 0) flagp[0] = (cnt > 512) ? 1 : 0;
}

// ---- convert all params to fp32 header ----
struct ParamTab { const void* src[25]; int off[25]; int cnt[25]; };
__global__ void cvt_params_k(ParamTab tab, const int* flagp, float* dst) {
  int bf = flagp[0];
  int b = blockIdx.x;
  const void* s = tab.src[b];
  float* d = dst + tab.off[b];
  int n = tab.cnt[b];
  for (int i = threadIdx.x; i < n; i += 256) d[i] = ldx(s, i, bf);
}

// ---- fd: channel means ----
__global__ void reduce_mean_k(const void* __restrict__ x, float* __restrict__ ap,
                              const int* flagp) {
  int bf = flagp[0];
  int bc = blockIdx.x;
  int base = bc * HW;
  float s = 0.f;
  for (int i = threadIdx.x; i < HW; i += 256) s += ldx(x, base + i, bf);
  #pragma unroll
  for (int o = 32; o > 0; o >>= 1) s += __shfl_down(s, o);
  __shared__ float r[4];
  if ((threadIdx.x & 63) == 0) r[threadIdx.x >> 6] = s;
  __syncthreads();
  if (threadIdx.x == 0) ap[bc] = (r[0] + r[1] + r[2] + r[3]) * (1.f / HW);
}

// ---- fd: 72-wide linear + BN + per-group softmax over 9 ----
__global__ void fd_weights_k(const float* __restrict__ ap, const float* __restrict__ P,
                             float* __restrict__ wts) {
  int n = blockIdx.x, t = threadIdx.x;
  __shared__ float vals[72], es[72];
  if (t < 72) {
    float acc = 0.f;
    for (int c = 0; c < C; c++) acc += P[O_FDW + t * C + c] * ap[n * C + c];
    acc = (acc - P[O_BNM + t]) * rsqrtf(P[O_BNV + t] + 1e-5f);
    vals[t] = acc * P[O_BNG + t] + P[O_BNB + t];
  }
  __syncthreads();
  if (t < 72) {
    int base = (t / 9) * 9;
    float mx = -1e30f;
    for (int k = 0; k < 9; k++) mx = fmaxf(mx, vals[base + k]);
    es[t] = expf(vals[t] - mx);
  }
  __syncthreads();
  if (t < 72) {
    int base = (t / 9) * 9;
    float s = 0.f;
    for (int k = 0; k < 9; k++) s += es[base + k];
    wts[n * 72 + t] = es[t] / s;
  }
}

// ---- fd: involution low-pass (reflect pad), low + high ----
__global__ void fd_apply_k(const void* __restrict__ x, const float* __restrict__ wts,
                           bf16* __restrict__ low, bf16* __restrict__ high,
                           const int* flagp) {
  int bf = flagp[0];
  int idx = blockIdx.x * 256 + threadIdx.x;
  int w = idx & (W - 1);
  int h = (idx >> 7) & (H - 1);
  int c = (idx / HW) % C;
  int b = idx / (C * HW);
  const float* wt = wts + b * 72 + (c / 6) * 9;
  int xbase = (b * C + c) * HW;
  float acc = 0.f, ctr = 0.f;
  #pragma unroll
  for (int i = 0; i < 3; i++) {
    int hh = refl(h + i - 1, H);
    #pragma unroll
    for (int j = 0; j < 3; j++) {
      int ww = refl(w + j - 1, W);
      float v = ldx(x, xbase + hh * W + ww, bf);
      if (i == 1 && j == 1) ctr = v;
      acc += wt[i * 3 + j] * v;
    }
  }
  low[idx] = tob(acc);
  high[idx] = tob(ctr - acc);
}

// ---- fmgm_high: fused (1x3)->(3x1) dwconv (zero pad, biases) -> gelu * x ----
__global__ void fmgm_high_k(const bf16* __restrict__ hi, const float* __restrict__ P,
                            bf16* __restrict__ out) {
  int idx = blockIdx.x * 256 + threadIdx.x;
  int w = idx & (W - 1);
  int h = (idx >> 7) & (H - 1);
  int c = (idx / HW) % C;
  const bf16* p = hi + (idx - (h * W + w));
  float k1[3], k2[3];
  #pragma unroll
  for (int j = 0; j < 3; j++) { k1[j] = P[O_FHW1 + c * 3 + j]; k2[j] = P[O_FHW2 + c * 3 + j]; }
  float bb1 = P[O_FHB1 + c];
  float acc = P[O_FHB2 + c];
  #pragma unroll
  for (int i = 0; i < 3; i++) {
    int hh = h + i - 1;
    if (hh < 0 || hh >= H) continue;
    float y1 = bb1;
    #pragma unroll
    for (int j = 0; j < 3; j++) {
      int ww = w + j - 1;
      if (ww >= 0 && ww < W) y1 += k1[j] * ldf(p, hh * W + ww);
    }
    acc += k2[i] * y1;
  }
  out[idx] = tob(geluf(acc) * ldf(p, h * W + w));
}

// ---- rfft along W, v3: lane-parallel radix-2 FFT64 (shuffle butterflies) ----
// pack: z[l] = x[2l] + i x[2l+1]; 6-stage DIF -> Z[bitrev(l)] at lane l;
// Hermitian unpack via 2 dynamic shuffles -> X[l] (and X[64] from lane 0).
__global__ void __launch_bounds__(256) rfft_row_k(const bf16* __restrict__ low,
                                                  float* __restrict__ spec) {
  int t = threadIdx.x;
  int wid = t >> 6, l = t & 63;
  int row = blockIdx.x * 4 + wid;        // in [0, B*C*H)
  int h = row & (H - 1);
  int bc = row >> 7;
  int c = bc % C, b = bc / C;
  const unsigned* xr = (const unsigned*)(low + (size_t)row * W);
  unsigned v2 = xr[l];                   // two bf16: elems 2l, 2l+1
  float zr = __uint_as_float(v2 << 16);
  float zi = __uint_as_float(v2 & 0xFFFF0000u);
  // forward DIF FFT64 across lanes, twiddles e^{-i pi n / d}
  #pragma unroll
  for (int s = 0; s < 6; s++) {
    int d = 32 >> s;
    float pr = __shfl_xor(zr, d);
    float pi = __shfl_xor(zi, d);
    float a = (float)(l & (d - 1)) / (float)d;
    float wr = cospif(a), wi = -sinpif(a);
    float sr = zr + pr, si = zi + pi;
    float dr = pr - zr, di = pi - zi;
    float mr2 = dr * wr - di * wi;
    float mi2 = dr * wi + di * wr;
    bool hib = (l & d) != 0;
    zr = hib ? mr2 : sr;
    zi = hib ? mi2 : si;
  }
  // gather Z[l] (at lane bitrev(l)) and Z[(64-l)&63]
  int rl = __brev(l) >> 26;
  int lm = (64 - l) & 63;
  int rm = __brev(lm) >> 26;
  float Zkr = __shfl(zr, rl), Zki = __shfl(zi, rl);
  float Zmr = __shfl(zr, rm), Zmi = __shfl(zi, rm);
  float Fer = 0.5f * (Zkr + Zmr), Fei = 0.5f * (Zki - Zmi);
  float Dr  = 0.5f * (Zkr - Zmr), Di  = 0.5f * (Zki + Zmi);
  float For = Di, Foi = -Dr;             // D / i
  float a = (float)l * (1.f / 64.f);
  float tr = cospif(a), ti = -sinpif(a); // e^{-2 pi i l / 128}
  float Xr = Fer + tr * For - ti * Foi;
  float Xi = Fei + tr * Foi + ti * For;
  size_t o = ((size_t)(b * C2 + c) * H + h) * WF + l;
  size_t ioff = (size_t)C * H * WF;
  spec[o] = Xr;
  spec[o + ioff] = Xi;
  if (l == 0) {                          // k = 64 (Nyquist): Fe0 - Fo0 = se - so
    spec[o + 64] = Fer - For;
    spec[o + 64 + ioff] = 0.f;
  }
}

// ---- complex FFT-128 along H, v6: lane-parallel radix-2, LDS tile ----
// grid = B*C*2; half 0 owns kx[0,32), half 1 owns kx[32,65]. 256 thr = 4 waves.
// Each wave FFTs whole columns: lane l holds rows l, l+64 (2 complex values).
// Stage A (dist-64 butterfly) in-lane -> two FFT64 across lanes (shfl_xor).
// Lane l ends with X[2*br6(l)], X[2*br6(l)+1]; in-place LDS write (columns
// are wave-disjoint), then coalesced store.
__global__ void __launch_bounds__(256) fft_col_k(float* __restrict__ spec,
                                                 float sgn, float scale) {
  __shared__ float re_s[128 * 33], im_s[128 * 33];   // 33.8 KB, stride 33
  int t = threadIdx.x;
  int half = blockIdx.x & 1;
  int bc = blockIdx.x >> 1;
  int cc = bc % C, b = bc / C;
  size_t reb = ((size_t)(b * C2 + cc) * H) * WF;
  size_t imb = reb + (size_t)C * H * WF;
  int ncol = half ? 33 : 32;
  if (half == 0) {
    #pragma unroll
    for (int i = 0; i < 16; i++) {
      int idx = i * 256 + t;             // 4096 = 128*32
      int r = idx >> 5, c = idx & 31;
      re_s[r * 33 + c] = spec[reb + r * WF + c];
      im_s[r * 33 + c] = spec[imb + r * WF + c];
    }
  } else {
    #pragma unroll
    for (int i = 0; i < 17; i++) {
      int idx = i * 256 + t;             // 4352 >= 128*33
      if (idx < 128 * 33) {
        int r = idx / 33, c = idx - r * 33;
        re_s[r * 33 + c] = spec[reb + r * WF + 32 + c];
        im_s[r * 33 + c] = spec[imb + r * WF + 32 + c];
      }
    }
  }
  __syncthreads();
  int w = t >> 6, l = t & 63;
  // twiddles depend only on (lane, stage): hoist out of the column loop
  float cA = cospif((float)l * (1.f / 64.f));
  float sA = sinpif((float)l * (1.f / 64.f)) * sgn;  // e^{sgn*2pi i l/128}
  float cs[6], ss[6];
  #pragma unroll
  for (int s = 0; s < 6; s++) {
    int d = 32 >> s;
    float a = (float)(l & (d - 1)) / (float)d;
    cs[s] = cospif(a); ss[s] = sinpif(a) * sgn;
  }
  int br = __brev(l) >> 26;
  for (int c = w; c < ncol; c += 4) {
    float ar = re_s[l * 33 + c],         ai = im_s[l * 33 + c];
    float xr = re_s[(l + 64) * 33 + c],  xi = im_s[(l + 64) * 33 + c];
    // stage A: distance-64 butterfly, in-lane
    float ur = ar + xr, ui = ai + xi;                // -> even freqs
    float tr = ar - xr, ti = ai - xi;
    float vr = tr * cA - ti * sA;                    // -> odd freqs
    float vi = tr * sA + ti * cA;
    // two FFT64 across lanes (DIF, shuffle butterflies)
    #pragma unroll
    for (int s = 0; s < 6; s++) {
      int d = 32 >> s;
      float pr = __shfl_xor(ur, d), pi = __shfl_xor(ui, d);
      float qr = __shfl_xor(vr, d), qi = __shfl_xor(vi, d);
      float sur = ur + pr, sui = ui + pi;
      float dur = pr - ur, dui = pi - ui;
      float svr = vr + qr, svi = vi + qi;
      float dvr = qr - vr, dvi = qi - vi;
      float mur = dur * cs[s] - dui * ss[s];
      float mui = dur * ss[s] + dui * cs[s];
      float mvr = dvr * cs[s] - dvi * ss[s];
      float mvi = dvr * ss[s] + dvi * cs[s];
      bool hib = (l & d) != 0;
      ur = hib ? mur : sur; ui = hib ? mui : sui;
      vr = hib ? mvr : svr; vi = hib ? mvi : svi;
    }
    int r0 = 2 * br;                     // X[2*br] = U-res, X[2*br+1] = V-res
    re_s[r0 * 33 + c] = ur * scale;       im_s[r0 * 33 + c] = ui * scale;
    re_s[(r0 + 1) * 33 + c] = vr * scale; im_s[(r0 + 1) * 33 + c] = vi * scale;
  }
  __syncthreads();
  if (half == 0) {
    #pragma unroll
    for (int i = 0; i < 16; i++) {
      int idx = i * 256 + t;
      int r = idx >> 5, c = idx & 31;
      spec[reb + r * WF + c] = re_s[r * 33 + c];
      spec[imb + r * WF + c] = im_s[r * 33 + c];
    }
  } else {
    #pragma unroll
    for (int i = 0; i < 17; i++) {
      int idx = i * 256 + t;
      if (idx < 128 * 33) {
        int r = idx / 33, c = idx - r * 33;
        spec[reb + r * WF + 32 + c] = re_s[r * 33 + c];
        spec[imb + r * WF + 32 + c] = im_s[r * 33 + c];
      }
    }
  }
}

// ---- freq-domain channel-mix gate v3: thread-per-pixel, X in regs, no LDS ----
// yf *= gelu(W yf + b). Block = 128 thr = 2 waves sharing 64 pixels:
// wave 0 computes outs 0..47, wave 1 outs 48..95. Weight rows are contiguous
// 96-float s_load streams (j-outer). In-place safe: barrier between the
// all-channels load phase and first store; each thread is the sole writer of
// its own (pixel, out-channel) slots; gate multiplicand re-read from global
// (L1-hot, still original) to keep register-array indices compile-time.
__global__ void __launch_bounds__(128) freq_gate_k(float* __restrict__ spec,
                                                   const float* __restrict__ P) {
  int t = threadIdx.x;
  int l = t & 63;
  int wid = __builtin_amdgcn_readfirstlane(t >> 6);  // 0 or 1, wave-uniform
  int gp = blockIdx.x * 64 + l;          // pixel-column in [0, B*SPECHW)
  int b = gp / SPECHW;
  int off = gp - b * SPECHW;
  float* base = spec + (size_t)b * C2 * SPECHW + off;
  float x[96];
  #pragma unroll
  for (int c = 0; c < 96; c++) x[c] = base[(size_t)c * SPECHW];
  __syncthreads();                       // all loads complete before any store
  const float* wr = P + O_FLW + wid * 48 * 96;
  const float* bb = P + O_FLB + wid * 48;
  float* ob = base + (size_t)(wid * 48) * SPECHW;
  #pragma unroll 2
  for (int j = 0; j < 48; j++) {
    const float* wj = wr + j * 96;
    float a0 = 0.f, a1 = 0.f, a2 = 0.f, a3 = 0.f;
    #pragma unroll
    for (int c = 0; c < 96; c += 4) {
      a0 += wj[c]     * x[c];
      a1 += wj[c + 1] * x[c + 1];
      a2 += wj[c + 2] * x[c + 2];
      a3 += wj[c + 3] * x[c + 3];
    }
    float g = geluf(a0 + a1 + a2 + a3 + bb[j]);
    float xo = ob[(size_t)j * SPECHW];   // original value (sole writer is us)
    ob[(size_t)j * SPECHW] = xo * g;
  }
}

// ---- irfft along W, v3: Hermitian pack + lane-parallel inverse FFT64 ----
// Z[k] = Fe[k] + i Fo[k]; u = IFFT64(Z) unnormalized -> lane l holds u[bitrev(l)];
// y[2m] = Re u[m]/64, y[2m+1] = Im u[m]/64 (1/128 row norm absorbed).
__global__ void __launch_bounds__(256) irfft_row_k(const float* __restrict__ spec,
                                                   bf16* __restrict__ out) {
  int t = threadIdx.x;
  int wid = t >> 6, l = t & 63;
  int row = blockIdx.x * 4 + wid;        // in [0, B*C*H)
  int h = row & (H - 1);
  int bc = row >> 7;
  int c = bc % C, b = bc / C;
  size_t rb = ((size_t)(b * C2 + c) * H + h) * WF;
  size_t ioff = (size_t)C * H * WF;
  float xr = spec[rb + l];
  float xi = (l == 0) ? 0.f : spec[rb + ioff + l];   // C2R: ignore DC imag
  float r64 = spec[rb + 64];                         // Nyquist (real used only)
  int lm = (64 - l) & 63;
  float mr = __shfl(xr, lm);
  float mi = __shfl(xi, lm);
  if (l == 0) { mr = r64; mi = 0.f; }                // X[64] for the k=0 pair
  float Fer = 0.5f * (xr + mr), Fei = 0.5f * (xi - mi);
  float Dr  = 0.5f * (xr - mr), Di  = 0.5f * (xi + mi);
  float a = (float)l * (1.f / 64.f);
  float tr = cospif(a), ti = sinpif(a);              // e^{+2 pi i l / 128}
  float For = tr * Dr - ti * Di;
  float Foi = tr * Di + ti * Dr;
  float zr = Fer - Foi, zi = Fei + For;              // Z = Fe + i*Fo
  // inverse DIF FFT64 across lanes, twiddles e^{+i pi n / d}
  #pragma unroll
  for (int s = 0; s < 6; s++) {
    int d = 32 >> s;
    float pr = __shfl_xor(zr, d);
    float pi = __shfl_xor(zi, d);
    float aa = (float)(l & (d - 1)) / (float)d;
    float wr = cospif(aa), wi = sinpif(aa);
    float sr = zr + pr, si = zi + pi;
    float dr = pr - zr, di = pi - zi;
    float mr2 = dr * wr - di * wi;
    float mi2 = dr * wi + di * wr;
    bool hib = (l & d) != 0;
    zr = hib ? mr2 : sr;
    zi = hib ? mi2 : si;
  }
  int m = __brev(l) >> 26;               // lane holds u[m]
  unsigned p0 = b2u(tob(zr * (1.f / 64.f)));
  unsigned p1 = b2u(tob(zi * (1.f / 64.f)));
  ((unsigned*)(out + (size_t)row * W))[m] = p0 | (p1 << 16);
}

// ---- 1x1 conv v3: thread-per-pixel, X in regs, contiguous s_load weights ----
// mode 1: input is the external x (flag-dtyped); mode 0: internal bf16
__global__ void __launch_bounds__(128) conv1x1_k(const void* __restrict__ in, bf16* __restrict__ out,
                                                 const float* __restrict__ w,
                                                 const int* flagp, int mode) {
  int bf = mode ? flagp[0] : 1;
  int gp = blockIdx.x * 128 + threadIdx.x;   // pixel in [0, B*HW)
  int b = gp >> 14;                           // HW = 16384
  int p = gp & (HW - 1);
  int ib = b * 48 * HW + p;
  float x[48];
  #pragma unroll
  for (int c = 0; c < 48; c++) x[c] = ldx(in, ib + c * HW, bf);
  bf16* op = out + (size_t)ib;
  #pragma unroll 2
  for (int j = 0; j < 48; j++) {
    const float* wj = w + j * 48;
    float a0 = 0.f, a1 = 0.f, a2 = 0.f, a3 = 0.f;
    #pragma unroll
    for (int c = 0; c < 48; c += 4) {
      a0 += wj[c]     * x[c];
      a1 += wj[c + 1] * x[c + 1];
      a2 += wj[c + 2] * x[c + 2];
      a3 += wj[c + 3] * x[c + 3];
    }
    op[(size_t)j * HW] = tob(a0 + a1 + a2 + a3);
  }
}

// ---- depthwise 3x3 v2: 4 px/thread, vector row loads, zero pad ----
__global__ void dw3x3_k(const bf16* __restrict__ in, bf16* __restrict__ out,
                        const float* __restrict__ w) {
  int idx4 = blockIdx.x * 256 + threadIdx.x;   // pixel-quad index
  int wq = idx4 & 31;                          // W/4 = 32
  int h = (idx4 >> 5) & (H - 1);
  int plane = idx4 >> 12;                      // b*48 + c  (HW/4 = 4096)
  int c = plane % 48;
  const bf16* p = in + (size_t)plane * HW;
  int w0 = wq << 2;
  float acc[4] = {0.f, 0.f, 0.f, 0.f};
  #pragma unroll
  for (int i = 0; i < 3; i++) {
    int hh = h + i - 1;
    if (hh < 0 || hh >= H) continue;
    const bf16* row = p + hh * W + w0;
    ushort4 u = *(const ushort4*)row;          // 8B-aligned (w0 % 4 == 0)
    float v[6];
    v[1] = u2f(u.x); v[2] = u2f(u.y); v[3] = u2f(u.z); v[4] = u2f(u.w);
    v[0] = (w0 > 0) ? ldf(row, -1) : 0.f;
    v[5] = (w0 + 4 < W) ? ldf(row, 4) : 0.f;
    #pragma unroll
    for (int j = 0; j < 3; j++) {
      float wt = w[c * 9 + i * 3 + j];
      #pragma unroll
      for (int q = 0; q < 4; q++) acc[q] += wt * v[q + j];
    }
  }
  ushort4 o;
  o.x = b2u(tob(acc[0])); o.y = b2u(tob(acc[1]));
  o.z = b2u(tob(acc[2])); o.w = b2u(tob(acc[3]));
  *(ushort4*)(out + (size_t)idx4 * 4) = o;
}

// ---- attn gram, split-L partials: grid = 32 bh * NCHUNK blocks ----
__global__ void __launch_bounds__(256) attn_part_k(const bf16* __restrict__ q,
                                                   const bf16* __restrict__ kbuf,
                                                   float* __restrict__ partial) {
  int blk = blockIdx.x;
  int bh = blk >> 6, chunk = blk & (NCHUNK - 1);
  int b = bh >> 2, hd = bh & 3;
  int t = threadIdx.x;
  int l0 = chunk * 256;
  __shared__ float qs[12 * 257], ks[12 * 257];
  const bf16* qb = q + (size_t)(b * 48 + hd * 12) * HW + l0;
  const bf16* kb = kbuf + (size_t)(b * 48 + hd * 12) * HW + l0;
  #pragma unroll
  for (int m = 0; m < 12; m++) {
    qs[m * 257 + t] = ldf(qb, m * HW + t);
    ks[m * 257 + t] = ldf(kb, m * HW + t);
  }
  __syncthreads();
  float acc = 0.f;
  if (t < 144) {
    const float* qr = qs + (t / 12) * 257;
    const float* kr = ks + (t % 12) * 257;
    #pragma unroll 4
    for (int j = 0; j < 256; j++) acc += qr[j] * kr[j];
  } else if (t < 156) {
    const float* qr = qs + (t - 144) * 257;
    #pragma unroll 4
    for (int j = 0; j < 256; j++) acc += qr[j] * qr[j];
  } else if (t < 168) {
    const float* kr = ks + (t - 156) * 257;
    #pragma unroll 4
    for (int j = 0; j < 256; j++) acc += kr[j] * kr[j];
  }
  if (t < 168) partial[(size_t)(chunk * 32 + bh) * 168 + t] = acc;
}

// ---- reduce partials + norms + softmax -> 12x12 attn per bh ----
__global__ void __launch_bounds__(256) attn_fin_k(const float* __restrict__ partial,
                                                  const float* __restrict__ temp,
                                                  float* __restrict__ attn) {
  int bh = blockIdx.x, hd = bh & 3;
  int t = threadIdx.x;
  __shared__ float red[168];
  if (t < 168) {
    float s = 0.f;
    for (int ch = 0; ch < NCHUNK; ch++) s += partial[(size_t)(ch * 32 + bh) * 168 + t];
    red[t] = s;
  }
  __syncthreads();
  if (t < 12) {
    float tm = temp[hd];
    float rq = 1.f / fmaxf(sqrtf(red[144 + t]), 1e-12f);
    float vals[12], mx = -1e30f;
    #pragma unroll
    for (int d = 0; d < 12; d++) {
      float rk = 1.f / fmaxf(sqrtf(red[156 + d]), 1e-12f);
      vals[d] = red[t * 12 + d] * rq * rk * tm;
      mx = fmaxf(mx, vals[d]);
    }
    float s = 0.f;
    #pragma unroll
    for (int d = 0; d < 12; d++) { vals[d] = expf(vals[d] - mx); s += vals[d]; }
    float inv = 1.f / s;
    float* ao = attn + (size_t)(bh * 12 + t) * 12;
    #pragma unroll
    for (int d = 0; d < 12; d++) ao[d] = vals[d] * inv;
  }
}

// ---- out = attn @ v ----
__global__ void attn_apply_k(const float* __restrict__ attn, const bf16* __restrict__ vbuf,
                             bf16* __restrict__ out) {
  int blk = blockIdx.x;
  int bh = blk >> 6, b = bh >> 2, hd = bh & 3;
  int l = ((blk & 63) << 8) + threadIdx.x;
  __shared__ float al[144];
  if (threadIdx.x < 144) al[threadIdx.x] = attn[bh * 144 + threadIdx.x];
  __syncthreads();
  const bf16* vb = vbuf + (size_t)(b * 48 + hd * 12) * HW + l;
  float vv[12];
  #pragma unroll
  for (int d = 0; d < 12; d++) vv[d] = ldf(vb, d * HW);
  bf16* ob = out + (size_t)(b * 48 + hd * 12) * HW + l;
  #pragma unroll
  for (int c = 0; c < 12; c++) {
    float s = 0.f;
    #pragma unroll
    for (int d = 0; d < 12; d++) s += al[c * 12 + d] * vv[d];
    ob[(size_t)c * HW] = tob(s);
  }
}

// ---- final v3: thread-per-pixel, inputs in regs, + bias + residual ----
__global__ void __launch_bounds__(128) conv_final_k(const bf16* __restrict__ ho,
                                                    const bf16* __restrict__ lo,
                                                    const float* __restrict__ P,
                                                    const void* __restrict__ x,
                                                    void* __restrict__ out,
                                                    const int* flagp) {
  int bf = flagp[0];
  int gp = blockIdx.x * 128 + threadIdx.x;   // pixel in [0, B*HW)
  int b = gp >> 14;
  int p = gp & (HW - 1);
  size_t pb = (size_t)b * 48 * HW + p;
  float v[96];
  #pragma unroll
  for (int c = 0; c < 48; c++) {
    v[c]      = ldf(ho, pb + (size_t)c * HW);
    v[48 + c] = ldf(lo, pb + (size_t)c * HW);
  }
  #pragma unroll 2
  for (int j = 0; j < 48; j++) {
    const float* wj = P + O_FPW + j * 96;
    float a0 = 0.f, a1 = 0.f, a2 = 0.f, a3 = 0.f;
    #pragma unroll
    for (int c = 0; c < 96; c += 4) {
      a0 += wj[c]     * v[c];
      a1 += wj[c + 1] * v[c + 1];
      a2 += wj[c + 2] * v[c + 2];
      a3 += wj[c + 3] * v[c + 3];
    }
    size_t oi = pb + (size_t)j * HW;
    float val = a0 + a1 + a2 + a3 + P[O_FPB + j] + ldx(x, (int)oi, bf);
    if (bf) ((bf16*)out)[oi] = tob(val);
    else    ((float*)out)[oi] = val;
  }
}

extern "C" void kernel_launch(void* const* d_in, const int* in_sizes, int n_in,
                              void* d_out, int out_size, void* d_ws, size_t ws_size,
                              hipStream_t stream) {
  const void* x = d_in[0];

  // ws layout (fp32 units): ap@0, wts@512, attnm@2048, flag@7000,
  // params@8192 (ends 47224), partials@49152 (64*32*168 -> ends 393216),
  // bf16 planes @400000
  float* ws    = (float*)d_ws;
  float* ap    = ws;
  float* wts   = ws + 512;
  float* attnm = ws + 2048;
  int*   flagp = (int*)(ws + 7000);
  float* P     = ws + 8192;
  float* parts = ws + 49152;
  bf16* base = (bf16*)(ws + 400000);
  bf16* HF = base;
  bf16* LF = base + (size_t)NCHW;
  bf16* T  = base + (size_t)2 * NCHW;
  bf16* Q  = base + (size_t)3 * NCHW;
  bf16* K  = base + (size_t)4 * NCHW;
  float* spec = (float*)T;

  // ---- dtype detect + param convert ----
  detect_k<<<1, 256, 0, stream>>>(x, flagp);
  ParamTab tab;
  const int offs[25] = {O_FDW, O_BNG, O_BNB, O_BNM, O_BNV,
                        O_FHW1, O_FHB1, O_FHW2, O_FHB2,
                        O_FLW, O_FLB,
                        O_HQW, O_HKVW, O_HQDW, O_HKVDW, O_HPW, O_HT,
                        O_LQW, O_LKVW, O_LQDW, O_LKVDW, O_LPW, O_LT,
                        O_FPW, O_FPB};
  const int cnts[25] = {3456, 72, 72, 72, 72,
                        144, 48, 144, 48,
                        9216, 96,
                        2304, 4608, 432, 864, 2304, 4,
                        2304, 4608, 432, 864, 2304, 4,
                        4608, 48};
  for (int i = 0; i < 25; i++) { tab.src[i] = d_in[i + 1]; tab.off[i] = offs[i]; tab.cnt[i] = cnts[i]; }
  cvt_params_k<<<25, 256, 0, stream>>>(tab, flagp, P);

  // ---- fd ----
  reduce_mean_k<<<B * C, 256, 0, stream>>>(x, ap, flagp);
  fd_weights_k<<<B, 128, 0, stream>>>(ap, P, wts);
  fd_apply_k<<<NCHW / 256, 256, 0, stream>>>(x, wts, LF, Q, flagp);   // low->LF, high->Q
  // ---- fmgm_high ----
  fmgm_high_k<<<NCHW / 256, 256, 0, stream>>>(Q, P, HF);              // hf->HF
  // ---- fmgm_low: rfft2 -> gate -> irfft2 ----
  rfft_row_k<<<B * C * H / 4, 256, 0, stream>>>(LF, spec);
  fft_col_k<<<B * C * 2, 256, 0, stream>>>(spec, -1.f, 1.f);
  freq_gate_k<<<B * (SPECHW / 64), 128, 0, stream>>>(spec, P);
  fft_col_k<<<B * C * 2, 256, 0, stream>>>(spec, 1.f, 1.f / 128.f);
  irfft_row_k<<<B * C * H / 4, 256, 0, stream>>>(spec, LF);           // lf->LF
  // ---- fga (high branch: freq = hf in HF) ----
  conv1x1_k<<<B * HW / 128, 128, 0, stream>>>(HF, T, P + O_HQW, flagp, 0);
  dw3x3_k<<<NCHW / 1024, 256, 0, stream>>>(T, Q, P + O_HQDW);         // q->Q (high dead)
  conv1x1_k<<<B * HW / 128, 128, 0, stream>>>(x, T, P + O_HKVW, flagp, 1);
  dw3x3_k<<<NCHW / 1024, 256, 0, stream>>>(T, K, P + O_HKVDW);        // k->K
  conv1x1_k<<<B * HW / 128, 128, 0, stream>>>(x, T, P + O_HKVW + 48 * 48, flagp, 1);
  dw3x3_k<<<NCHW / 1024, 256, 0, stream>>>(T, HF, P + O_HKVDW + 48 * 9); // v->HF (hf dead)
  attn_part_k<<<32 * NCHUNK, 256, 0, stream>>>(Q, K, parts);
  attn_fin_k<<<32, 256, 0, stream>>>(parts, P + O_HT, attnm);
  attn_apply_k<<<B * 4 * 64, 256, 0, stream>>>(attnm, HF, K);         // attnout->K (k dead)
  conv1x1_k<<<B * HW / 128, 128, 0, stream>>>(K, Q, P + O_HPW, flagp, 0);  // ho->Q (q dead)
  // ---- fga (low branch: freq = lf in LF) ----
  conv1x1_k<<<B * HW / 128, 128, 0, stream>>>(LF, T, P + O_LQW, flagp, 0);
  dw3x3_k<<<NCHW / 1024, 256, 0, stream>>>(T, HF, P + O_LQDW);        // q->HF
  conv1x1_k<<<B * HW / 128, 128, 0, stream>>>(x, T, P + O_LKVW, flagp, 1);
  dw3x3_k<<<NCHW / 1024, 256, 0, stream>>>(T, K, P + O_LKVDW);        // k->K
  conv1x1_k<<<B * HW / 128, 128, 0, stream>>>(x, T, P + O_LKVW + 48 * 48, flagp, 1);
  dw3x3_k<<<NCHW / 1024, 256, 0, stream>>>(T, LF, P + O_LKVDW + 48 * 9); // v->LF (lf dead)
  attn_part_k<<<32 * NCHUNK, 256, 0, stream>>>(HF, K, parts);
  attn_fin_k<<<32, 256, 0, stream>>>(parts, P + O_LT, attnm);
  attn_apply_k<<<B * 4 * 64, 256, 0, stream>>>(attnm, LF, K);         // attnout->K
  conv1x1_k<<<B * HW / 128, 128, 0, stream>>>(K, T, P + O_LPW, flagp, 0);  // lo->T
  // ---- final 1x1 + bias + residual ----
  conv_final_k<<<B * HW / 128, 128, 0, stream>>>(Q, T, P, x, d_out, flagp);
}

// Round 4
// 684.653 us; speedup vs baseline: 1.4740x; 1.4740x over previous
//
#include <hip/hip_runtime.h>
#include <hip/hip_bf16.h>
#include <math.h>

using bf16 = __hip_bfloat16;
#define DI __device__ __forceinline__

namespace {
constexpr int B = 8, C = 48, H = 128, W = 128;
constexpr int HW = H * W;                 // 16384
constexpr int NCHW = B * C * HW;          // 6,291,456
constexpr int C2 = 96;
constexpr int WF = 65;                    // rfft width
constexpr int SPECHW = H * WF;            // 8320 (divisible by 64)
constexpr int SPECN = B * C2 * SPECHW;    // 6,389,760 floats
// spec (fp32) overlays the T+Q+K bf16 region = 3*NCHW bf16 slots
static_assert((size_t)SPECN * 4 <= (size_t)3 * NCHW * 2, "spec must fit in T+Q+K overlay");
static_assert(SPECHW % 64 == 0, "freq_gate 64-pixel blocks must not straddle batches");

// fp32 param header offsets (in floats), base = ws + 8192
// NOTE: matmul weights (FLW, *QW, *KVW, *PW, FPW) are stored TRANSPOSED
// (input-major): wt[c*rows + o]. Depthwise/BN/bias params stay plain.
constexpr int O_FDW = 0,    O_BNG = 3456, O_BNB = 3528, O_BNM = 3600, O_BNV = 3672;
constexpr int O_FHW1 = 3744, O_FHB1 = 3888, O_FHW2 = 3936, O_FHB2 = 3984;
constexpr int O_FLW = 4032,  O_FLB = 13248;
constexpr int O_HQW = 13344, O_HKVW = 15648, O_HQDW = 20256, O_HKVDW = 20688, O_HPW = 21552, O_HT = 23856;
constexpr int O_LQW = 23860, O_LKVW = 26164, O_LQDW = 30772, O_LKVDW = 31204, O_LPW = 32068, O_LT = 34372;
constexpr int O_FPW = 34376, O_FPB = 38984;  // end 39032

constexpr int NCHUNK = 64;                // L split for attn gram
}

DI float ldf(const float* p, int i) { return p[i]; }
DI float ldf(const bf16* p, int i) { return __bfloat162float(p[i]); }
DI bf16 tob(float x) { return __float2bfloat16(x); }
DI unsigned short b2u(bf16 v) { union { bf16 b; unsigned short u; } x; x.b = v; return x.u; }
DI float u2f(unsigned short u) { return __uint_as_float((unsigned)u << 16); }
DI float ldx(const void* p, int i, int bf) {
  return bf ? __bfloat162float(((const bf16*)p)[i]) : ((const float*)p)[i];
}
DI float geluf(float x) { return 0.5f * x * (1.f + erff(x * 0.70710678118654752f)); }
DI int refl(int i, int n) { return i < 0 ? -i : (i >= n ? 2 * n - 2 - i : i); }

// ---- dtype detector: bf16 data -> even u16 slots have sane exponents ----
__global__ void detect_k(const void* x, int* flagp) {
  const unsigned short* u = (const unsigned short*)x;
  int t = threadIdx.x;
  int good = 0;
  for (int i = t; i < 1024; i += 256) {
    unsigned short v = u[2 * i];
    int e = (v >> 7) & 0xFF;
    if (e >= 100 && e <= 140) good++;
  }
  __shared__ int cnt;
  if (t == 0) cnt = 0;
  __syncthreads();
  atomicAdd(&cnt, good);
  __syncthreads();
  if (t == 0) flagp[0] = (cnt > 512) ? 1 : 0;
}

// ---- convert all params to fp32 header; matmul weights transposed ----
// rows[b] == 0: plain copy. rows[b] = R (out-channels of original [R][cols]):
// dst[(i%cols)*R + i/cols] = src[i]  -> input-major wt[c*R + o].
struct ParamTab { const void* src[25]; int off[25]; int cnt[25]; int rows[25]; };
__global__ void cvt_params_k(ParamTab tab, const int* flagp, float* dst) {
  int bf = flagp[0];
  int b = blockIdx.x;
  const void* s = tab.src[b];
  float* d = dst + tab.off[b];
  int n = tab.cnt[b];
  int rows = tab.rows[b];
  if (rows == 0) {
    for (int i = threadIdx.x; i < n; i += 256) d[i] = ldx(s, i, bf);
  } else {
    int cols = n / rows;
    for (int i = threadIdx.x; i < n; i += 256)
      d[(i % cols) * rows + (i / cols)] = ldx(s, i, bf);
  }
}

// ---- fd: channel means ----
__global__ void reduce_mean_k(const void* __restrict__ x, float* __restrict__ ap,
                              const int* flagp) {
  int bf = flagp[0];
  int bc = blockIdx.x;
  int base = bc * HW;
  float s = 0.f;
  for (int i = threadIdx.x; i < HW; i += 256) s += ldx(x, base + i, bf);
  #pragma unroll
  for (int o = 32; o > 0; o >>= 1) s += __shfl_down(s, o);
  __shared__ float r[4];
  if ((threadIdx.x & 63) == 0) r[threadIdx.x >> 6] = s;
  __syncthreads();
  if (threadIdx.x == 0) ap[bc] = (r[0] + r[1] + r[2] + r[3]) * (1.f / HW);
}

// ---- fd: 72-wide linear + BN + per-group softmax over 9 ----
__global__ void fd_weights_k(const float* __restrict__ ap, const float* __restrict__ P,
                             float* __restrict__ wts) {
  int n = blockIdx.x, t = threadIdx.x;
  __shared__ float vals[72], es[72];
  if (t < 72) {
    float acc = 0.f;
    for (int c = 0; c < C; c++) acc += P[O_FDW + t * C + c] * ap[n * C + c];
    acc = (acc - P[O_BNM + t]) * rsqrtf(P[O_BNV + t] + 1e-5f);
    vals[t] = acc * P[O_BNG + t] + P[O_BNB + t];
  }
  __syncthreads();
  if (t < 72) {
    int base = (t / 9) * 9;
    float mx = -1e30f;
    for (int k = 0; k < 9; k++) mx = fmaxf(mx, vals[base + k]);
    es[t] = expf(vals[t] - mx);
  }
  __syncthreads();
  if (t < 72) {
    int base = (t / 9) * 9;
    float s = 0.f;
    for (int k = 0; k < 9; k++) s += es[base + k];
    wts[n * 72 + t] = es[t] / s;
  }
}

// ---- fd: involution low-pass (reflect pad), low + high ----
__global__ void fd_apply_k(const void* __restrict__ x, const float* __restrict__ wts,
                           bf16* __restrict__ low, bf16* __restrict__ high,
                           const int* flagp) {
  int bf = flagp[0];
  int idx = blockIdx.x * 256 + threadIdx.x;
  int w = idx & (W - 1);
  int h = (idx >> 7) & (H - 1);
  int c = (idx / HW) % C;
  int b = idx / (C * HW);
  const float* wt = wts + b * 72 + (c / 6) * 9;
  int xbase = (b * C + c) * HW;
  float acc = 0.f, ctr = 0.f;
  #pragma unroll
  for (int i = 0; i < 3; i++) {
    int hh = refl(h + i - 1, H);
    #pragma unroll
    for (int j = 0; j < 3; j++) {
      int ww = refl(w + j - 1, W);
      float v = ldx(x, xbase + hh * W + ww, bf);
      if (i == 1 && j == 1) ctr = v;
      acc += wt[i * 3 + j] * v;
    }
  }
  low[idx] = tob(acc);
  high[idx] = tob(ctr - acc);
}

// ---- fmgm_high: fused (1x3)->(3x1) dwconv (zero pad, biases) -> gelu * x ----
__global__ void fmgm_high_k(const bf16* __restrict__ hi, const float* __restrict__ P,
                            bf16* __restrict__ out) {
  int idx = blockIdx.x * 256 + threadIdx.x;
  int w = idx & (W - 1);
  int h = (idx >> 7) & (H - 1);
  int c = (idx / HW) % C;
  const bf16* p = hi + (idx - (h * W + w));
  float k1[3], k2[3];
  #pragma unroll
  for (int j = 0; j < 3; j++) { k1[j] = P[O_FHW1 + c * 3 + j]; k2[j] = P[O_FHW2 + c * 3 + j]; }
  float bb1 = P[O_FHB1 + c];
  float acc = P[O_FHB2 + c];
  #pragma unroll
  for (int i = 0; i < 3; i++) {
    int hh = h + i - 1;
    if (hh < 0 || hh >= H) continue;
    float y1 = bb1;
    #pragma unroll
    for (int j = 0; j < 3; j++) {
      int ww = w + j - 1;
      if (ww >= 0 && ww < W) y1 += k1[j] * ldf(p, hh * W + ww);
    }
    acc += k2[i] * y1;
  }
  out[idx] = tob(geluf(acc) * ldf(p, h * W + w));
}

// ---- rfft along W, v3: lane-parallel radix-2 FFT64 (shuffle butterflies) ----
// pack: z[l] = x[2l] + i x[2l+1]; 6-stage DIF -> Z[bitrev(l)] at lane l;
// Hermitian unpack via 2 dynamic shuffles -> X[l] (and X[64] from lane 0).
__global__ void __launch_bounds__(256) rfft_row_k(const bf16* __restrict__ low,
                                                  float* __restrict__ spec) {
  int t = threadIdx.x;
  int wid = t >> 6, l = t & 63;
  int row = blockIdx.x * 4 + wid;        // in [0, B*C*H)
  int h = row & (H - 1);
  int bc = row >> 7;
  int c = bc % C, b = bc / C;
  const unsigned* xr = (const unsigned*)(low + (size_t)row * W);
  unsigned v2 = xr[l];                   // two bf16: elems 2l, 2l+1
  float zr = __uint_as_float(v2 << 16);
  float zi = __uint_as_float(v2 & 0xFFFF0000u);
  // forward DIF FFT64 across lanes, twiddles e^{-i pi n / d}
  #pragma unroll
  for (int s = 0; s < 6; s++) {
    int d = 32 >> s;
    float pr = __shfl_xor(zr, d);
    float pi = __shfl_xor(zi, d);
    float a = (float)(l & (d - 1)) / (float)d;
    float wr = cospif(a), wi = -sinpif(a);
    float sr = zr + pr, si = zi + pi;
    float dr = pr - zr, di = pi - zi;
    float mr2 = dr * wr - di * wi;
    float mi2 = dr * wi + di * wr;
    bool hib = (l & d) != 0;
    zr = hib ? mr2 : sr;
    zi = hib ? mi2 : si;
  }
  // gather Z[l] (at lane bitrev(l)) and Z[(64-l)&63]
  int rl = __brev(l) >> 26;
  int lm = (64 - l) & 63;
  int rm = __brev(lm) >> 26;
  float Zkr = __shfl(zr, rl), Zki = __shfl(zi, rl);
  float Zmr = __shfl(zr, rm), Zmi = __shfl(zi, rm);
  float Fer = 0.5f * (Zkr + Zmr), Fei = 0.5f * (Zki - Zmi);
  float Dr  = 0.5f * (Zkr - Zmr), Di  = 0.5f * (Zki + Zmi);
  float For = Di, Foi = -Dr;             // D / i
  float a = (float)l * (1.f / 64.f);
  float tr = cospif(a), ti = -sinpif(a); // e^{-2 pi i l / 128}
  float Xr = Fer + tr * For - ti * Foi;
  float Xi = Fei + tr * Foi + ti * For;
  size_t o = ((size_t)(b * C2 + c) * H + h) * WF + l;
  size_t ioff = (size_t)C * H * WF;
  spec[o] = Xr;
  spec[o + ioff] = Xi;
  if (l == 0) {                          // k = 64 (Nyquist): Fe0 - Fo0 = se - so
    spec[o + 64] = Fer - For;
    spec[o + 64 + ioff] = 0.f;
  }
}

// ---- complex FFT-128 along H, v6: lane-parallel radix-2, LDS tile ----
// grid = B*C*2; half 0 owns kx[0,32), half 1 owns kx[32,65]. 256 thr = 4 waves.
// Each wave FFTs whole columns: lane l holds rows l, l+64 (2 complex values).
// Stage A (dist-64 butterfly) in-lane -> two FFT64 across lanes (shfl_xor).
// Lane l ends with X[2*br6(l)], X[2*br6(l)+1]; in-place LDS write (columns
// are wave-disjoint), then coalesced store.
__global__ void __launch_bounds__(256) fft_col_k(float* __restrict__ spec,
                                                 float sgn, float scale) {
  __shared__ float re_s[128 * 33], im_s[128 * 33];   // 33.8 KB, stride 33
  int t = threadIdx.x;
  int half = blockIdx.x & 1;
  int bc = blockIdx.x >> 1;
  int cc = bc % C, b = bc / C;
  size_t reb = ((size_t)(b * C2 + cc) * H) * WF;
  size_t imb = reb + (size_t)C * H * WF;
  int ncol = half ? 33 : 32;
  if (half == 0) {
    #pragma unroll
    for (int i = 0; i < 16; i++) {
      int idx = i * 256 + t;             // 4096 = 128*32
      int r = idx >> 5, c = idx & 31;
      re_s[r * 33 + c] = spec[reb + r * WF + c];
      im_s[r * 33 + c] = spec[imb + r * WF + c];
    }
  } else {
    #pragma unroll
    for (int i = 0; i < 17; i++) {
      int idx = i * 256 + t;             // 4352 >= 128*33
      if (idx < 128 * 33) {
        int r = idx / 33, c = idx - r * 33;
        re_s[r * 33 + c] = spec[reb + r * WF + 32 + c];
        im_s[r * 33 + c] = spec[imb + r * WF + 32 + c];
      }
    }
  }
  __syncthreads();
  int w = t >> 6, l = t & 63;
  // twiddles depend only on (lane, stage): hoist out of the column loop
  float cA = cospif((float)l * (1.f / 64.f));
  float sA = sinpif((float)l * (1.f / 64.f)) * sgn;  // e^{sgn*2pi i l/128}
  float cs[6], ss[6];
  #pragma unroll
  for (int s = 0; s < 6; s++) {
    int d = 32 >> s;
    float a = (float)(l & (d - 1)) / (float)d;
    cs[s] = cospif(a); ss[s] = sinpif(a) * sgn;
  }
  int br = __brev(l) >> 26;
  for (int c = w; c < ncol; c += 4) {
    float ar = re_s[l * 33 + c],         ai = im_s[l * 33 + c];
    float xr = re_s[(l + 64) * 33 + c],  xi = im_s[(l + 64) * 33 + c];
    // stage A: distance-64 butterfly, in-lane
    float ur = ar + xr, ui = ai + xi;                // -> even freqs
    float tr = ar - xr, ti = ai - xi;
    float vr = tr * cA - ti * sA;                    // -> odd freqs
    float vi = tr * sA + ti * cA;
    // two FFT64 across lanes (DIF, shuffle butterflies)
    #pragma unroll
    for (int s = 0; s < 6; s++) {
      int d = 32 >> s;
      float pr = __shfl_xor(ur, d), pi = __shfl_xor(ui, d);
      float qr = __shfl_xor(vr, d), qi = __shfl_xor(vi, d);
      float sur = ur + pr, sui = ui + pi;
      float dur = pr - ur, dui = pi - ui;
      float svr = vr + qr, svi = vi + qi;
      float dvr = qr - vr, dvi = qi - vi;
      float mur = dur * cs[s] - dui * ss[s];
      float mui = dur * ss[s] + dui * cs[s];
      float mvr = dvr * cs[s] - dvi * ss[s];
      float mvi = dvr * ss[s] + dvi * cs[s];
      bool hib = (l & d) != 0;
      ur = hib ? mur : sur; ui = hib ? mui : sui;
      vr = hib ? mvr : svr; vi = hib ? mvi : svi;
    }
    int r0 = 2 * br;                     // X[2*br] = U-res, X[2*br+1] = V-res
    re_s[r0 * 33 + c] = ur * scale;       im_s[r0 * 33 + c] = ui * scale;
    re_s[(r0 + 1) * 33 + c] = vr * scale; im_s[(r0 + 1) * 33 + c] = vi * scale;
  }
  __syncthreads();
  if (half == 0) {
    #pragma unroll
    for (int i = 0; i < 16; i++) {
      int idx = i * 256 + t;
      int r = idx >> 5, c = idx & 31;
      spec[reb + r * WF + c] = re_s[r * 33 + c];
      spec[imb + r * WF + c] = im_s[r * 33 + c];
    }
  } else {
    #pragma unroll
    for (int i = 0; i < 17; i++) {
      int idx = i * 256 + t;
      if (idx < 128 * 33) {
        int r = idx / 33, c = idx - r * 33;
        spec[reb + r * WF + 32 + c] = re_s[r * 33 + c];
        spec[imb + r * WF + 32 + c] = im_s[r * 33 + c];
      }
    }
  }
}

// ---- freq-domain channel-mix gate: yf *= gelu(W yf + b) ----
// transposed weights: per-c slice of 24 outputs is contiguous (1-2 cache lines)
__global__ void __launch_bounds__(256) freq_gate_k(float* __restrict__ spec,
                                                   const float* __restrict__ P) {
  __shared__ float vs[96 * 65];
  int t = threadIdx.x;
  int blk = blockIdx.x;
  int b = blk / (SPECHW / 64);
  int pp0 = (blk % (SPECHW / 64)) * 64;
  float* sb = spec + (size_t)b * C2 * SPECHW + pp0;
  #pragma unroll
  for (int i = 0; i < 24; i++) {
    int idx = i * 256 + t;
    int c = idx >> 6, p = idx & 63;
    vs[c * 65 + p] = sb[(size_t)c * SPECHW + p];
  }
  __syncthreads();
  int p = t & 63;
  int og = __builtin_amdgcn_readfirstlane(t >> 6);   // wave-uniform 0..3
  const float* Wcol = P + O_FLW + og * 24;           // transposed: [c*96 + j]
  float acc[24];
  #pragma unroll
  for (int j = 0; j < 24; j++) acc[j] = 0.f;
  for (int c = 0; c < 96; c++) {
    float vv = vs[c * 65 + p];
    const float* wc = Wcol + c * 96;
    #pragma unroll
    for (int j = 0; j < 24; j++) acc[j] += wc[j] * vv;
  }
  #pragma unroll
  for (int j = 0; j < 24; j++) {
    int o = og * 24 + j;
    float g = geluf(acc[j] + P[O_FLB + o]);
    sb[(size_t)o * SPECHW + p] = vs[o * 65 + p] * g;
  }
}

// ---- irfft along W, v3: Hermitian pack + lane-parallel inverse FFT64 ----
// Z[k] = Fe[k] + i Fo[k]; u = IFFT64(Z) unnormalized -> lane l holds u[bitrev(l)];
// y[2m] = Re u[m]/64, y[2m+1] = Im u[m]/64 (1/128 row norm absorbed).
__global__ void __launch_bounds__(256) irfft_row_k(const float* __restrict__ spec,
                                                   bf16* __restrict__ out) {
  int t = threadIdx.x;
  int wid = t >> 6, l = t & 63;
  int row = blockIdx.x * 4 + wid;        // in [0, B*C*H)
  int h = row & (H - 1);
  int bc = row >> 7;
  int c = bc % C, b = bc / C;
  size_t rb = ((size_t)(b * C2 + c) * H + h) * WF;
  size_t ioff = (size_t)C * H * WF;
  float xr = spec[rb + l];
  float xi = (l == 0) ? 0.f : spec[rb + ioff + l];   // C2R: ignore DC imag
  float r64 = spec[rb + 64];                         // Nyquist (real used only)
  int lm = (64 - l) & 63;
  float mr = __shfl(xr, lm);
  float mi = __shfl(xi, lm);
  if (l == 0) { mr = r64; mi = 0.f; }                // X[64] for the k=0 pair
  float Fer = 0.5f * (xr + mr), Fei = 0.5f * (xi - mi);
  float Dr  = 0.5f * (xr - mr), Di  = 0.5f * (xi + mi);
  float a = (float)l * (1.f / 64.f);
  float tr = cospif(a), ti = sinpif(a);              // e^{+2 pi i l / 128}
  float For = tr * Dr - ti * Di;
  float Foi = tr * Di + ti * Dr;
  float zr = Fer - Foi, zi = Fei + For;              // Z = Fe + i*Fo
  // inverse DIF FFT64 across lanes, twiddles e^{+i pi n / d}
  #pragma unroll
  for (int s = 0; s < 6; s++) {
    int d = 32 >> s;
    float pr = __shfl_xor(zr, d);
    float pi = __shfl_xor(zi, d);
    float aa = (float)(l & (d - 1)) / (float)d;
    float wr = cospif(aa), wi = sinpif(aa);
    float sr = zr + pr, si = zi + pi;
    float dr = pr - zr, di = pi - zi;
    float mr2 = dr * wr - di * wi;
    float mi2 = dr * wi + di * wr;
    bool hib = (l & d) != 0;
    zr = hib ? mr2 : sr;
    zi = hib ? mi2 : si;
  }
  int m = __brev(l) >> 26;               // lane holds u[m]
  unsigned p0 = b2u(tob(zr * (1.f / 64.f)));
  unsigned p1 = b2u(tob(zi * (1.f / 64.f)));
  ((unsigned*)(out + (size_t)row * W))[m] = p0 | (p1 << 16);
}

// ---- 1x1 conv v2t: 64 px/block, 4 waves x 12 outputs, transposed weights ----
// wt[c*wstride + o]; wave og covers outputs og*12..og*12+11 (pass base + col off)
// mode 1: input is the external x (flag-dtyped); mode 0: internal bf16
__global__ void __launch_bounds__(256) conv1x1_k(const void* __restrict__ in, bf16* __restrict__ out,
                                                 const float* __restrict__ wt, int wstride,
                                                 const int* flagp, int mode) {
  int bf = mode ? flagp[0] : 1;
  __shared__ float vs[48 * 64];
  int t = threadIdx.x;
  int blk = blockIdx.x;                // B * 256
  int b = blk >> 8;
  int p0 = (blk & 255) << 6;
  int ibase = b * 48 * HW + p0;
  #pragma unroll
  for (int i = 0; i < 12; i++) {
    int idx = i * 256 + t;
    int c = idx >> 6, p = idx & 63;
    vs[idx] = ldx(in, ibase + c * HW + p, bf);
  }
  __syncthreads();
  int p = t & 63;
  int og = __builtin_amdgcn_readfirstlane(t >> 6);   // wave-uniform 0..3
  const float* Wcol = wt + og * 12;                  // transposed: [c*wstride + j]
  float acc[12];
  #pragma unroll
  for (int j = 0; j < 12; j++) acc[j] = 0.f;
  for (int c = 0; c < 48; c++) {
    float v = vs[c * 64 + p];
    const float* wc = Wcol + c * wstride;
    #pragma unroll
    for (int j = 0; j < 12; j++) acc[j] += wc[j] * v;
  }
  bf16* op = out + (size_t)b * 48 * HW + p0 + p;
  #pragma unroll
  for (int j = 0; j < 12; j++) op[(size_t)(og * 12 + j) * HW] = tob(acc[j]);
}

// ---- depthwise 3x3 v2: 4 px/thread, vector row loads, zero pad ----
__global__ void dw3x3_k(const bf16* __restrict__ in, bf16* __restrict__ out,
                        const float* __restrict__ w) {
  int idx4 = blockIdx.x * 256 + threadIdx.x;   // pixel-quad index
  int wq = idx4 & 31;                          // W/4 = 32
  int h = (idx4 >> 5) & (H - 1);
  int plane = idx4 >> 12;                      // b*48 + c  (HW/4 = 4096)
  int c = plane % 48;
  const bf16* p = in + (size_t)plane * HW;
  int w0 = wq << 2;
  float acc[4] = {0.f, 0.f, 0.f, 0.f};
  #pragma unroll
  for (int i = 0; i < 3; i++) {
    int hh = h + i - 1;
    if (hh < 0 || hh >= H) continue;
    const bf16* row = p + hh * W + w0;
    ushort4 u = *(const ushort4*)row;          // 8B-aligned (w0 % 4 == 0)
    float v[6];
    v[1] = u2f(u.x); v[2] = u2f(u.y); v[3] = u2f(u.z); v[4] = u2f(u.w);
    v[0] = (w0 > 0) ? ldf(row, -1) : 0.f;
    v[5] = (w0 + 4 < W) ? ldf(row, 4) : 0.f;
    #pragma unroll
    for (int j = 0; j < 3; j++) {
      float wt = w[c * 9 + i * 3 + j];
      #pragma unroll
      for (int q = 0; q < 4; q++) acc[q] += wt * v[q + j];
    }
  }
  ushort4 o;
  o.x = b2u(tob(acc[0])); o.y = b2u(tob(acc[1]));
  o.z = b2u(tob(acc[2])); o.w = b2u(tob(acc[3]));
  *(ushort4*)(out + (size_t)idx4 * 4) = o;
}

// ---- attn gram, split-L partials: grid = 32 bh * NCHUNK blocks ----
__global__ void __launch_bounds__(256) attn_part_k(const bf16* __restrict__ q,
                                                   const bf16* __restrict__ kbuf,
                                                   float* __restrict__ partial) {
  int blk = blockIdx.x;
  int bh = blk >> 6, chunk = blk & (NCHUNK - 1);
  int b = bh >> 2, hd = bh & 3;
  int t = threadIdx.x;
  int l0 = chunk * 256;
  __shared__ float qs[12 * 257], ks[12 * 257];
  const bf16* qb = q + (size_t)(b * 48 + hd * 12) * HW + l0;
  const bf16* kb = kbuf + (size_t)(b * 48 + hd * 12) * HW + l0;
  #pragma unroll
  for (int m = 0; m < 12; m++) {
    qs[m * 257 + t] = ldf(qb, m * HW + t);
    ks[m * 257 + t] = ldf(kb, m * HW + t);
  }
  __syncthreads();
  float acc = 0.f;
  if (t < 144) {
    const float* qr = qs + (t / 12) * 257;
    const float* kr = ks + (t % 12) * 257;
    #pragma unroll 4
    for (int j = 0; j < 256; j++) acc += qr[j] * kr[j];
  } else if (t < 156) {
    const float* qr = qs + (t - 144) * 257;
    #pragma unroll 4
    for (int j = 0; j < 256; j++) acc += qr[j] * qr[j];
  } else if (t < 168) {
    const float* kr = ks + (t - 156) * 257;
    #pragma unroll 4
    for (int j = 0; j < 256; j++) acc += kr[j] * kr[j];
  }
  if (t < 168) partial[(size_t)(chunk * 32 + bh) * 168 + t] = acc;
}

// ---- reduce partials + norms + softmax -> 12x12 attn per bh ----
__global__ void __launch_bounds__(256) attn_fin_k(const float* __restrict__ partial,
                                                  const float* __restrict__ temp,
                                                  float* __restrict__ attn) {
  int bh = blockIdx.x, hd = bh & 3;
  int t = threadIdx.x;
  __shared__ float red[168];
  if (t < 168) {
    float s = 0.f;
    for (int ch = 0; ch < NCHUNK; ch++) s += partial[(size_t)(ch * 32 + bh) * 168 + t];
    red[t] = s;
  }
  __syncthreads();
  if (t < 12) {
    float tm = temp[hd];
    float rq = 1.f / fmaxf(sqrtf(red[144 + t]), 1e-12f);
    float vals[12], mx = -1e30f;
    #pragma unroll
    for (int d = 0; d < 12; d++) {
      float rk = 1.f / fmaxf(sqrtf(red[156 + d]), 1e-12f);
      vals[d] = red[t * 12 + d] * rq * rk * tm;
      mx = fmaxf(mx, vals[d]);
    }
    float s = 0.f;
    #pragma unroll
    for (int d = 0; d < 12; d++) { vals[d] = expf(vals[d] - mx); s += vals[d]; }
    float inv = 1.f / s;
    float* ao = attn + (size_t)(bh * 12 + t) * 12;
    #pragma unroll
    for (int d = 0; d < 12; d++) ao[d] = vals[d] * inv;
  }
}

// ---- out = attn @ v ----
__global__ void attn_apply_k(const float* __restrict__ attn, const bf16* __restrict__ vbuf,
                             bf16* __restrict__ out) {
  int blk = blockIdx.x;
  int bh = blk >> 6, b = bh >> 2, hd = bh & 3;
  int l = ((blk & 63) << 8) + threadIdx.x;
  __shared__ float al[144];
  if (threadIdx.x < 144) al[threadIdx.x] = attn[bh * 144 + threadIdx.x];
  __syncthreads();
  const bf16* vb = vbuf + (size_t)(b * 48 + hd * 12) * HW + l;
  float vv[12];
  #pragma unroll
  for (int d = 0; d < 12; d++) vv[d] = ldf(vb, d * HW);
  bf16* ob = out + (size_t)(b * 48 + hd * 12) * HW + l;
  #pragma unroll
  for (int c = 0; c < 12; c++) {
    float s = 0.f;
    #pragma unroll
    for (int d = 0; d < 12; d++) s += al[c * 12 + d] * vv[d];
    ob[(size_t)c * HW] = tob(s);
  }
}

// ---- final v2t: 64 px/block, 4 waves x 12 outputs, transposed weights ----
__global__ void __launch_bounds__(256) conv_final_k(const bf16* __restrict__ ho,
                                                    const bf16* __restrict__ lo,
                                                    const float* __restrict__ P,
                                                    const void* __restrict__ x,
                                                    void* __restrict__ out,
                                                    const int* flagp) {
  int bf = flagp[0];
  __shared__ float vs[96 * 64];
  int t = threadIdx.x;
  int blk = blockIdx.x;                // B * 256
  int b = blk >> 8;
  int p0 = (blk & 255) << 6;
  int pbase = b * 48 * HW + p0;
  #pragma unroll
  for (int i = 0; i < 12; i++) {
    int idx = i * 256 + t;
    int c = idx >> 6, p = idx & 63;
    vs[idx] = ldf(ho, pbase + c * HW + p);
    vs[48 * 64 + idx] = ldf(lo, pbase + c * HW + p);
  }
  __syncthreads();
  int p = t & 63;
  int og = __builtin_amdgcn_readfirstlane(t >> 6);   // wave-uniform 0..3
  const float* Wcol = P + O_FPW + og * 12;           // transposed: [c*48 + j]
  float acc[12];
  #pragma unroll
  for (int j = 0; j < 12; j++) acc[j] = 0.f;
  for (int c = 0; c < 96; c++) {
    float v = vs[c * 64 + p];
    const float* wc = Wcol + c * 48;
    #pragma unroll
    for (int j = 0; j < 12; j++) acc[j] += wc[j] * v;
  }
  #pragma unroll
  for (int j = 0; j < 12; j++) {
    int o = og * 12 + j;
    int oi = pbase + o * HW + p;
    float val = acc[j] + P[O_FPB + o] + ldx(x, oi, bf);
    if (bf) ((bf16*)out)[oi] = tob(val);
    else    ((float*)out)[oi] = val;
  }
}

extern "C" void kernel_launch(void* const* d_in, const int* in_sizes, int n_in,
                              void* d_out, int out_size, void* d_ws, size_t ws_size,
                              hipStream_t stream) {
  const void* x = d_in[0];

  // ws layout (fp32 units): ap@0, wts@512, attnm@2048, flag@7000,
  // params@8192 (ends 47224), partials@49152 (64*32*168 -> ends 393216),
  // bf16 planes @400000
  float* ws    = (float*)d_ws;
  float* ap    = ws;
  float* wts   = ws + 512;
  float* attnm = ws + 2048;
  int*   flagp = (int*)(ws + 7000);
  float* P     = ws + 8192;
  float* parts = ws + 49152;
  bf16* base = (bf16*)(ws + 400000);
  bf16* HF = base;
  bf16* LF = base + (size_t)NCHW;
  bf16* T  = base + (size_t)2 * NCHW;
  bf16* Q  = base + (size_t)3 * NCHW;
  bf16* K  = base + (size_t)4 * NCHW;
  float* spec = (float*)T;

  // ---- dtype detect + param convert (matmul weights transposed) ----
  detect_k<<<1, 256, 0, stream>>>(x, flagp);
  ParamTab tab;
  const int offs[25] = {O_FDW, O_BNG, O_BNB, O_BNM, O_BNV,
                        O_FHW1, O_FHB1, O_FHW2, O_FHB2,
                        O_FLW, O_FLB,
                        O_HQW, O_HKVW, O_HQDW, O_HKVDW, O_HPW, O_HT,
                        O_LQW, O_LKVW, O_LQDW, O_LKVDW, O_LPW, O_LT,
                        O_FPW, O_FPB};
  const int cnts[25] = {3456, 72, 72, 72, 72,
                        144, 48, 144, 48,
                        9216, 96,
                        2304, 4608, 432, 864, 2304, 4,
                        2304, 4608, 432, 864, 2304, 4,
                        4608, 48};
  const int rows[25] = {0, 0, 0, 0, 0,
                        0, 0, 0, 0,
                        96, 0,
                        48, 96, 0, 0, 48, 0,
                        48, 96, 0, 0, 48, 0,
                        48, 0};
  for (int i = 0; i < 25; i++) {
    tab.src[i] = d_in[i + 1]; tab.off[i] = offs[i]; tab.cnt[i] = cnts[i]; tab.rows[i] = rows[i];
  }
  cvt_params_k<<<25, 256, 0, stream>>>(tab, flagp, P);

  // ---- fd ----
  reduce_mean_k<<<B * C, 256, 0, stream>>>(x, ap, flagp);
  fd_weights_k<<<B, 128, 0, stream>>>(ap, P, wts);
  fd_apply_k<<<NCHW / 256, 256, 0, stream>>>(x, wts, LF, Q, flagp);   // low->LF, high->Q
  // ---- fmgm_high ----
  fmgm_high_k<<<NCHW / 256, 256, 0, stream>>>(Q, P, HF);              // hf->HF
  // ---- fmgm_low: rfft2 -> gate -> irfft2 ----
  rfft_row_k<<<B * C * H / 4, 256, 0, stream>>>(LF, spec);
  fft_col_k<<<B * C * 2, 256, 0, stream>>>(spec, -1.f, 1.f);
  freq_gate_k<<<B * (SPECHW / 64), 256, 0, stream>>>(spec, P);
  fft_col_k<<<B * C * 2, 256, 0, stream>>>(spec, 1.f, 1.f / 128.f);
  irfft_row_k<<<B * C * H / 4, 256, 0, stream>>>(spec, LF);           // lf->LF
  // ---- fga (high branch: freq = hf in HF) ----
  conv1x1_k<<<B * 256, 256, 0, stream>>>(HF, T, P + O_HQW, 48, flagp, 0);
  dw3x3_k<<<NCHW / 1024, 256, 0, stream>>>(T, Q, P + O_HQDW);         // q->Q (high dead)
  conv1x1_k<<<B * 256, 256, 0, stream>>>(x, T, P + O_HKVW, 96, flagp, 1);
  dw3x3_k<<<NCHW / 1024, 256, 0, stream>>>(T, K, P + O_HKVDW);        // k->K
  conv1x1_k<<<B * 256, 256, 0, stream>>>(x, T, P + O_HKVW + 48, 96, flagp, 1);
  dw3x3_k<<<NCHW / 1024, 256, 0, stream>>>(T, HF, P + O_HKVDW + 48 * 9); // v->HF (hf dead)
  attn_part_k<<<32 * NCHUNK, 256, 0, stream>>>(Q, K, parts);
  attn_fin_k<<<32, 256, 0, stream>>>(parts, P + O_HT, attnm);
  attn_apply_k<<<B * 4 * 64, 256, 0, stream>>>(attnm, HF, K);         // attnout->K (k dead)
  conv1x1_k<<<B * 256, 256, 0, stream>>>(K, Q, P + O_HPW, 48, flagp, 0);  // ho->Q (q dead)
  // ---- fga (low branch: freq = lf in LF) ----
  conv1x1_k<<<B * 256, 256, 0, stream>>>(LF, T, P + O_LQW, 48, flagp, 0);
  dw3x3_k<<<NCHW / 1024, 256, 0, stream>>>(T, HF, P + O_LQDW);        // q->HF
  conv1x1_k<<<B * 256, 256, 0, stream>>>(x, T, P + O_LKVW, 96, flagp, 1);
  dw3x3_k<<<NCHW / 1024, 256, 0, stream>>>(T, K, P + O_LKVDW);        // k->K
  conv1x1_k<<<B * 256, 256, 0, stream>>>(x, T, P + O_LKVW + 48, 96, flagp, 1);
  dw3x3_k<<<NCHW / 1024, 256, 0, stream>>>(T, LF, P + O_LKVDW + 48 * 9); // v->LF (lf dead)
  attn_part_k<<<32 * NCHUNK, 256, 0, stream>>>(HF, K, parts);
  attn_fin_k<<<32, 256, 0, stream>>>(parts, P + O_LT, attnm);
  attn_apply_k<<<B * 4 * 64, 256, 0, stream>>>(attnm, LF, K);         // attnout->K
  conv1x1_k<<<B * 256, 256, 0, stream>>>(K, T, P + O_LPW, 48, flagp, 0);  // lo->T
  // ---- final 1x1 + bias + residual ----
  conv_final_k<<<B * 256, 256, 0, stream>>>(Q, T, P, x, d_out, flagp);
}

// Round 5
// 647.213 us; speedup vs baseline: 1.5592x; 1.0578x over previous
//
#include <hip/hip_runtime.h>
#include <hip/hip_bf16.h>
#include <math.h>

using bf16 = __hip_bfloat16;
#define DI __device__ __forceinline__

namespace {
constexpr int B = 8, C = 48, H = 128, W = 128;
constexpr int HW = H * W;                 // 16384
constexpr int NCHW = B * C * HW;          // 6,291,456
constexpr int C2 = 96;
constexpr int WF = 65;                    // rfft width
constexpr int SPECHW = H * WF;            // 8320 (divisible by 64)
constexpr int SPECN = B * C2 * SPECHW;    // 6,389,760 floats
// spec (fp32) overlays the T+Q+K bf16 region = 3*NCHW bf16 slots
static_assert((size_t)SPECN * 4 <= (size_t)3 * NCHW * 2, "spec must fit in T+Q+K overlay");
static_assert(SPECHW % 64 == 0, "freq_gate 64-pixel blocks must not straddle batches");

// fp32 param header offsets (in floats), base = ws + 8192
// NOTE: matmul weights (FLW, *QW, *KVW, *PW, FPW) are stored TRANSPOSED
// (input-major): wt[c*rows + o]. Depthwise/BN/bias params stay plain.
constexpr int O_FDW = 0,    O_BNG = 3456, O_BNB = 3528, O_BNM = 3600, O_BNV = 3672;
constexpr int O_FHW1 = 3744, O_FHB1 = 3888, O_FHW2 = 3936, O_FHB2 = 3984;
constexpr int O_FLW = 4032,  O_FLB = 13248;
constexpr int O_HQW = 13344, O_HKVW = 15648, O_HQDW = 20256, O_HKVDW = 20688, O_HPW = 21552, O_HT = 23856;
constexpr int O_LQW = 23860, O_LKVW = 26164, O_LQDW = 30772, O_LKVDW = 31204, O_LPW = 32068, O_LT = 34372;
constexpr int O_FPW = 34376, O_FPB = 38984;  // end 39032

constexpr int NCHUNK = 64;                // L split for attn gram
}

DI float ldf(const float* p, int i) { return p[i]; }
DI float ldf(const bf16* p, int i) { return __bfloat162float(p[i]); }
DI bf16 tob(float x) { return __float2bfloat16(x); }
DI unsigned short b2u(bf16 v) { union { bf16 b; unsigned short u; } x; x.b = v; return x.u; }
DI float u2f(unsigned short u) { return __uint_as_float((unsigned)u << 16); }
DI float ldx(const void* p, int i, int bf) {
  return bf ? __bfloat162float(((const bf16*)p)[i]) : ((const float*)p)[i];
}
DI float geluf(float x) { return 0.5f * x * (1.f + erff(x * 0.70710678118654752f)); }
DI int refl(int i, int n) { return i < 0 ? -i : (i >= n ? 2 * n - 2 - i : i); }

// ---- dtype detector: bf16 data -> even u16 slots have sane exponents ----
__global__ void detect_k(const void* x, int* flagp) {
  const unsigned short* u = (const unsigned short*)x;
  int t = threadIdx.x;
  int good = 0;
  for (int i = t; i < 1024; i += 256) {
    unsigned short v = u[2 * i];
    int e = (v >> 7) & 0xFF;
    if (e >= 100 && e <= 140) good++;
  }
  __shared__ int cnt;
  if (t == 0) cnt = 0;
  __syncthreads();
  atomicAdd(&cnt, good);
  __syncthreads();
  if (t == 0) flagp[0] = (cnt > 512) ? 1 : 0;
}

// ---- convert all params to fp32 header; matmul weights transposed ----
// rows[b] == 0: plain copy. rows[b] = R (out-channels of original [R][cols]):
// dst[(i%cols)*R + i/cols] = src[i]  -> input-major wt[c*R + o].
struct ParamTab { const void* src[25]; int off[25]; int cnt[25]; int rows[25]; };
__global__ void cvt_params_k(ParamTab tab, const int* flagp, float* dst) {
  int bf = flagp[0];
  int b = blockIdx.x;
  const void* s = tab.src[b];
  float* d = dst + tab.off[b];
  int n = tab.cnt[b];
  int rows = tab.rows[b];
  if (rows == 0) {
    for (int i = threadIdx.x; i < n; i += 256) d[i] = ldx(s, i, bf);
  } else {
    int cols = n / rows;
    for (int i = threadIdx.x; i < n; i += 256)
      d[(i % cols) * rows + (i / cols)] = ldx(s, i, bf);
  }
}

// ---- fd: channel means, v2: vector loads ----
__global__ void reduce_mean_k(const void* __restrict__ x, float* __restrict__ ap,
                              const int* flagp) {
  int bf = flagp[0];
  int bc = blockIdx.x;
  float s = 0.f;
  if (bf) {
    const ushort4* xp = (const ushort4*)((const bf16*)x + (size_t)bc * HW);
    for (int i = threadIdx.x; i < HW / 4; i += 256) {
      ushort4 u = xp[i];
      s += u2f(u.x) + u2f(u.y) + u2f(u.z) + u2f(u.w);
    }
  } else {
    const float4* xp = (const float4*)((const float*)x + (size_t)bc * HW);
    for (int i = threadIdx.x; i < HW / 4; i += 256) {
      float4 u = xp[i];
      s += u.x + u.y + u.z + u.w;
    }
  }
  #pragma unroll
  for (int o = 32; o > 0; o >>= 1) s += __shfl_down(s, o);
  __shared__ float r[4];
  if ((threadIdx.x & 63) == 0) r[threadIdx.x >> 6] = s;
  __syncthreads();
  if (threadIdx.x == 0) ap[bc] = (r[0] + r[1] + r[2] + r[3]) * (1.f / HW);
}

// ---- fd: 72-wide linear + BN + per-group softmax over 9 ----
__global__ void fd_weights_k(const float* __restrict__ ap, const float* __restrict__ P,
                             float* __restrict__ wts) {
  int n = blockIdx.x, t = threadIdx.x;
  __shared__ float vals[72], es[72];
  if (t < 72) {
    float acc = 0.f;
    for (int c = 0; c < C; c++) acc += P[O_FDW + t * C + c] * ap[n * C + c];
    acc = (acc - P[O_BNM + t]) * rsqrtf(P[O_BNV + t] + 1e-5f);
    vals[t] = acc * P[O_BNG + t] + P[O_BNB + t];
  }
  __syncthreads();
  if (t < 72) {
    int base = (t / 9) * 9;
    float mx = -1e30f;
    for (int k = 0; k < 9; k++) mx = fmaxf(mx, vals[base + k]);
    es[t] = expf(vals[t] - mx);
  }
  __syncthreads();
  if (t < 72) {
    int base = (t / 9) * 9;
    float s = 0.f;
    for (int k = 0; k < 9; k++) s += es[base + k];
    wts[n * 72 + t] = es[t] / s;
  }
}

// ---- fd v2: involution low-pass (reflect pad), 4 px/thread, vector rows ----
// reflect at W-edges picks in-register: refl(-1)=1 -> v[2], refl(W)=W-2 -> v[3]
__global__ void fd_apply_k(const void* __restrict__ x, const float* __restrict__ wts,
                           bf16* __restrict__ low, bf16* __restrict__ high,
                           const int* flagp) {
  int bf = flagp[0];
  int idx4 = blockIdx.x * 256 + threadIdx.x;   // quad index over NCHW/4
  int w0 = (idx4 & 31) << 2;                   // W/4 = 32
  int h = (idx4 >> 5) & (H - 1);
  int plane = idx4 >> 12;                      // b*C + c
  int c = plane % C;
  int b = plane / C;
  const float* wt = wts + b * 72 + (c / 6) * 9;
  size_t pbase = (size_t)plane * HW;
  float acc[4] = {0.f, 0.f, 0.f, 0.f};
  float ctr[4];
  #pragma unroll
  for (int i = 0; i < 3; i++) {
    int hh = refl(h + i - 1, H);
    float v[6];
    if (bf) {
      const bf16* row = (const bf16*)x + pbase + hh * W + w0;
      ushort4 u = *(const ushort4*)row;        // 8B aligned
      v[1] = u2f(u.x); v[2] = u2f(u.y); v[3] = u2f(u.z); v[4] = u2f(u.w);
      v[0] = (w0 > 0) ? ldf(row, -1) : v[2];
      v[5] = (w0 + 4 < W) ? ldf(row, 4) : v[3];
    } else {
      const float* row = (const float*)x + pbase + hh * W + w0;
      float4 u = *(const float4*)row;          // 16B aligned
      v[1] = u.x; v[2] = u.y; v[3] = u.z; v[4] = u.w;
      v[0] = (w0 > 0) ? row[-1] : v[2];
      v[5] = (w0 + 4 < W) ? row[4] : v[3];
    }
    if (i == 1) { ctr[0] = v[1]; ctr[1] = v[2]; ctr[2] = v[3]; ctr[3] = v[4]; }
    #pragma unroll
    for (int j = 0; j < 3; j++) {
      float wv = wt[i * 3 + j];
      #pragma unroll
      for (int q = 0; q < 4; q++) acc[q] += wv * v[q + j];
    }
  }
  ushort4 ol, oh;
  ol.x = b2u(tob(acc[0])); ol.y = b2u(tob(acc[1]));
  ol.z = b2u(tob(acc[2])); ol.w = b2u(tob(acc[3]));
  oh.x = b2u(tob(ctr[0] - acc[0])); oh.y = b2u(tob(ctr[1] - acc[1]));
  oh.z = b2u(tob(ctr[2] - acc[2])); oh.w = b2u(tob(ctr[3] - acc[3]));
  *(ushort4*)(low + (size_t)idx4 * 4) = ol;
  *(ushort4*)(high + (size_t)idx4 * 4) = oh;
}

// ---- fmgm_high v2: fused (1x3)->(3x1) dwconv -> gelu * x, 4 px/thread ----
__global__ void fmgm_high_k(const bf16* __restrict__ hi, const float* __restrict__ P,
                            bf16* __restrict__ out) {
  int idx4 = blockIdx.x * 256 + threadIdx.x;   // quad index over NCHW/4
  int w0 = (idx4 & 31) << 2;
  int h = (idx4 >> 5) & (H - 1);
  int plane = idx4 >> 12;
  int c = plane % C;
  const bf16* p = hi + (size_t)plane * HW;
  float k1[3], k2[3];
  #pragma unroll
  for (int j = 0; j < 3; j++) { k1[j] = P[O_FHW1 + c * 3 + j]; k2[j] = P[O_FHW2 + c * 3 + j]; }
  float b1 = P[O_FHB1 + c];
  float b2 = P[O_FHB2 + c];
  float acc[4] = {b2, b2, b2, b2};
  float ctr[4];
  #pragma unroll
  for (int i = 0; i < 3; i++) {
    int hh = h + i - 1;
    if (hh < 0 || hh >= H) continue;
    const bf16* row = p + hh * W + w0;
    ushort4 u = *(const ushort4*)row;          // 8B aligned
    float v[6];
    v[1] = u2f(u.x); v[2] = u2f(u.y); v[3] = u2f(u.z); v[4] = u2f(u.w);
    v[0] = (w0 > 0) ? ldf(row, -1) : 0.f;      // zero pad
    v[5] = (w0 + 4 < W) ? ldf(row, 4) : 0.f;
    if (i == 1) { ctr[0] = v[1]; ctr[1] = v[2]; ctr[2] = v[3]; ctr[3] = v[4]; }
    float kk = k2[i];
    #pragma unroll
    for (int q = 0; q < 4; q++) {
      float y1 = b1 + k1[0] * v[q] + k1[1] * v[q + 1] + k1[2] * v[q + 2];
      acc[q] += kk * y1;
    }
  }
  ushort4 o;
  o.x = b2u(tob(geluf(acc[0]) * ctr[0]));
  o.y = b2u(tob(geluf(acc[1]) * ctr[1]));
  o.z = b2u(tob(geluf(acc[2]) * ctr[2]));
  o.w = b2u(tob(geluf(acc[3]) * ctr[3]));
  *(ushort4*)(out + (size_t)idx4 * 4) = o;
}

// ---- rfft along W, v3: lane-parallel radix-2 FFT64 (shuffle butterflies) ----
// pack: z[l] = x[2l] + i x[2l+1]; 6-stage DIF -> Z[bitrev(l)] at lane l;
// Hermitian unpack via 2 dynamic shuffles -> X[l] (and X[64] from lane 0).
__global__ void __launch_bounds__(256) rfft_row_k(const bf16* __restrict__ low,
                                                  float* __restrict__ spec) {
  int t = threadIdx.x;
  int wid = t >> 6, l = t & 63;
  int row = blockIdx.x * 4 + wid;        // in [0, B*C*H)
  int h = row & (H - 1);
  int bc = row >> 7;
  int c = bc % C, b = bc / C;
  const unsigned* xr = (const unsigned*)(low + (size_t)row * W);
  unsigned v2 = xr[l];                   // two bf16: elems 2l, 2l+1
  float zr = __uint_as_float(v2 << 16);
  float zi = __uint_as_float(v2 & 0xFFFF0000u);
  // forward DIF FFT64 across lanes, twiddles e^{-i pi n / d}
  #pragma unroll
  for (int s = 0; s < 6; s++) {
    int d = 32 >> s;
    float pr = __shfl_xor(zr, d);
    float pi = __shfl_xor(zi, d);
    float a = (float)(l & (d - 1)) / (float)d;
    float wr = cospif(a), wi = -sinpif(a);
    float sr = zr + pr, si = zi + pi;
    float dr = pr - zr, di = pi - zi;
    float mr2 = dr * wr - di * wi;
    float mi2 = dr * wi + di * wr;
    bool hib = (l & d) != 0;
    zr = hib ? mr2 : sr;
    zi = hib ? mi2 : si;
  }
  // gather Z[l] (at lane bitrev(l)) and Z[(64-l)&63]
  int rl = __brev(l) >> 26;
  int lm = (64 - l) & 63;
  int rm = __brev(lm) >> 26;
  float Zkr = __shfl(zr, rl), Zki = __shfl(zi, rl);
  float Zmr = __shfl(zr, rm), Zmi = __shfl(zi, rm);
  float Fer = 0.5f * (Zkr + Zmr), Fei = 0.5f * (Zki - Zmi);
  float Dr  = 0.5f * (Zkr - Zmr), Di  = 0.5f * (Zki + Zmi);
  float For = Di, Foi = -Dr;             // D / i
  float a = (float)l * (1.f / 64.f);
  float tr = cospif(a), ti = -sinpif(a); // e^{-2 pi i l / 128}
  float Xr = Fer + tr * For - ti * Foi;
  float Xi = Fei + tr * Foi + ti * For;
  size_t o = ((size_t)(b * C2 + c) * H + h) * WF + l;
  size_t ioff = (size_t)C * H * WF;
  spec[o] = Xr;
  spec[o + ioff] = Xi;
  if (l == 0) {                          // k = 64 (Nyquist): Fe0 - Fo0 = se - so
    spec[o + 64] = Fer - For;
    spec[o + 64 + ioff] = 0.f;
  }
}

// ---- complex FFT-128 along H, v6: lane-parallel radix-2, LDS tile ----
// grid = B*C*2; half 0 owns kx[0,32), half 1 owns kx[32,65]. 256 thr = 4 waves.
// Each wave FFTs whole columns: lane l holds rows l, l+64 (2 complex values).
// Stage A (dist-64 butterfly) in-lane -> two FFT64 across lanes (shfl_xor).
// Lane l ends with X[2*br6(l)], X[2*br6(l)+1]; in-place LDS write (columns
// are wave-disjoint), then coalesced store.
__global__ void __launch_bounds__(256) fft_col_k(float* __restrict__ spec,
                                                 float sgn, float scale) {
  __shared__ float re_s[128 * 33], im_s[128 * 33];   // 33.8 KB, stride 33
  int t = threadIdx.x;
  int half = blockIdx.x & 1;
  int bc = blockIdx.x >> 1;
  int cc = bc % C, b = bc / C;
  size_t reb = ((size_t)(b * C2 + cc) * H) * WF;
  size_t imb = reb + (size_t)C * H * WF;
  int ncol = half ? 33 : 32;
  if (half == 0) {
    #pragma unroll
    for (int i = 0; i < 16; i++) {
      int idx = i * 256 + t;             // 4096 = 128*32
      int r = idx >> 5, c = idx & 31;
      re_s[r * 33 + c] = spec[reb + r * WF + c];
      im_s[r * 33 + c] = spec[imb + r * WF + c];
    }
  } else {
    #pragma unroll
    for (int i = 0; i < 17; i++) {
      int idx = i * 256 + t;             // 4352 >= 128*33
      if (idx < 128 * 33) {
        int r = idx / 33, c = idx - r * 33;
        re_s[r * 33 + c] = spec[reb + r * WF + 32 + c];
        im_s[r * 33 + c] = spec[imb + r * WF + 32 + c];
      }
    }
  }
  __syncthreads();
  int w = t >> 6, l = t & 63;
  // twiddles depend only on (lane, stage): hoist out of the column loop
  float cA = cospif((float)l * (1.f / 64.f));
  float sA = sinpif((float)l * (1.f / 64.f)) * sgn;  // e^{sgn*2pi i l/128}
  float cs[6], ss[6];
  #pragma unroll
  for (int s = 0; s < 6; s++) {
    int d = 32 >> s;
    float a = (float)(l & (d - 1)) / (float)d;
    cs[s] = cospif(a); ss[s] = sinpif(a) * sgn;
  }
  int br = __brev(l) >> 26;
  for (int c = w; c < ncol; c += 4) {
    float ar = re_s[l * 33 + c],         ai = im_s[l * 33 + c];
    float xr = re_s[(l + 64) * 33 + c],  xi = im_s[(l + 64) * 33 + c];
    // stage A: distance-64 butterfly, in-lane
    float ur = ar + xr, ui = ai + xi;                // -> even freqs
    float tr = ar - xr, ti = ai - xi;
    float vr = tr * cA - ti * sA;                    // -> odd freqs
    float vi = tr * sA + ti * cA;
    // two FFT64 across lanes (DIF, shuffle butterflies)
    #pragma unroll
    for (int s = 0; s < 6; s++) {
      int d = 32 >> s;
      float pr = __shfl_xor(ur, d), pi = __shfl_xor(ui, d);
      float qr = __shfl_xor(vr, d), qi = __shfl_xor(vi, d);
      float sur = ur + pr, sui = ui + pi;
      float dur = pr - ur, dui = pi - ui;
      float svr = vr + qr, svi = vi + qi;
      float dvr = qr - vr, dvi = qi - vi;
      float mur = dur * cs[s] - dui * ss[s];
      float mui = dur * ss[s] + dui * cs[s];
      float mvr = dvr * cs[s] - dvi * ss[s];
      float mvi = dvr * ss[s] + dvi * cs[s];
      bool hib = (l & d) != 0;
      ur = hib ? mur : sur; ui = hib ? mui : sui;
      vr = hib ? mvr : svr; vi = hib ? mvi : svi;
    }
    int r0 = 2 * br;                     // X[2*br] = U-res, X[2*br+1] = V-res
    re_s[r0 * 33 + c] = ur * scale;       im_s[r0 * 33 + c] = ui * scale;
    re_s[(r0 + 1) * 33 + c] = vr * scale; im_s[(r0 + 1) * 33 + c] = vi * scale;
  }
  __syncthreads();
  if (half == 0) {
    #pragma unroll
    for (int i = 0; i < 16; i++) {
      int idx = i * 256 + t;
      int r = idx >> 5, c = idx & 31;
      spec[reb + r * WF + c] = re_s[r * 33 + c];
      spec[imb + r * WF + c] = im_s[r * 33 + c];
    }
  } else {
    #pragma unroll
    for (int i = 0; i < 17; i++) {
      int idx = i * 256 + t;
      if (idx < 128 * 33) {
        int r = idx / 33, c = idx - r * 33;
        spec[reb + r * WF + 32 + c] = re_s[r * 33 + c];
        spec[imb + r * WF + 32 + c] = im_s[r * 33 + c];
      }
    }
  }
}

// ---- freq-domain channel-mix gate: yf *= gelu(W yf + b) ----
// transposed weights: per-c slice of 24 outputs is contiguous (1-2 cache lines)
__global__ void __launch_bounds__(256) freq_gate_k(float* __restrict__ spec,
                                                   const float* __restrict__ P) {
  __shared__ float vs[96 * 65];
  int t = threadIdx.x;
  int blk = blockIdx.x;
  int b = blk / (SPECHW / 64);
  int pp0 = (blk % (SPECHW / 64)) * 64;
  float* sb = spec + (size_t)b * C2 * SPECHW + pp0;
  #pragma unroll
  for (int i = 0; i < 24; i++) {
    int idx = i * 256 + t;
    int c = idx >> 6, p = idx & 63;
    vs[c * 65 + p] = sb[(size_t)c * SPECHW + p];
  }
  __syncthreads();
  int p = t & 63;
  int og = __builtin_amdgcn_readfirstlane(t >> 6);   // wave-uniform 0..3
  const float* Wcol = P + O_FLW + og * 24;           // transposed: [c*96 + j]
  float acc[24];
  #pragma unroll
  for (int j = 0; j < 24; j++) acc[j] = 0.f;
  for (int c = 0; c < 96; c++) {
    float vv = vs[c * 65 + p];
    const float* wc = Wcol + c * 96;
    #pragma unroll
    for (int j = 0; j < 24; j++) acc[j] += wc[j] * vv;
  }
  #pragma unroll
  for (int j = 0; j < 24; j++) {
    int o = og * 24 + j;
    float g = geluf(acc[j] + P[O_FLB + o]);
    sb[(size_t)o * SPECHW + p] = vs[o * 65 + p] * g;
  }
}

// ---- irfft along W, v3: Hermitian pack + lane-parallel inverse FFT64 ----
// Z[k] = Fe[k] + i Fo[k]; u = IFFT64(Z) unnormalized -> lane l holds u[bitrev(l)];
// y[2m] = Re u[m]/64, y[2m+1] = Im u[m]/64 (1/128 row norm absorbed).
__global__ void __launch_bounds__(256) irfft_row_k(const float* __restrict__ spec,
                                                   bf16* __restrict__ out) {
  int t = threadIdx.x;
  int wid = t >> 6, l = t & 63;
  int row = blockIdx.x * 4 + wid;        // in [0, B*C*H)
  int h = row & (H - 1);
  int bc = row >> 7;
  int c = bc % C, b = bc / C;
  size_t rb = ((size_t)(b * C2 + c) * H + h) * WF;
  size_t ioff = (size_t)C * H * WF;
  float xr = spec[rb + l];
  float xi = (l == 0) ? 0.f : spec[rb + ioff + l];   // C2R: ignore DC imag
  float r64 = spec[rb + 64];                         // Nyquist (real used only)
  int lm = (64 - l) & 63;
  float mr = __shfl(xr, lm);
  float mi = __shfl(xi, lm);
  if (l == 0) { mr = r64; mi = 0.f; }                // X[64] for the k=0 pair
  float Fer = 0.5f * (xr + mr), Fei = 0.5f * (xi - mi);
  float Dr  = 0.5f * (xr - mr), Di  = 0.5f * (xi + mi);
  float a = (float)l * (1.f / 64.f);
  float tr = cospif(a), ti = sinpif(a);              // e^{+2 pi i l / 128}
  float For = tr * Dr - ti * Di;
  float Foi = tr * Di + ti * Dr;
  float zr = Fer - Foi, zi = Fei + For;              // Z = Fe + i*Fo
  // inverse DIF FFT64 across lanes, twiddles e^{+i pi n / d}
  #pragma unroll
  for (int s = 0; s < 6; s++) {
    int d = 32 >> s;
    float pr = __shfl_xor(zr, d);
    float pi = __shfl_xor(zi, d);
    float aa = (float)(l & (d - 1)) / (float)d;
    float wr = cospif(aa), wi = sinpif(aa);
    float sr = zr + pr, si = zi + pi;
    float dr = pr - zr, di = pi - zi;
    float mr2 = dr * wr - di * wi;
    float mi2 = dr * wi + di * wr;
    bool hib = (l & d) != 0;
    zr = hib ? mr2 : sr;
    zi = hib ? mi2 : si;
  }
  int m = __brev(l) >> 26;               // lane holds u[m]
  unsigned p0 = b2u(tob(zr * (1.f / 64.f)));
  unsigned p1 = b2u(tob(zi * (1.f / 64.f)));
  ((unsigned*)(out + (size_t)row * W))[m] = p0 | (p1 << 16);
}

// ---- 1x1 conv v2t: 64 px/block, 4 waves x 12 outputs, transposed weights ----
// wt[c*wstride + o]; wave og covers outputs og*12..og*12+11 (pass base + col off)
// mode 1: input is the external x (flag-dtyped); mode 0: internal bf16
__global__ void __launch_bounds__(256) conv1x1_k(const void* __restrict__ in, bf16* __restrict__ out,
                                                 const float* __restrict__ wt, int wstride,
                                                 const int* flagp, int mode) {
  int bf = mode ? flagp[0] : 1;
  __shared__ float vs[48 * 64];
  int t = threadIdx.x;
  int blk = blockIdx.x;                // B * 256
  int b = blk >> 8;
  int p0 = (blk & 255) << 6;
  int ibase = b * 48 * HW + p0;
  #pragma unroll
  for (int i = 0; i < 12; i++) {
    int idx = i * 256 + t;
    int c = idx >> 6, p = idx & 63;
    vs[idx] = ldx(in, ibase + c * HW + p, bf);
  }
  __syncthreads();
  int p = t & 63;
  int og = __builtin_amdgcn_readfirstlane(t >> 6);   // wave-uniform 0..3
  const float* Wcol = wt + og * 12;                  // transposed: [c*wstride + j]
  float acc[12];
  #pragma unroll
  for (int j = 0; j < 12; j++) acc[j] = 0.f;
  for (int c = 0; c < 48; c++) {
    float v = vs[c * 64 + p];
    const float* wc = Wcol + c * wstride;
    #pragma unroll
    for (int j = 0; j < 12; j++) acc[j] += wc[j] * v;
  }
  bf16* op = out + (size_t)b * 48 * HW + p0 + p;
  #pragma unroll
  for (int j = 0; j < 12; j++) op[(size_t)(og * 12 + j) * HW] = tob(acc[j]);
}

// ---- depthwise 3x3 v2: 4 px/thread, vector row loads, zero pad ----
__global__ void dw3x3_k(const bf16* __restrict__ in, bf16* __restrict__ out,
                        const float* __restrict__ w) {
  int idx4 = blockIdx.x * 256 + threadIdx.x;   // pixel-quad index
  int wq = idx4 & 31;                          // W/4 = 32
  int h = (idx4 >> 5) & (H - 1);
  int plane = idx4 >> 12;                      // b*48 + c  (HW/4 = 4096)
  int c = plane % 48;
  const bf16* p = in + (size_t)plane * HW;
  int w0 = wq << 2;
  float acc[4] = {0.f, 0.f, 0.f, 0.f};
  #pragma unroll
  for (int i = 0; i < 3; i++) {
    int hh = h + i - 1;
    if (hh < 0 || hh >= H) continue;
    const bf16* row = p + hh * W + w0;
    ushort4 u = *(const ushort4*)row;          // 8B-aligned (w0 % 4 == 0)
    float v[6];
    v[1] = u2f(u.x); v[2] = u2f(u.y); v[3] = u2f(u.z); v[4] = u2f(u.w);
    v[0] = (w0 > 0) ? ldf(row, -1) : 0.f;
    v[5] = (w0 + 4 < W) ? ldf(row, 4) : 0.f;
    #pragma unroll
    for (int j = 0; j < 3; j++) {
      float wt = w[c * 9 + i * 3 + j];
      #pragma unroll
      for (int q = 0; q < 4; q++) acc[q] += wt * v[q + j];
    }
  }
  ushort4 o;
  o.x = b2u(tob(acc[0])); o.y = b2u(tob(acc[1]));
  o.z = b2u(tob(acc[2])); o.w = b2u(tob(acc[3]));
  *(ushort4*)(out + (size_t)idx4 * 4) = o;
}

// ---- attn gram, split-L partials: grid = 32 bh * NCHUNK blocks ----
__global__ void __launch_bounds__(256) attn_part_k(const bf16* __restrict__ q,
                                                   const bf16* __restrict__ kbuf,
                                                   float* __restrict__ partial) {
  int blk = blockIdx.x;
  int bh = blk >> 6, chunk = blk & (NCHUNK - 1);
  int b = bh >> 2, hd = bh & 3;
  int t = threadIdx.x;
  int l0 = chunk * 256;
  __shared__ float qs[12 * 257], ks[12 * 257];
  const bf16* qb = q + (size_t)(b * 48 + hd * 12) * HW + l0;
  const bf16* kb = kbuf + (size_t)(b * 48 + hd * 12) * HW + l0;
  #pragma unroll
  for (int m = 0; m < 12; m++) {
    qs[m * 257 + t] = ldf(qb, m * HW + t);
    ks[m * 257 + t] = ldf(kb, m * HW + t);
  }
  __syncthreads();
  float acc = 0.f;
  if (t < 144) {
    const float* qr = qs + (t / 12) * 257;
    const float* kr = ks + (t % 12) * 257;
    #pragma unroll 4
    for (int j = 0; j < 256; j++) acc += qr[j] * kr[j];
  } else if (t < 156) {
    const float* qr = qs + (t - 144) * 257;
    #pragma unroll 4
    for (int j = 0; j < 256; j++) acc += qr[j] * qr[j];
  } else if (t < 168) {
    const float* kr = ks + (t - 156) * 257;
    #pragma unroll 4
    for (int j = 0; j < 256; j++) acc += kr[j] * kr[j];
  }
  if (t < 168) partial[(size_t)(chunk * 32 + bh) * 168 + t] = acc;
}

// ---- reduce partials + norms + softmax -> 12x12 attn per bh ----
__global__ void __launch_bounds__(256) attn_fin_k(const float* __restrict__ partial,
                                                  const float* __restrict__ temp,
                                                  float* __restrict__ attn) {
  int bh = blockIdx.x, hd = bh & 3;
  int t = threadIdx.x;
  __shared__ float red[168];
  if (t < 168) {
    float s = 0.f;
    for (int ch = 0; ch < NCHUNK; ch++) s += partial[(size_t)(ch * 32 + bh) * 168 + t];
    red[t] = s;
  }
  __syncthreads();
  if (t < 12) {
    float tm = temp[hd];
    float rq = 1.f / fmaxf(sqrtf(red[144 + t]), 1e-12f);
    float vals[12], mx = -1e30f;
    #pragma unroll
    for (int d = 0; d < 12; d++) {
      float rk = 1.f / fmaxf(sqrtf(red[156 + d]), 1e-12f);
      vals[d] = red[t * 12 + d] * rq * rk * tm;
      mx = fmaxf(mx, vals[d]);
    }
    float s = 0.f;
    #pragma unroll
    for (int d = 0; d < 12; d++) { vals[d] = expf(vals[d] - mx); s += vals[d]; }
    float inv = 1.f / s;
    float* ao = attn + (size_t)(bh * 12 + t) * 12;
    #pragma unroll
    for (int d = 0; d < 12; d++) ao[d] = vals[d] * inv;
  }
}

// ---- out = attn @ v ----
__global__ void attn_apply_k(const float* __restrict__ attn, const bf16* __restrict__ vbuf,
                             bf16* __restrict__ out) {
  int blk = blockIdx.x;
  int bh = blk >> 6, b = bh >> 2, hd = bh & 3;
  int l = ((blk & 63) << 8) + threadIdx.x;
  __shared__ float al[144];
  if (threadIdx.x < 144) al[threadIdx.x] = attn[bh * 144 + threadIdx.x];
  __syncthreads();
  const bf16* vb = vbuf + (size_t)(b * 48 + hd * 12) * HW + l;
  float vv[12];
  #pragma unroll
  for (int d = 0; d < 12; d++) vv[d] = ldf(vb, d * HW);
  bf16* ob = out + (size_t)(b * 48 + hd * 12) * HW + l;
  #pragma unroll
  for (int c = 0; c < 12; c++) {
    float s = 0.f;
    #pragma unroll
    for (int d = 0; d < 12; d++) s += al[c * 12 + d] * vv[d];
    ob[(size_t)c * HW] = tob(s);
  }
}

// ---- final v2t: 64 px/block, 4 waves x 12 outputs, transposed weights ----
__global__ void __launch_bounds__(256) conv_final_k(const bf16* __restrict__ ho,
                                                    const bf16* __restrict__ lo,
                                                    const float* __restrict__ P,
                                                    const void* __restrict__ x,
                                                    void* __restrict__ out,
                                                    const int* flagp) {
  int bf = flagp[0];
  __shared__ float vs[96 * 64];
  int t = threadIdx.x;
  int blk = blockIdx.x;                // B * 256
  int b = blk >> 8;
  int p0 = (blk & 255) << 6;
  int pbase = b * 48 * HW + p0;
  #pragma unroll
  for (int i = 0; i < 12; i++) {
    int idx = i * 256 + t;
    int c = idx >> 6, p = idx & 63;
    vs[idx] = ldf(ho, pbase + c * HW + p);
    vs[48 * 64 + idx] = ldf(lo, pbase + c * HW + p);
  }
  __syncthreads();
  int p = t & 63;
  int og = __builtin_amdgcn_readfirstlane(t >> 6);   // wave-uniform 0..3
  const float* Wcol = P + O_FPW + og * 12;           // transposed: [c*48 + j]
  float acc[12];
  #pragma unroll
  for (int j = 0; j < 12; j++) acc[j] = 0.f;
  for (int c = 0; c < 96; c++) {
    float v = vs[c * 64 + p];
    const float* wc = Wcol + c * 48;
    #pragma unroll
    for (int j = 0; j < 12; j++) acc[j] += wc[j] * v;
  }
  #pragma unroll
  for (int j = 0; j < 12; j++) {
    int o = og * 12 + j;
    int oi = pbase + o * HW + p;
    float val = acc[j] + P[O_FPB + o] + ldx(x, oi, bf);
    if (bf) ((bf16*)out)[oi] = tob(val);
    else    ((float*)out)[oi] = val;
  }
}

extern "C" void kernel_launch(void* const* d_in, const int* in_sizes, int n_in,
                              void* d_out, int out_size, void* d_ws, size_t ws_size,
                              hipStream_t stream) {
  const void* x = d_in[0];

  // ws layout (fp32 units): ap@0, wts@512, attnm@2048, flag@7000,
  // params@8192 (ends 47224), partials@49152 (64*32*168 -> ends 393216),
  // bf16 planes @400000
  float* ws    = (float*)d_ws;
  float* ap    = ws;
  float* wts   = ws + 512;
  float* attnm = ws + 2048;
  int*   flagp = (int*)(ws + 7000);
  float* P     = ws + 8192;
  float* parts = ws + 49152;
  bf16* base = (bf16*)(ws + 400000);
  bf16* HF = base;
  bf16* LF = base + (size_t)NCHW;
  bf16* T  = base + (size_t)2 * NCHW;
  bf16* Q  = base + (size_t)3 * NCHW;
  bf16* K  = base + (size_t)4 * NCHW;
  float* spec = (float*)T;

  // ---- dtype detect + param convert (matmul weights transposed) ----
  detect_k<<<1, 256, 0, stream>>>(x, flagp);
  ParamTab tab;
  const int offs[25] = {O_FDW, O_BNG, O_BNB, O_BNM, O_BNV,
                        O_FHW1, O_FHB1, O_FHW2, O_FHB2,
                        O_FLW, O_FLB,
                        O_HQW, O_HKVW, O_HQDW, O_HKVDW, O_HPW, O_HT,
                        O_LQW, O_LKVW, O_LQDW, O_LKVDW, O_LPW, O_LT,
                        O_FPW, O_FPB};
  const int cnts[25] = {3456, 72, 72, 72, 72,
                        144, 48, 144, 48,
                        9216, 96,
                        2304, 4608, 432, 864, 2304, 4,
                        2304, 4608, 432, 864, 2304, 4,
                        4608, 48};
  const int rows[25] = {0, 0, 0, 0, 0,
                        0, 0, 0, 0,
                        96, 0,
                        48, 96, 0, 0, 48, 0,
                        48, 96, 0, 0, 48, 0,
                        48, 0};
  for (int i = 0; i < 25; i++) {
    tab.src[i] = d_in[i + 1]; tab.off[i] = offs[i]; tab.cnt[i] = cnts[i]; tab.rows[i] = rows[i];
  }
  cvt_params_k<<<25, 256, 0, stream>>>(tab, flagp, P);

  // ---- fd ----
  reduce_mean_k<<<B * C, 256, 0, stream>>>(x, ap, flagp);
  fd_weights_k<<<B, 128, 0, stream>>>(ap, P, wts);
  fd_apply_k<<<NCHW / 1024, 256, 0, stream>>>(x, wts, LF, Q, flagp);  // low->LF, high->Q
  // ---- fmgm_high ----
  fmgm_high_k<<<NCHW / 1024, 256, 0, stream>>>(Q, P, HF);             // hf->HF
  // ---- fmgm_low: rfft2 -> gate -> irfft2 ----
  rfft_row_k<<<B * C * H / 4, 256, 0, stream>>>(LF, spec);
  fft_col_k<<<B * C * 2, 256, 0, stream>>>(spec, -1.f, 1.f);
  freq_gate_k<<<B * (SPECHW / 64), 256, 0, stream>>>(spec, P);
  fft_col_k<<<B * C * 2, 256, 0, stream>>>(spec, 1.f, 1.f / 128.f);
  irfft_row_k<<<B * C * H / 4, 256, 0, stream>>>(spec, LF);           // lf->LF
  // ---- fga (high branch: freq = hf in HF) ----
  conv1x1_k<<<B * 256, 256, 0, stream>>>(HF, T, P + O_HQW, 48, flagp, 0);
  dw3x3_k<<<NCHW / 1024, 256, 0, stream>>>(T, Q, P + O_HQDW);         // q->Q (high dead)
  conv1x1_k<<<B * 256, 256, 0, stream>>>(x, T, P + O_HKVW, 96, flagp, 1);
  dw3x3_k<<<NCHW / 1024, 256, 0, stream>>>(T, K, P + O_HKVDW);        // k->K
  conv1x1_k<<<B * 256, 256, 0, stream>>>(x, T, P + O_HKVW + 48, 96, flagp, 1);
  dw3x3_k<<<NCHW / 1024, 256, 0, stream>>>(T, HF, P + O_HKVDW + 48 * 9); // v->HF (hf dead)
  attn_part_k<<<32 * NCHUNK, 256, 0, stream>>>(Q, K, parts);
  attn_fin_k<<<32, 256, 0, stream>>>(parts, P + O_HT, attnm);
  attn_apply_k<<<B * 4 * 64, 256, 0, stream>>>(attnm, HF, K);         // attnout->K (k dead)
  conv1x1_k<<<B * 256, 256, 0, stream>>>(K, Q, P + O_HPW, 48, flagp, 0);  // ho->Q (q dead)
  // ---- fga (low branch: freq = lf in LF) ----
  conv1x1_k<<<B * 256, 256, 0, stream>>>(LF, T, P + O_LQW, 48, flagp, 0);
  dw3x3_k<<<NCHW / 1024, 256, 0, stream>>>(T, HF, P + O_LQDW);        // q->HF
  conv1x1_k<<<B * 256, 256, 0, stream>>>(x, T, P + O_LKVW, 96, flagp, 1);
  dw3x3_k<<<NCHW / 1024, 256, 0, stream>>>(T, K, P + O_LKVDW);        // k->K
  conv1x1_k<<<B * 256, 256, 0, stream>>>(x, T, P + O_LKVW + 48, 96, flagp, 1);
  dw3x3_k<<<NCHW / 1024, 256, 0, stream>>>(T, LF, P + O_LKVDW + 48 * 9); // v->LF (lf dead)
  attn_part_k<<<32 * NCHUNK, 256, 0, stream>>>(HF, K, parts);
  attn_fin_k<<<32, 256, 0, stream>>>(parts, P + O_LT, attnm);
  attn_apply_k<<<B * 4 * 64, 256, 0, stream>>>(attnm, LF, K);         // attnout->K
  conv1x1_k<<<B * 256, 256, 0, stream>>>(K, T, P + O_LPW, 48, flagp, 0);  // lo->T
  // ---- final 1x1 + bias + residual ----
  conv_final_k<<<B * 256, 256, 0, stream>>>(Q, T, P, x, d_out, flagp);
}

// Round 6
// 598.349 us; speedup vs baseline: 1.6866x; 1.0817x over previous
//
#include <hip/hip_runtime.h>
#include <hip/hip_bf16.h>
#include <math.h>

using bf16 = __hip_bfloat16;
#define DI __device__ __forceinline__

namespace {
constexpr int B = 8, C = 48, H = 128, W = 128;
constexpr int HW = H * W;                 // 16384
constexpr int NCHW = B * C * HW;          // 6,291,456
constexpr int C2 = 96;
constexpr int WF = 65;                    // rfft width
constexpr int SPECHW = H * WF;            // 8320 (divisible by 64)
constexpr int SPECN = B * C2 * SPECHW;    // 6,389,760 floats
// spec (fp32) overlays planes P2+P3+P4 = 3*NCHW bf16 slots
static_assert((size_t)SPECN * 4 <= (size_t)3 * NCHW * 2, "spec must fit in P2..P4 overlay");
static_assert(SPECHW % 64 == 0, "freq_gate 64-pixel blocks must not straddle batches");

// fp32 param header offsets (in floats), base = ws + 8192
// NOTE: matmul weights (FLW, *QW, *KVW, *PW, FPW) are stored TRANSPOSED
// (input-major): wt[c*rows + o]. Depthwise/BN/bias params stay plain.
constexpr int O_FDW = 0,    O_BNG = 3456, O_BNB = 3528, O_BNM = 3600, O_BNV = 3672;
constexpr int O_FHW1 = 3744, O_FHB1 = 3888, O_FHW2 = 3936, O_FHB2 = 3984;
constexpr int O_FLW = 4032,  O_FLB = 13248;
constexpr int O_HQW = 13344, O_HKVW = 15648, O_HQDW = 20256, O_HKVDW = 20688, O_HPW = 21552, O_HT = 23856;
constexpr int O_LQW = 23860, O_LKVW = 26164, O_LQDW = 30772, O_LKVDW = 31204, O_LPW = 32068, O_LT = 34372;
constexpr int O_FPW = 34376, O_FPB = 38984;  // end 39032

constexpr int NCHUNK = 64;                // L split for attn gram
}

DI float ldf(const float* p, int i) { return p[i]; }
DI float ldf(const bf16* p, int i) { return __bfloat162float(p[i]); }
DI bf16 tob(float x) { return __float2bfloat16(x); }
DI unsigned short b2u(bf16 v) { union { bf16 b; unsigned short u; } x; x.b = v; return x.u; }
DI float u2f(unsigned short u) { return __uint_as_float((unsigned)u << 16); }
DI float ldx(const void* p, int i, int bf) {
  return bf ? __bfloat162float(((const bf16*)p)[i]) : ((const float*)p)[i];
}
DI float geluf(float x) { return 0.5f * x * (1.f + erff(x * 0.70710678118654752f)); }
DI int refl(int i, int n) { return i < 0 ? -i : (i >= n ? 2 * n - 2 - i : i); }

// ---- dtype detector: bf16 data -> even u16 slots have sane exponents ----
__global__ void detect_k(const void* x, int* flagp) {
  const unsigned short* u = (const unsigned short*)x;
  int t = threadIdx.x;
  int good = 0;
  for (int i = t; i < 1024; i += 256) {
    unsigned short v = u[2 * i];
    int e = (v >> 7) & 0xFF;
    if (e >= 100 && e <= 140) good++;
  }
  __shared__ int cnt;
  if (t == 0) cnt = 0;
  __syncthreads();
  atomicAdd(&cnt, good);
  __syncthreads();
  if (t == 0) flagp[0] = (cnt > 512) ? 1 : 0;
}

// ---- convert all params to fp32 header; matmul weights transposed ----
// rows[b] == 0: plain copy. rows[b] = R (out-channels of original [R][cols]):
// dst[(i%cols)*R + i/cols] = src[i]  -> input-major wt[c*R + o].
struct ParamTab { const void* src[25]; int off[25]; int cnt[25]; int rows[25]; };
__global__ void cvt_params_k(ParamTab tab, const int* flagp, float* dst) {
  int bf = flagp[0];
  int b = blockIdx.x;
  const void* s = tab.src[b];
  float* d = dst + tab.off[b];
  int n = tab.cnt[b];
  int rows = tab.rows[b];
  if (rows == 0) {
    for (int i = threadIdx.x; i < n; i += 256) d[i] = ldx(s, i, bf);
  } else {
    int cols = n / rows;
    for (int i = threadIdx.x; i < n; i += 256)
      d[(i % cols) * rows + (i / cols)] = ldx(s, i, bf);
  }
}

// ---- fd: channel means, v2: vector loads ----
__global__ void reduce_mean_k(const void* __restrict__ x, float* __restrict__ ap,
                              const int* flagp) {
  int bf = flagp[0];
  int bc = blockIdx.x;
  float s = 0.f;
  if (bf) {
    const ushort4* xp = (const ushort4*)((const bf16*)x + (size_t)bc * HW);
    for (int i = threadIdx.x; i < HW / 4; i += 256) {
      ushort4 u = xp[i];
      s += u2f(u.x) + u2f(u.y) + u2f(u.z) + u2f(u.w);
    }
  } else {
    const float4* xp = (const float4*)((const float*)x + (size_t)bc * HW);
    for (int i = threadIdx.x; i < HW / 4; i += 256) {
      float4 u = xp[i];
      s += u.x + u.y + u.z + u.w;
    }
  }
  #pragma unroll
  for (int o = 32; o > 0; o >>= 1) s += __shfl_down(s, o);
  __shared__ float r[4];
  if ((threadIdx.x & 63) == 0) r[threadIdx.x >> 6] = s;
  __syncthreads();
  if (threadIdx.x == 0) ap[bc] = (r[0] + r[1] + r[2] + r[3]) * (1.f / HW);
}

// ---- fd: 72-wide linear + BN + per-group softmax over 9 ----
__global__ void fd_weights_k(const float* __restrict__ ap, const float* __restrict__ P,
                             float* __restrict__ wts) {
  int n = blockIdx.x, t = threadIdx.x;
  __shared__ float vals[72], es[72];
  if (t < 72) {
    float acc = 0.f;
    for (int c = 0; c < C; c++) acc += P[O_FDW + t * C + c] * ap[n * C + c];
    acc = (acc - P[O_BNM + t]) * rsqrtf(P[O_BNV + t] + 1e-5f);
    vals[t] = acc * P[O_BNG + t] + P[O_BNB + t];
  }
  __syncthreads();
  if (t < 72) {
    int base = (t / 9) * 9;
    float mx = -1e30f;
    for (int k = 0; k < 9; k++) mx = fmaxf(mx, vals[base + k]);
    es[t] = expf(vals[t] - mx);
  }
  __syncthreads();
  if (t < 72) {
    int base = (t / 9) * 9;
    float s = 0.f;
    for (int k = 0; k < 9; k++) s += es[base + k];
    wts[n * 72 + t] = es[t] / s;
  }
}

// ---- fd v2: involution low-pass (reflect pad), 4 px/thread, vector rows ----
// reflect at W-edges picks in-register: refl(-1)=1 -> v[2], refl(W)=W-2 -> v[3]
__global__ void fd_apply_k(const void* __restrict__ x, const float* __restrict__ wts,
                           bf16* __restrict__ low, bf16* __restrict__ high,
                           const int* flagp) {
  int bf = flagp[0];
  int idx4 = blockIdx.x * 256 + threadIdx.x;   // quad index over NCHW/4
  int w0 = (idx4 & 31) << 2;                   // W/4 = 32
  int h = (idx4 >> 5) & (H - 1);
  int plane = idx4 >> 12;                      // b*C + c
  int c = plane % C;
  int b = plane / C;
  const float* wt = wts + b * 72 + (c / 6) * 9;
  size_t pbase = (size_t)plane * HW;
  float acc[4] = {0.f, 0.f, 0.f, 0.f};
  float ctr[4];
  #pragma unroll
  for (int i = 0; i < 3; i++) {
    int hh = refl(h + i - 1, H);
    float v[6];
    if (bf) {
      const bf16* row = (const bf16*)x + pbase + hh * W + w0;
      ushort4 u = *(const ushort4*)row;        // 8B aligned
      v[1] = u2f(u.x); v[2] = u2f(u.y); v[3] = u2f(u.z); v[4] = u2f(u.w);
      v[0] = (w0 > 0) ? ldf(row, -1) : v[2];
      v[5] = (w0 + 4 < W) ? ldf(row, 4) : v[3];
    } else {
      const float* row = (const float*)x + pbase + hh * W + w0;
      float4 u = *(const float4*)row;          // 16B aligned
      v[1] = u.x; v[2] = u.y; v[3] = u.z; v[4] = u.w;
      v[0] = (w0 > 0) ? row[-1] : v[2];
      v[5] = (w0 + 4 < W) ? row[4] : v[3];
    }
    if (i == 1) { ctr[0] = v[1]; ctr[1] = v[2]; ctr[2] = v[3]; ctr[3] = v[4]; }
    #pragma unroll
    for (int j = 0; j < 3; j++) {
      float wv = wt[i * 3 + j];
      #pragma unroll
      for (int q = 0; q < 4; q++) acc[q] += wv * v[q + j];
    }
  }
  ushort4 ol, oh;
  ol.x = b2u(tob(acc[0])); ol.y = b2u(tob(acc[1]));
  ol.z = b2u(tob(acc[2])); ol.w = b2u(tob(acc[3]));
  oh.x = b2u(tob(ctr[0] - acc[0])); oh.y = b2u(tob(ctr[1] - acc[1]));
  oh.z = b2u(tob(ctr[2] - acc[2])); oh.w = b2u(tob(ctr[3] - acc[3]));
  *(ushort4*)(low + (size_t)idx4 * 4) = ol;
  *(ushort4*)(high + (size_t)idx4 * 4) = oh;
}

// ---- fmgm_high v2: fused (1x3)->(3x1) dwconv -> gelu * x, 4 px/thread ----
__global__ void fmgm_high_k(const bf16* __restrict__ hi, const float* __restrict__ P,
                            bf16* __restrict__ out) {
  int idx4 = blockIdx.x * 256 + threadIdx.x;   // quad index over NCHW/4
  int w0 = (idx4 & 31) << 2;
  int h = (idx4 >> 5) & (H - 1);
  int plane = idx4 >> 12;
  int c = plane % C;
  const bf16* p = hi + (size_t)plane * HW;
  float k1[3], k2[3];
  #pragma unroll
  for (int j = 0; j < 3; j++) { k1[j] = P[O_FHW1 + c * 3 + j]; k2[j] = P[O_FHW2 + c * 3 + j]; }
  float b1 = P[O_FHB1 + c];
  float b2 = P[O_FHB2 + c];
  float acc[4] = {b2, b2, b2, b2};
  float ctr[4];
  #pragma unroll
  for (int i = 0; i < 3; i++) {
    int hh = h + i - 1;
    if (hh < 0 || hh >= H) continue;
    const bf16* row = p + hh * W + w0;
    ushort4 u = *(const ushort4*)row;          // 8B aligned
    float v[6];
    v[1] = u2f(u.x); v[2] = u2f(u.y); v[3] = u2f(u.z); v[4] = u2f(u.w);
    v[0] = (w0 > 0) ? ldf(row, -1) : 0.f;      // zero pad
    v[5] = (w0 + 4 < W) ? ldf(row, 4) : 0.f;
    if (i == 1) { ctr[0] = v[1]; ctr[1] = v[2]; ctr[2] = v[3]; ctr[3] = v[4]; }
    float kk = k2[i];
    #pragma unroll
    for (int q = 0; q < 4; q++) {
      float y1 = b1 + k1[0] * v[q] + k1[1] * v[q + 1] + k1[2] * v[q + 2];
      acc[q] += kk * y1;
    }
  }
  ushort4 o;
  o.x = b2u(tob(geluf(acc[0]) * ctr[0]));
  o.y = b2u(tob(geluf(acc[1]) * ctr[1]));
  o.z = b2u(tob(geluf(acc[2]) * ctr[2]));
  o.w = b2u(tob(geluf(acc[3]) * ctr[3]));
  *(ushort4*)(out + (size_t)idx4 * 4) = o;
}

// ---- rfft along W, v3: lane-parallel radix-2 FFT64 (shuffle butterflies) ----
__global__ void __launch_bounds__(256) rfft_row_k(const bf16* __restrict__ low,
                                                  float* __restrict__ spec) {
  int t = threadIdx.x;
  int wid = t >> 6, l = t & 63;
  int row = blockIdx.x * 4 + wid;        // in [0, B*C*H)
  int h = row & (H - 1);
  int bc = row >> 7;
  int c = bc % C, b = bc / C;
  const unsigned* xr = (const unsigned*)(low + (size_t)row * W);
  unsigned v2 = xr[l];                   // two bf16: elems 2l, 2l+1
  float zr = __uint_as_float(v2 << 16);
  float zi = __uint_as_float(v2 & 0xFFFF0000u);
  #pragma unroll
  for (int s = 0; s < 6; s++) {
    int d = 32 >> s;
    float pr = __shfl_xor(zr, d);
    float pi = __shfl_xor(zi, d);
    float a = (float)(l & (d - 1)) / (float)d;
    float wr = cospif(a), wi = -sinpif(a);
    float sr = zr + pr, si = zi + pi;
    float dr = pr - zr, di = pi - zi;
    float mr2 = dr * wr - di * wi;
    float mi2 = dr * wi + di * wr;
    bool hib = (l & d) != 0;
    zr = hib ? mr2 : sr;
    zi = hib ? mi2 : si;
  }
  int rl = __brev(l) >> 26;
  int lm = (64 - l) & 63;
  int rm = __brev(lm) >> 26;
  float Zkr = __shfl(zr, rl), Zki = __shfl(zi, rl);
  float Zmr = __shfl(zr, rm), Zmi = __shfl(zi, rm);
  float Fer = 0.5f * (Zkr + Zmr), Fei = 0.5f * (Zki - Zmi);
  float Dr  = 0.5f * (Zkr - Zmr), Di  = 0.5f * (Zki + Zmi);
  float For = Di, Foi = -Dr;             // D / i
  float a = (float)l * (1.f / 64.f);
  float tr = cospif(a), ti = -sinpif(a); // e^{-2 pi i l / 128}
  float Xr = Fer + tr * For - ti * Foi;
  float Xi = Fei + tr * Foi + ti * For;
  size_t o = ((size_t)(b * C2 + c) * H + h) * WF + l;
  size_t ioff = (size_t)C * H * WF;
  spec[o] = Xr;
  spec[o + ioff] = Xi;
  if (l == 0) {                          // k = 64 (Nyquist)
    spec[o + 64] = Fer - For;
    spec[o + 64 + ioff] = 0.f;
  }
}

// ---- complex FFT-128 along H, v6: lane-parallel radix-2, LDS tile ----
__global__ void __launch_bounds__(256) fft_col_k(float* __restrict__ spec,
                                                 float sgn, float scale) {
  __shared__ float re_s[128 * 33], im_s[128 * 33];   // 33.8 KB, stride 33
  int t = threadIdx.x;
  int half = blockIdx.x & 1;
  int bc = blockIdx.x >> 1;
  int cc = bc % C, b = bc / C;
  size_t reb = ((size_t)(b * C2 + cc) * H) * WF;
  size_t imb = reb + (size_t)C * H * WF;
  int ncol = half ? 33 : 32;
  if (half == 0) {
    #pragma unroll
    for (int i = 0; i < 16; i++) {
      int idx = i * 256 + t;             // 4096 = 128*32
      int r = idx >> 5, c = idx & 31;
      re_s[r * 33 + c] = spec[reb + r * WF + c];
      im_s[r * 33 + c] = spec[imb + r * WF + c];
    }
  } else {
    #pragma unroll
    for (int i = 0; i < 17; i++) {
      int idx = i * 256 + t;             // 4352 >= 128*33
      if (idx < 128 * 33) {
        int r = idx / 33, c = idx - r * 33;
        re_s[r * 33 + c] = spec[reb + r * WF + 32 + c];
        im_s[r * 33 + c] = spec[imb + r * WF + 32 + c];
      }
    }
  }
  __syncthreads();
  int w = t >> 6, l = t & 63;
  float cA = cospif((float)l * (1.f / 64.f));
  float sA = sinpif((float)l * (1.f / 64.f)) * sgn;  // e^{sgn*2pi i l/128}
  float cs[6], ss[6];
  #pragma unroll
  for (int s = 0; s < 6; s++) {
    int d = 32 >> s;
    float a = (float)(l & (d - 1)) / (float)d;
    cs[s] = cospif(a); ss[s] = sinpif(a) * sgn;
  }
  int br = __brev(l) >> 26;
  for (int c = w; c < ncol; c += 4) {
    float ar = re_s[l * 33 + c],         ai = im_s[l * 33 + c];
    float xr = re_s[(l + 64) * 33 + c],  xi = im_s[(l + 64) * 33 + c];
    float ur = ar + xr, ui = ai + xi;                // -> even freqs
    float tr = ar - xr, ti = ai - xi;
    float vr = tr * cA - ti * sA;                    // -> odd freqs
    float vi = tr * sA + ti * cA;
    #pragma unroll
    for (int s = 0; s < 6; s++) {
      int d = 32 >> s;
      float pr = __shfl_xor(ur, d), pi = __shfl_xor(ui, d);
      float qr = __shfl_xor(vr, d), qi = __shfl_xor(vi, d);
      float sur = ur + pr, sui = ui + pi;
      float dur = pr - ur, dui = pi - ui;
      float svr = vr + qr, svi = vi + qi;
      float dvr = qr - vr, dvi = qi - vi;
      float mur = dur * cs[s] - dui * ss[s];
      float mui = dur * ss[s] + dui * cs[s];
      float mvr = dvr * cs[s] - dvi * ss[s];
      float mvi = dvr * ss[s] + dvi * cs[s];
      bool hib = (l & d) != 0;
      ur = hib ? mur : sur; ui = hib ? mui : sui;
      vr = hib ? mvr : svr; vi = hib ? mvi : svi;
    }
    int r0 = 2 * br;                     // X[2*br] = U-res, X[2*br+1] = V-res
    re_s[r0 * 33 + c] = ur * scale;       im_s[r0 * 33 + c] = ui * scale;
    re_s[(r0 + 1) * 33 + c] = vr * scale; im_s[(r0 + 1) * 33 + c] = vi * scale;
  }
  __syncthreads();
  if (half == 0) {
    #pragma unroll
    for (int i = 0; i < 16; i++) {
      int idx = i * 256 + t;
      int r = idx >> 5, c = idx & 31;
      spec[reb + r * WF + c] = re_s[r * 33 + c];
      spec[imb + r * WF + c] = im_s[r * 33 + c];
    }
  } else {
    #pragma unroll
    for (int i = 0; i < 17; i++) {
      int idx = i * 256 + t;
      if (idx < 128 * 33) {
        int r = idx / 33, c = idx - r * 33;
        spec[reb + r * WF + 32 + c] = re_s[r * 33 + c];
        spec[imb + r * WF + 32 + c] = im_s[r * 33 + c];
      }
    }
  }
}

// ---- freq-domain channel-mix gate: yf *= gelu(W yf + b) ----
__global__ void __launch_bounds__(256) freq_gate_k(float* __restrict__ spec,
                                                   const float* __restrict__ P) {
  __shared__ float vs[96 * 65];
  int t = threadIdx.x;
  int blk = blockIdx.x;
  int b = blk / (SPECHW / 64);
  int pp0 = (blk % (SPECHW / 64)) * 64;
  float* sb = spec + (size_t)b * C2 * SPECHW + pp0;
  #pragma unroll
  for (int i = 0; i < 24; i++) {
    int idx = i * 256 + t;
    int c = idx >> 6, p = idx & 63;
    vs[c * 65 + p] = sb[(size_t)c * SPECHW + p];
  }
  __syncthreads();
  int p = t & 63;
  int og = __builtin_amdgcn_readfirstlane(t >> 6);   // wave-uniform 0..3
  const float* Wcol = P + O_FLW + og * 24;           // transposed: [c*96 + j]
  float acc[24];
  #pragma unroll
  for (int j = 0; j < 24; j++) acc[j] = 0.f;
  for (int c = 0; c < 96; c++) {
    float vv = vs[c * 65 + p];
    const float* wc = Wcol + c * 96;
    #pragma unroll
    for (int j = 0; j < 24; j++) acc[j] += wc[j] * vv;
  }
  #pragma unroll
  for (int j = 0; j < 24; j++) {
    int o = og * 24 + j;
    float g = geluf(acc[j] + P[O_FLB + o]);
    sb[(size_t)o * SPECHW + p] = vs[o * 65 + p] * g;
  }
}

// ---- irfft along W, v3: Hermitian pack + lane-parallel inverse FFT64 ----
__global__ void __launch_bounds__(256) irfft_row_k(const float* __restrict__ spec,
                                                   bf16* __restrict__ out) {
  int t = threadIdx.x;
  int wid = t >> 6, l = t & 63;
  int row = blockIdx.x * 4 + wid;        // in [0, B*C*H)
  int h = row & (H - 1);
  int bc = row >> 7;
  int c = bc % C, b = bc / C;
  size_t rb = ((size_t)(b * C2 + c) * H + h) * WF;
  size_t ioff = (size_t)C * H * WF;
  float xr = spec[rb + l];
  float xi = (l == 0) ? 0.f : spec[rb + ioff + l];   // C2R: ignore DC imag
  float r64 = spec[rb + 64];                         // Nyquist (real used only)
  int lm = (64 - l) & 63;
  float mr = __shfl(xr, lm);
  float mi = __shfl(xi, lm);
  if (l == 0) { mr = r64; mi = 0.f; }                // X[64] for the k=0 pair
  float Fer = 0.5f * (xr + mr), Fei = 0.5f * (xi - mi);
  float Dr  = 0.5f * (xr - mr), Di  = 0.5f * (xi + mi);
  float a = (float)l * (1.f / 64.f);
  float tr = cospif(a), ti = sinpif(a);              // e^{+2 pi i l / 128}
  float For = tr * Dr - ti * Di;
  float Foi = tr * Di + ti * Dr;
  float zr = Fer - Foi, zi = Fei + For;              // Z = Fe + i*Fo
  #pragma unroll
  for (int s = 0; s < 6; s++) {
    int d = 32 >> s;
    float pr = __shfl_xor(zr, d);
    float pi = __shfl_xor(zi, d);
    float aa = (float)(l & (d - 1)) / (float)d;
    float wr = cospif(aa), wi = sinpif(aa);
    float sr = zr + pr, si = zi + pi;
    float dr = pr - zr, di = pi - zi;
    float mr2 = dr * wr - di * wi;
    float mi2 = dr * wi + di * wr;
    bool hib = (l & d) != 0;
    zr = hib ? mr2 : sr;
    zi = hib ? mi2 : si;
  }
  int m = __brev(l) >> 26;               // lane holds u[m]
  unsigned p0 = b2u(tob(zr * (1.f / 64.f)));
  unsigned p1 = b2u(tob(zi * (1.f / 64.f)));
  ((unsigned*)(out + (size_t)row * W))[m] = p0 | (p1 << 16);
}

// ---- 1x1 conv v3t: 64 px/block, 4 waves x 12 outputs, transposed weights ----
// wt[c*wstride + o]; perb: weights at wt + b*2304 (per-batch fused attn@proj).
// mode 1: input is the external x (flag-dtyped); mode 0: internal bf16
__global__ void __launch_bounds__(256) conv1x1_k(const void* __restrict__ in, bf16* __restrict__ out,
                                                 const float* __restrict__ wt, int wstride,
                                                 const int* flagp, int mode, int perb) {
  int bf = mode ? flagp[0] : 1;
  __shared__ float vs[48 * 64];
  int t = threadIdx.x;
  int blk = blockIdx.x;                // B * 256
  int b = blk >> 8;
  int p0 = (blk & 255) << 6;
  int ibase = b * 48 * HW + p0;
  #pragma unroll
  for (int i = 0; i < 12; i++) {
    int idx = i * 256 + t;
    int c = idx >> 6, p = idx & 63;
    vs[idx] = ldx(in, ibase + c * HW + p, bf);
  }
  __syncthreads();
  int p = t & 63;
  int og = __builtin_amdgcn_readfirstlane(t >> 6);   // wave-uniform 0..3
  const float* Wcol = wt + (perb ? b * 2304 : 0) + og * 12;
  float acc[12];
  #pragma unroll
  for (int j = 0; j < 12; j++) acc[j] = 0.f;
  for (int c = 0; c < 48; c++) {
    float v = vs[c * 64 + p];
    const float* wc = Wcol + c * wstride;
    #pragma unroll
    for (int j = 0; j < 12; j++) acc[j] += wc[j] * v;
  }
  bf16* op = out + (size_t)b * 48 * HW + p0 + p;
  #pragma unroll
  for (int j = 0; j < 12; j++) op[(size_t)(og * 12 + j) * HW] = tob(acc[j]);
}

// ---- fused x->KV conv: one x staging, 192 outputs (HK/HV/LK/LV) ----
// wave og: og0=HKVW[:,0:48]->o0, og1=HKVW[:,48:96]->o1, og2=LKVW[:,0:48]->o2,
// og3=LKVW[:,48:96]->o3 (all transposed, stride 96).
__global__ void __launch_bounds__(256) convxkv_k(const void* __restrict__ in,
                                                 bf16* __restrict__ o0, bf16* __restrict__ o1,
                                                 bf16* __restrict__ o2, bf16* __restrict__ o3,
                                                 const float* __restrict__ P,
                                                 const int* flagp) {
  int bf = flagp[0];
  __shared__ float vs[48 * 64];
  int t = threadIdx.x;
  int blk = blockIdx.x;                // B * 256
  int b = blk >> 8;
  int p0 = (blk & 255) << 6;
  int ibase = b * 48 * HW + p0;
  #pragma unroll
  for (int i = 0; i < 12; i++) {
    int idx = i * 256 + t;
    int c = idx >> 6, p = idx & 63;
    vs[idx] = ldx(in, ibase + c * HW + p, bf);
  }
  __syncthreads();
  int p = t & 63;
  int og = __builtin_amdgcn_readfirstlane(t >> 6);   // wave-uniform 0..3
  const float* Wcol = P + (og < 2 ? O_HKVW : O_LKVW) + (og & 1) * 48;
  bf16* ob = (og == 0 ? o0 : og == 1 ? o1 : og == 2 ? o2 : o3);
  bf16* op = ob + (size_t)b * 48 * HW + p0 + p;
  float acc[48];
  #pragma unroll
  for (int j = 0; j < 48; j++) acc[j] = 0.f;
  for (int c = 0; c < 48; c++) {
    float v = vs[c * 64 + p];
    const float* wc = Wcol + c * 96;
    #pragma unroll
    for (int j = 0; j < 48; j++) acc[j] += wc[j] * v;
  }
  #pragma unroll
  for (int j = 0; j < 48; j++) op[(size_t)j * HW] = tob(acc[j]);
}

// ---- depthwise 3x3 v2: 4 px/thread, vector row loads, zero pad ----
DI void dw_quad(const bf16* __restrict__ p, const float* __restrict__ w,
                int c, int h, int w0, float acc[4]) {
  #pragma unroll
  for (int i = 0; i < 3; i++) {
    int hh = h + i - 1;
    if (hh < 0 || hh >= H) continue;
    const bf16* row = p + hh * W + w0;
    ushort4 u = *(const ushort4*)row;          // 8B-aligned (w0 % 4 == 0)
    float v[6];
    v[1] = u2f(u.x); v[2] = u2f(u.y); v[3] = u2f(u.z); v[4] = u2f(u.w);
    v[0] = (w0 > 0) ? ldf(row, -1) : 0.f;
    v[5] = (w0 + 4 < W) ? ldf(row, 4) : 0.f;
    #pragma unroll
    for (int j = 0; j < 3; j++) {
      float wt = w[c * 9 + i * 3 + j];
      #pragma unroll
      for (int q = 0; q < 4; q++) acc[q] += wt * v[q + j];
    }
  }
}

__global__ void dw3x3_k(const bf16* __restrict__ in, bf16* __restrict__ out,
                        const float* __restrict__ w) {
  int idx4 = blockIdx.x * 256 + threadIdx.x;   // pixel-quad index
  int wq = idx4 & 31;                          // W/4 = 32
  int h = (idx4 >> 5) & (H - 1);
  int plane = idx4 >> 12;                      // b*48 + c  (HW/4 = 4096)
  int c = plane % 48;
  int w0 = wq << 2;
  float acc[4] = {0.f, 0.f, 0.f, 0.f};
  dw_quad(in + (size_t)plane * HW, w, c, h, w0, acc);
  ushort4 o;
  o.x = b2u(tob(acc[0])); o.y = b2u(tob(acc[1]));
  o.z = b2u(tob(acc[2])); o.w = b2u(tob(acc[3]));
  *(ushort4*)(out + (size_t)idx4 * 4) = o;
}

// ---- paired depthwise 3x3: two independent plane sets, one launch ----
__global__ void dw3x3x2_k(const bf16* __restrict__ in1, bf16* __restrict__ out1,
                          const bf16* __restrict__ in2, bf16* __restrict__ out2,
                          const float* __restrict__ w1, const float* __restrict__ w2) {
  int idx4 = blockIdx.x * 256 + threadIdx.x;
  int wq = idx4 & 31;
  int h = (idx4 >> 5) & (H - 1);
  int plane = idx4 >> 12;
  int c = plane % 48;
  int w0 = wq << 2;
  float a1[4] = {0.f, 0.f, 0.f, 0.f};
  dw_quad(in1 + (size_t)plane * HW, w1, c, h, w0, a1);
  ushort4 o1;
  o1.x = b2u(tob(a1[0])); o1.y = b2u(tob(a1[1]));
  o1.z = b2u(tob(a1[2])); o1.w = b2u(tob(a1[3]));
  *(ushort4*)(out1 + (size_t)idx4 * 4) = o1;
  float a2[4] = {0.f, 0.f, 0.f, 0.f};
  dw_quad(in2 + (size_t)plane * HW, w2, c, h, w0, a2);
  ushort4 o2;
  o2.x = b2u(tob(a2[0])); o2.y = b2u(tob(a2[1]));
  o2.z = b2u(tob(a2[2])); o2.w = b2u(tob(a2[3]));
  *(ushort4*)(out2 + (size_t)idx4 * 4) = o2;
}

// ---- attn gram, split-L partials: grid = 32 bh * NCHUNK blocks ----
__global__ void __launch_bounds__(256) attn_part_k(const bf16* __restrict__ q,
                                                   const bf16* __restrict__ kbuf,
                                                   float* __restrict__ partial) {
  int blk = blockIdx.x;
  int bh = blk >> 6, chunk = blk & (NCHUNK - 1);
  int b = bh >> 2, hd = bh & 3;
  int t = threadIdx.x;
  int l0 = chunk * 256;
  __shared__ float qs[12 * 257], ks[12 * 257];
  const bf16* qb = q + (size_t)(b * 48 + hd * 12) * HW + l0;
  const bf16* kb = kbuf + (size_t)(b * 48 + hd * 12) * HW + l0;
  #pragma unroll
  for (int m = 0; m < 12; m++) {
    qs[m * 257 + t] = ldf(qb, m * HW + t);
    ks[m * 257 + t] = ldf(kb, m * HW + t);
  }
  __syncthreads();
  float acc = 0.f;
  if (t < 144) {
    const float* qr = qs + (t / 12) * 257;
    const float* kr = ks + (t % 12) * 257;
    #pragma unroll 4
    for (int j = 0; j < 256; j++) acc += qr[j] * kr[j];
  } else if (t < 156) {
    const float* qr = qs + (t - 144) * 257;
    #pragma unroll 4
    for (int j = 0; j < 256; j++) acc += qr[j] * qr[j];
  } else if (t < 168) {
    const float* kr = ks + (t - 156) * 257;
    #pragma unroll 4
    for (int j = 0; j < 256; j++) acc += kr[j] * kr[j];
  }
  if (t < 168) partial[(size_t)(chunk * 32 + bh) * 168 + t] = acc;
}

// ---- reduce partials + norms + softmax + fused projection matrix ----
// M[b][dg][o] = sum_c attn_hd[c][d] * PWt[(hd*12+c)*48 + o], dg = hd*12+d.
// The projection conv then computes ho[o] = sum_dg M[dg][o] * v[dg] directly.
__global__ void __launch_bounds__(256) attn_finM_k(const float* __restrict__ partial,
                                                   const float* __restrict__ temp,
                                                   const float* __restrict__ pwt,
                                                   float* __restrict__ M) {
  int bh = blockIdx.x, b = bh >> 2, hd = bh & 3;
  int t = threadIdx.x;
  __shared__ float red[168];
  __shared__ float sm[144];              // sm[c*12 + d]
  if (t < 168) {
    float s = 0.f;
    for (int ch = 0; ch < NCHUNK; ch++) s += partial[(size_t)(ch * 32 + bh) * 168 + t];
    red[t] = s;
  }
  __syncthreads();
  if (t < 12) {
    float tm = temp[hd];
    float rq = 1.f / fmaxf(sqrtf(red[144 + t]), 1e-12f);
    float vals[12], mx = -1e30f;
    #pragma unroll
    for (int d = 0; d < 12; d++) {
      float rk = 1.f / fmaxf(sqrtf(red[156 + d]), 1e-12f);
      vals[d] = red[t * 12 + d] * rq * rk * tm;
      mx = fmaxf(mx, vals[d]);
    }
    float s = 0.f;
    #pragma unroll
    for (int d = 0; d < 12; d++) { vals[d] = expf(vals[d] - mx); s += vals[d]; }
    float inv = 1.f / s;
    #pragma unroll
    for (int d = 0; d < 12; d++) sm[t * 12 + d] = vals[d] * inv;
  }
  __syncthreads();
  for (int e = t; e < 576; e += 256) {   // 12 d-rows x 48 outputs
    int d = e / 48, o = e - d * 48;
    float s = 0.f;
    #pragma unroll
    for (int c = 0; c < 12; c++) s += sm[c * 12 + d] * pwt[(hd * 12 + c) * 48 + o];
    M[(size_t)b * 2304 + (hd * 12 + d) * 48 + o] = s;
  }
}

// ---- final v2t: 64 px/block, 4 waves x 12 outputs, transposed weights ----
__global__ void __launch_bounds__(256) conv_final_k(const bf16* __restrict__ ho,
                                                    const bf16* __restrict__ lo,
                                                    const float* __restrict__ P,
                                                    const void* __restrict__ x,
                                                    void* __restrict__ out,
                                                    const int* flagp) {
  int bf = flagp[0];
  __shared__ float vs[96 * 64];
  int t = threadIdx.x;
  int blk = blockIdx.x;                // B * 256
  int b = blk >> 8;
  int p0 = (blk & 255) << 6;
  int pbase = b * 48 * HW + p0;
  #pragma unroll
  for (int i = 0; i < 12; i++) {
    int idx = i * 256 + t;
    int c = idx >> 6, p = idx & 63;
    vs[idx] = ldf(ho, pbase + c * HW + p);
    vs[48 * 64 + idx] = ldf(lo, pbase + c * HW + p);
  }
  __syncthreads();
  int p = t & 63;
  int og = __builtin_amdgcn_readfirstlane(t >> 6);   // wave-uniform 0..3
  const float* Wcol = P + O_FPW + og * 12;           // transposed: [c*48 + j]
  float acc[12];
  #pragma unroll
  for (int j = 0; j < 12; j++) acc[j] = 0.f;
  for (int c = 0; c < 96; c++) {
    float v = vs[c * 64 + p];
    const float* wc = Wcol + c * 48;
    #pragma unroll
    for (int j = 0; j < 12; j++) acc[j] += wc[j] * v;
  }
  #pragma unroll
  for (int j = 0; j < 12; j++) {
    int o = og * 12 + j;
    int oi = pbase + o * HW + p;
    float val = acc[j] + P[O_FPB + o] + ldx(x, oi, bf);
    if (bf) ((bf16*)out)[oi] = tob(val);
    else    ((float*)out)[oi] = val;
  }
}

extern "C" void kernel_launch(void* const* d_in, const int* in_sizes, int n_in,
                              void* d_out, int out_size, void* d_ws, size_t ws_size,
                              hipStream_t stream) {
  const void* x = d_in[0];

  // ws layout (fp32 units): ap@0, flag@7000, params@8192 (ends 47224),
  // wts@48000, Mbuf@50000 (8*2304 -> ends 68432), parts@70000 (ends 414064),
  // bf16 planes P0..P9 @420000 (10 * NCHW bf16 = 125.8 MB)
  float* ws    = (float*)d_ws;
  float* ap    = ws;
  int*   flagp = (int*)(ws + 7000);
  float* P     = ws + 8192;
  float* wts   = ws + 48000;
  float* Mbuf  = ws + 50000;
  float* parts = ws + 70000;
  bf16* base = (bf16*)(ws + 420000);
  bf16* P0 = base;                       // hf -> ho
  bf16* P1 = base + (size_t)NCHW;        // lf -> lo
  bf16* P2 = base + (size_t)2 * NCHW;    // spec / HKpre / q-pre scratch
  bf16* P3 = base + (size_t)3 * NCHW;    // spec / HVpre / q
  bf16* P4 = base + (size_t)4 * NCHW;    // spec / LKpre
  bf16* P5 = base + (size_t)5 * NCHW;    // LVpre
  bf16* P6 = base + (size_t)6 * NCHW;    // HK
  bf16* P7 = base + (size_t)7 * NCHW;    // HV
  bf16* P8 = base + (size_t)8 * NCHW;    // LK
  bf16* P9 = base + (size_t)9 * NCHW;    // LV
  float* spec = (float*)P2;

  // ---- dtype detect + param convert (matmul weights transposed) ----
  detect_k<<<1, 256, 0, stream>>>(x, flagp);
  ParamTab tab;
  const int offs[25] = {O_FDW, O_BNG, O_BNB, O_BNM, O_BNV,
                        O_FHW1, O_FHB1, O_FHW2, O_FHB2,
                        O_FLW, O_FLB,
                        O_HQW, O_HKVW, O_HQDW, O_HKVDW, O_HPW, O_HT,
                        O_LQW, O_LKVW, O_LQDW, O_LKVDW, O_LPW, O_LT,
                        O_FPW, O_FPB};
  const int cnts[25] = {3456, 72, 72, 72, 72,
                        144, 48, 144, 48,
                        9216, 96,
                        2304, 4608, 432, 864, 2304, 4,
                        2304, 4608, 432, 864, 2304, 4,
                        4608, 48};
  const int rows[25] = {0, 0, 0, 0, 0,
                        0, 0, 0, 0,
                        96, 0,
                        48, 96, 0, 0, 48, 0,
                        48, 96, 0, 0, 48, 0,
                        48, 0};
  for (int i = 0; i < 25; i++) {
    tab.src[i] = d_in[i + 1]; tab.off[i] = offs[i]; tab.cnt[i] = cnts[i]; tab.rows[i] = rows[i];
  }
  cvt_params_k<<<25, 256, 0, stream>>>(tab, flagp, P);

  // ---- fd ----
  reduce_mean_k<<<B * C, 256, 0, stream>>>(x, ap, flagp);
  fd_weights_k<<<B, 128, 0, stream>>>(ap, P, wts);
  fd_apply_k<<<NCHW / 1024, 256, 0, stream>>>(x, wts, P1, P3, flagp); // low->P1, high->P3
  // ---- fmgm_high ----
  fmgm_high_k<<<NCHW / 1024, 256, 0, stream>>>(P3, P, P0);            // hf->P0
  // ---- fmgm_low: rfft2 -> gate -> irfft2 (spec overlays P2..P4) ----
  rfft_row_k<<<B * C * H / 4, 256, 0, stream>>>(P1, spec);
  fft_col_k<<<B * C * 2, 256, 0, stream>>>(spec, -1.f, 1.f);
  freq_gate_k<<<B * (SPECHW / 64), 256, 0, stream>>>(spec, P);
  fft_col_k<<<B * C * 2, 256, 0, stream>>>(spec, 1.f, 1.f / 128.f);
  irfft_row_k<<<B * C * H / 4, 256, 0, stream>>>(spec, P1);           // lf->P1
  // ---- fused x->KV convs (spec dead): HK,HV,LK,LV pre-planes ----
  convxkv_k<<<B * 256, 256, 0, stream>>>(x, P2, P3, P4, P5, P, flagp);
  dw3x3x2_k<<<NCHW / 1024, 256, 0, stream>>>(P2, P6, P3, P7,
                                             P + O_HKVDW, P + O_HKVDW + 48 * 9);
  dw3x3x2_k<<<NCHW / 1024, 256, 0, stream>>>(P4, P8, P5, P9,
                                             P + O_LKVDW, P + O_LKVDW + 48 * 9);
  // ---- fga high: q = dw(conv(hf)); attn; ho = (PW@attn) @ v ----
  conv1x1_k<<<B * 256, 256, 0, stream>>>(P0, P2, P + O_HQW, 48, flagp, 0, 0);
  dw3x3_k<<<NCHW / 1024, 256, 0, stream>>>(P2, P3, P + O_HQDW);       // q->P3 (P0 dead)
  attn_part_k<<<32 * NCHUNK, 256, 0, stream>>>(P3, P6, parts);
  attn_finM_k<<<32, 256, 0, stream>>>(parts, P + O_HT, P + O_HPW, Mbuf);
  conv1x1_k<<<B * 256, 256, 0, stream>>>(P7, P0, Mbuf, 48, flagp, 0, 1);  // ho->P0
  // ---- fga low ----
  conv1x1_k<<<B * 256, 256, 0, stream>>>(P1, P2, P + O_LQW, 48, flagp, 0, 0);
  dw3x3_k<<<NCHW / 1024, 256, 0, stream>>>(P2, P3, P + O_LQDW);       // q->P3 (P1 dead)
  attn_part_k<<<32 * NCHUNK, 256, 0, stream>>>(P3, P8, parts);
  attn_finM_k<<<32, 256, 0, stream>>>(parts, P + O_LT, P + O_LPW, Mbuf);
  conv1x1_k<<<B * 256, 256, 0, stream>>>(P9, P1, Mbuf, 48, flagp, 0, 1);  // lo->P1
  // ---- final 1x1 + bias + residual ----
  conv_final_k<<<B * 256, 256, 0, stream>>>(P0, P1, P, x, d_out, flagp);
}

// Round 7
// 543.031 us; speedup vs baseline: 1.8584x; 1.1019x over previous
//
#include <hip/hip_runtime.h>
#include <hip/hip_bf16.h>
#include <math.h>

using bf16 = __hip_bfloat16;
#define DI __device__ __forceinline__

namespace {
constexpr int B = 8, C = 48, H = 128, W = 128;
constexpr int HW = H * W;                 // 16384
constexpr int NCHW = B * C * HW;          // 6,291,456
constexpr int C2 = 96;
constexpr int WF = 65;                    // rfft width
constexpr int SPECHW = H * WF;            // 8320 (divisible by 64)
constexpr int SPECN = B * C2 * SPECHW;    // 6,389,760 floats
// spec (fp32) overlays planes P2+P3+P4 = 3*NCHW bf16 slots
static_assert((size_t)SPECN * 4 <= (size_t)3 * NCHW * 2, "spec must fit in P2..P4 overlay");
static_assert(SPECHW % 64 == 0, "freq_gate 64-pixel blocks must not straddle batches");

// fp32 param header offsets (in floats), base = ws + 8192
// NOTE: matmul weights (FLW, *QW, *KVW, *PW, FPW) are stored TRANSPOSED
// (input-major): wt[c*rows + o]. Depthwise/BN/bias params stay plain.
constexpr int O_FDW = 0,    O_BNG = 3456, O_BNB = 3528, O_BNM = 3600, O_BNV = 3672;
constexpr int O_FHW1 = 3744, O_FHB1 = 3888, O_FHW2 = 3936, O_FHB2 = 3984;
constexpr int O_FLW = 4032,  O_FLB = 13248;
constexpr int O_HQW = 13344, O_HKVW = 15648, O_HQDW = 20256, O_HKVDW = 20688, O_HPW = 21552, O_HT = 23856;
constexpr int O_LQW = 23860, O_LKVW = 26164, O_LQDW = 30772, O_LKVDW = 31204, O_LPW = 32068, O_LT = 34372;
constexpr int O_FPW = 34376, O_FPB = 38984;  // end 39032

constexpr int NCHUNK = 64;                // L split for attn gram
constexpr int PARTSZ = 32 * NCHUNK * 168; // per-branch partials (344064 floats)
}

DI float ldf(const float* p, int i) { return p[i]; }
DI float ldf(const bf16* p, int i) { return __bfloat162float(p[i]); }
DI bf16 tob(float x) { return __float2bfloat16(x); }
DI unsigned short b2u(bf16 v) { union { bf16 b; unsigned short u; } x; x.b = v; return x.u; }
DI float u2f(unsigned short u) { return __uint_as_float((unsigned)u << 16); }
DI float ldx(const void* p, int i, int bf) {
  return bf ? __bfloat162float(((const bf16*)p)[i]) : ((const float*)p)[i];
}
DI float geluf(float x) { return 0.5f * x * (1.f + erff(x * 0.70710678118654752f)); }
DI int refl(int i, int n) { return i < 0 ? -i : (i >= n ? 2 * n - 2 - i : i); }

// ---- dtype detector: bf16 data -> even u16 slots have sane exponents ----
__global__ void detect_k(const void* x, int* flagp) {
  const unsigned short* u = (const unsigned short*)x;
  int t = threadIdx.x;
  int good = 0;
  for (int i = t; i < 1024; i += 256) {
    unsigned short v = u[2 * i];
    int e = (v >> 7) & 0xFF;
    if (e >= 100 && e <= 140) good++;
  }
  __shared__ int cnt;
  if (t == 0) cnt = 0;
  __syncthreads();
  atomicAdd(&cnt, good);
  __syncthreads();
  if (t == 0) flagp[0] = (cnt > 512) ? 1 : 0;
}

// ---- convert all params to fp32 header; matmul weights transposed ----
struct ParamTab { const void* src[25]; int off[25]; int cnt[25]; int rows[25]; };
__global__ void cvt_params_k(ParamTab tab, const int* flagp, float* dst) {
  int bf = flagp[0];
  int b = blockIdx.x;
  const void* s = tab.src[b];
  float* d = dst + tab.off[b];
  int n = tab.cnt[b];
  int rows = tab.rows[b];
  if (rows == 0) {
    for (int i = threadIdx.x; i < n; i += 256) d[i] = ldx(s, i, bf);
  } else {
    int cols = n / rows;
    for (int i = threadIdx.x; i < n; i += 256)
      d[(i % cols) * rows + (i / cols)] = ldx(s, i, bf);
  }
}

// ---- fd: channel means, v2: vector loads ----
__global__ void reduce_mean_k(const void* __restrict__ x, float* __restrict__ ap,
                              const int* flagp) {
  int bf = flagp[0];
  int bc = blockIdx.x;
  float s = 0.f;
  if (bf) {
    const ushort4* xp = (const ushort4*)((const bf16*)x + (size_t)bc * HW);
    for (int i = threadIdx.x; i < HW / 4; i += 256) {
      ushort4 u = xp[i];
      s += u2f(u.x) + u2f(u.y) + u2f(u.z) + u2f(u.w);
    }
  } else {
    const float4* xp = (const float4*)((const float*)x + (size_t)bc * HW);
    for (int i = threadIdx.x; i < HW / 4; i += 256) {
      float4 u = xp[i];
      s += u.x + u.y + u.z + u.w;
    }
  }
  #pragma unroll
  for (int o = 32; o > 0; o >>= 1) s += __shfl_down(s, o);
  __shared__ float r[4];
  if ((threadIdx.x & 63) == 0) r[threadIdx.x >> 6] = s;
  __syncthreads();
  if (threadIdx.x == 0) ap[bc] = (r[0] + r[1] + r[2] + r[3]) * (1.f / HW);
}

// ---- fd: 72-wide linear + BN + per-group softmax over 9 ----
__global__ void fd_weights_k(const float* __restrict__ ap, const float* __restrict__ P,
                             float* __restrict__ wts) {
  int n = blockIdx.x, t = threadIdx.x;
  __shared__ float vals[72], es[72];
  if (t < 72) {
    float acc = 0.f;
    for (int c = 0; c < C; c++) acc += P[O_FDW + t * C + c] * ap[n * C + c];
    acc = (acc - P[O_BNM + t]) * rsqrtf(P[O_BNV + t] + 1e-5f);
    vals[t] = acc * P[O_BNG + t] + P[O_BNB + t];
  }
  __syncthreads();
  if (t < 72) {
    int base = (t / 9) * 9;
    float mx = -1e30f;
    for (int k = 0; k < 9; k++) mx = fmaxf(mx, vals[base + k]);
    es[t] = expf(vals[t] - mx);
  }
  __syncthreads();
  if (t < 72) {
    int base = (t / 9) * 9;
    float s = 0.f;
    for (int k = 0; k < 9; k++) s += es[base + k];
    wts[n * 72 + t] = es[t] / s;
  }
}

// ---- fd v2: involution low-pass (reflect pad), 4 px/thread, vector rows ----
__global__ void fd_apply_k(const void* __restrict__ x, const float* __restrict__ wts,
                           bf16* __restrict__ low, bf16* __restrict__ high,
                           const int* flagp) {
  int bf = flagp[0];
  int idx4 = blockIdx.x * 256 + threadIdx.x;   // quad index over NCHW/4
  int w0 = (idx4 & 31) << 2;                   // W/4 = 32
  int h = (idx4 >> 5) & (H - 1);
  int plane = idx4 >> 12;                      // b*C + c
  int c = plane % C;
  int b = plane / C;
  const float* wt = wts + b * 72 + (c / 6) * 9;
  size_t pbase = (size_t)plane * HW;
  float acc[4] = {0.f, 0.f, 0.f, 0.f};
  float ctr[4];
  #pragma unroll
  for (int i = 0; i < 3; i++) {
    int hh = refl(h + i - 1, H);
    float v[6];
    if (bf) {
      const bf16* row = (const bf16*)x + pbase + hh * W + w0;
      ushort4 u = *(const ushort4*)row;        // 8B aligned
      v[1] = u2f(u.x); v[2] = u2f(u.y); v[3] = u2f(u.z); v[4] = u2f(u.w);
      v[0] = (w0 > 0) ? ldf(row, -1) : v[2];
      v[5] = (w0 + 4 < W) ? ldf(row, 4) : v[3];
    } else {
      const float* row = (const float*)x + pbase + hh * W + w0;
      float4 u = *(const float4*)row;          // 16B aligned
      v[1] = u.x; v[2] = u.y; v[3] = u.z; v[4] = u.w;
      v[0] = (w0 > 0) ? row[-1] : v[2];
      v[5] = (w0 + 4 < W) ? row[4] : v[3];
    }
    if (i == 1) { ctr[0] = v[1]; ctr[1] = v[2]; ctr[2] = v[3]; ctr[3] = v[4]; }
    #pragma unroll
    for (int j = 0; j < 3; j++) {
      float wv = wt[i * 3 + j];
      #pragma unroll
      for (int q = 0; q < 4; q++) acc[q] += wv * v[q + j];
    }
  }
  ushort4 ol, oh;
  ol.x = b2u(tob(acc[0])); ol.y = b2u(tob(acc[1]));
  ol.z = b2u(tob(acc[2])); ol.w = b2u(tob(acc[3]));
  oh.x = b2u(tob(ctr[0] - acc[0])); oh.y = b2u(tob(ctr[1] - acc[1]));
  oh.z = b2u(tob(ctr[2] - acc[2])); oh.w = b2u(tob(ctr[3] - acc[3]));
  *(ushort4*)(low + (size_t)idx4 * 4) = ol;
  *(ushort4*)(high + (size_t)idx4 * 4) = oh;
}

// ---- fmgm_high v2: fused (1x3)->(3x1) dwconv -> gelu * x, 4 px/thread ----
__global__ void fmgm_high_k(const bf16* __restrict__ hi, const float* __restrict__ P,
                            bf16* __restrict__ out) {
  int idx4 = blockIdx.x * 256 + threadIdx.x;   // quad index over NCHW/4
  int w0 = (idx4 & 31) << 2;
  int h = (idx4 >> 5) & (H - 1);
  int plane = idx4 >> 12;
  int c = plane % C;
  const bf16* p = hi + (size_t)plane * HW;
  float k1[3], k2[3];
  #pragma unroll
  for (int j = 0; j < 3; j++) { k1[j] = P[O_FHW1 + c * 3 + j]; k2[j] = P[O_FHW2 + c * 3 + j]; }
  float b1 = P[O_FHB1 + c];
  float b2 = P[O_FHB2 + c];
  float acc[4] = {b2, b2, b2, b2};
  float ctr[4];
  #pragma unroll
  for (int i = 0; i < 3; i++) {
    int hh = h + i - 1;
    if (hh < 0 || hh >= H) continue;
    const bf16* row = p + hh * W + w0;
    ushort4 u = *(const ushort4*)row;          // 8B aligned
    float v[6];
    v[1] = u2f(u.x); v[2] = u2f(u.y); v[3] = u2f(u.z); v[4] = u2f(u.w);
    v[0] = (w0 > 0) ? ldf(row, -1) : 0.f;      // zero pad
    v[5] = (w0 + 4 < W) ? ldf(row, 4) : 0.f;
    if (i == 1) { ctr[0] = v[1]; ctr[1] = v[2]; ctr[2] = v[3]; ctr[3] = v[4]; }
    float kk = k2[i];
    #pragma unroll
    for (int q = 0; q < 4; q++) {
      float y1 = b1 + k1[0] * v[q] + k1[1] * v[q + 1] + k1[2] * v[q + 2];
      acc[q] += kk * y1;
    }
  }
  ushort4 o;
  o.x = b2u(tob(geluf(acc[0]) * ctr[0]));
  o.y = b2u(tob(geluf(acc[1]) * ctr[1]));
  o.z = b2u(tob(geluf(acc[2]) * ctr[2]));
  o.w = b2u(tob(geluf(acc[3]) * ctr[3]));
  *(ushort4*)(out + (size_t)idx4 * 4) = o;
}

// ---- rfft along W, v3: lane-parallel radix-2 FFT64 (shuffle butterflies) ----
__global__ void __launch_bounds__(256) rfft_row_k(const bf16* __restrict__ low,
                                                  float* __restrict__ spec) {
  int t = threadIdx.x;
  int wid = t >> 6, l = t & 63;
  int row = blockIdx.x * 4 + wid;        // in [0, B*C*H)
  int h = row & (H - 1);
  int bc = row >> 7;
  int c = bc % C, b = bc / C;
  const unsigned* xr = (const unsigned*)(low + (size_t)row * W);
  unsigned v2 = xr[l];                   // two bf16: elems 2l, 2l+1
  float zr = __uint_as_float(v2 << 16);
  float zi = __uint_as_float(v2 & 0xFFFF0000u);
  #pragma unroll
  for (int s = 0; s < 6; s++) {
    int d = 32 >> s;
    float pr = __shfl_xor(zr, d);
    float pi = __shfl_xor(zi, d);
    float a = (float)(l & (d - 1)) / (float)d;
    float wr = cospif(a), wi = -sinpif(a);
    float sr = zr + pr, si = zi + pi;
    float dr = pr - zr, di = pi - zi;
    float mr2 = dr * wr - di * wi;
    float mi2 = dr * wi + di * wr;
    bool hib = (l & d) != 0;
    zr = hib ? mr2 : sr;
    zi = hib ? mi2 : si;
  }
  int rl = __brev(l) >> 26;
  int lm = (64 - l) & 63;
  int rm = __brev(lm) >> 26;
  float Zkr = __shfl(zr, rl), Zki = __shfl(zi, rl);
  float Zmr = __shfl(zr, rm), Zmi = __shfl(zi, rm);
  float Fer = 0.5f * (Zkr + Zmr), Fei = 0.5f * (Zki - Zmi);
  float Dr  = 0.5f * (Zkr - Zmr), Di  = 0.5f * (Zki + Zmi);
  float For = Di, Foi = -Dr;             // D / i
  float a = (float)l * (1.f / 64.f);
  float tr = cospif(a), ti = -sinpif(a); // e^{-2 pi i l / 128}
  float Xr = Fer + tr * For - ti * Foi;
  float Xi = Fei + tr * Foi + ti * For;
  size_t o = ((size_t)(b * C2 + c) * H + h) * WF + l;
  size_t ioff = (size_t)C * H * WF;
  spec[o] = Xr;
  spec[o + ioff] = Xi;
  if (l == 0) {                          // k = 64 (Nyquist)
    spec[o + 64] = Fer - For;
    spec[o + 64 + ioff] = 0.f;
  }
}

// ---- complex FFT-128 along H, v6: lane-parallel radix-2, LDS tile ----
__global__ void __launch_bounds__(256) fft_col_k(float* __restrict__ spec,
                                                 float sgn, float scale) {
  __shared__ float re_s[128 * 33], im_s[128 * 33];   // 33.8 KB, stride 33
  int t = threadIdx.x;
  int half = blockIdx.x & 1;
  int bc = blockIdx.x >> 1;
  int cc = bc % C, b = bc / C;
  size_t reb = ((size_t)(b * C2 + cc) * H) * WF;
  size_t imb = reb + (size_t)C * H * WF;
  int ncol = half ? 33 : 32;
  if (half == 0) {
    #pragma unroll
    for (int i = 0; i < 16; i++) {
      int idx = i * 256 + t;             // 4096 = 128*32
      int r = idx >> 5, c = idx & 31;
      re_s[r * 33 + c] = spec[reb + r * WF + c];
      im_s[r * 33 + c] = spec[imb + r * WF + c];
    }
  } else {
    #pragma unroll
    for (int i = 0; i < 17; i++) {
      int idx = i * 256 + t;             // 4352 >= 128*33
      if (idx < 128 * 33) {
        int r = idx / 33, c = idx - r * 33;
        re_s[r * 33 + c] = spec[reb + r * WF + 32 + c];
        im_s[r * 33 + c] = spec[imb + r * WF + 32 + c];
      }
    }
  }
  __syncthreads();
  int w = t >> 6, l = t & 63;
  float cA = cospif((float)l * (1.f / 64.f));
  float sA = sinpif((float)l * (1.f / 64.f)) * sgn;  // e^{sgn*2pi i l/128}
  float cs[6], ss[6];
  #pragma unroll
  for (int s = 0; s < 6; s++) {
    int d = 32 >> s;
    float a = (float)(l & (d - 1)) / (float)d;
    cs[s] = cospif(a); ss[s] = sinpif(a) * sgn;
  }
  int br = __brev(l) >> 26;
  for (int c = w; c < ncol; c += 4) {
    float ar = re_s[l * 33 + c],         ai = im_s[l * 33 + c];
    float xr = re_s[(l + 64) * 33 + c],  xi = im_s[(l + 64) * 33 + c];
    float ur = ar + xr, ui = ai + xi;                // -> even freqs
    float tr = ar - xr, ti = ai - xi;
    float vr = tr * cA - ti * sA;                    // -> odd freqs
    float vi = tr * sA + ti * cA;
    #pragma unroll
    for (int s = 0; s < 6; s++) {
      int d = 32 >> s;
      float pr = __shfl_xor(ur, d), pi = __shfl_xor(ui, d);
      float qr = __shfl_xor(vr, d), qi = __shfl_xor(vi, d);
      float sur = ur + pr, sui = ui + pi;
      float dur = pr - ur, dui = pi - ui;
      float svr = vr + qr, svi = vi + qi;
      float dvr = qr - vr, dvi = qi - vi;
      float mur = dur * cs[s] - dui * ss[s];
      float mui = dur * ss[s] + dui * cs[s];
      float mvr = dvr * cs[s] - dvi * ss[s];
      float mvi = dvr * ss[s] + dvi * cs[s];
      bool hib = (l & d) != 0;
      ur = hib ? mur : sur; ui = hib ? mui : sui;
      vr = hib ? mvr : svr; vi = hib ? mvi : svi;
    }
    int r0 = 2 * br;                     // X[2*br] = U-res, X[2*br+1] = V-res
    re_s[r0 * 33 + c] = ur * scale;       im_s[r0 * 33 + c] = ui * scale;
    re_s[(r0 + 1) * 33 + c] = vr * scale; im_s[(r0 + 1) * 33 + c] = vi * scale;
  }
  __syncthreads();
  if (half == 0) {
    #pragma unroll
    for (int i = 0; i < 16; i++) {
      int idx = i * 256 + t;
      int r = idx >> 5, c = idx & 31;
      spec[reb + r * WF + c] = re_s[r * 33 + c];
      spec[imb + r * WF + c] = im_s[r * 33 + c];
    }
  } else {
    #pragma unroll
    for (int i = 0; i < 17; i++) {
      int idx = i * 256 + t;
      if (idx < 128 * 33) {
        int r = idx / 33, c = idx - r * 33;
        spec[reb + r * WF + 32 + c] = re_s[r * 33 + c];
        spec[imb + r * WF + 32 + c] = im_s[r * 33 + c];
      }
    }
  }
}

// ---- freq-domain channel-mix gate: yf *= gelu(W yf + b) ----
__global__ void __launch_bounds__(256) freq_gate_k(float* __restrict__ spec,
                                                   const float* __restrict__ P) {
  __shared__ float vs[96 * 65];
  int t = threadIdx.x;
  int blk = blockIdx.x;
  int b = blk / (SPECHW / 64);
  int pp0 = (blk % (SPECHW / 64)) * 64;
  float* sb = spec + (size_t)b * C2 * SPECHW + pp0;
  #pragma unroll
  for (int i = 0; i < 24; i++) {
    int idx = i * 256 + t;
    int c = idx >> 6, p = idx & 63;
    vs[c * 65 + p] = sb[(size_t)c * SPECHW + p];
  }
  __syncthreads();
  int p = t & 63;
  int og = __builtin_amdgcn_readfirstlane(t >> 6);   // wave-uniform 0..3
  const float* Wcol = P + O_FLW + og * 24;           // transposed: [c*96 + j]
  float acc[24];
  #pragma unroll
  for (int j = 0; j < 24; j++) acc[j] = 0.f;
  for (int c = 0; c < 96; c++) {
    float vv = vs[c * 65 + p];
    const float* wc = Wcol + c * 96;
    #pragma unroll
    for (int j = 0; j < 24; j++) acc[j] += wc[j] * vv;
  }
  #pragma unroll
  for (int j = 0; j < 24; j++) {
    int o = og * 24 + j;
    float g = geluf(acc[j] + P[O_FLB + o]);
    sb[(size_t)o * SPECHW + p] = vs[o * 65 + p] * g;
  }
}

// ---- irfft along W, v3: Hermitian pack + lane-parallel inverse FFT64 ----
__global__ void __launch_bounds__(256) irfft_row_k(const float* __restrict__ spec,
                                                   bf16* __restrict__ out) {
  int t = threadIdx.x;
  int wid = t >> 6, l = t & 63;
  int row = blockIdx.x * 4 + wid;        // in [0, B*C*H)
  int h = row & (H - 1);
  int bc = row >> 7;
  int c = bc % C, b = bc / C;
  size_t rb = ((size_t)(b * C2 + c) * H + h) * WF;
  size_t ioff = (size_t)C * H * WF;
  float xr = spec[rb + l];
  float xi = (l == 0) ? 0.f : spec[rb + ioff + l];   // C2R: ignore DC imag
  float r64 = spec[rb + 64];                         // Nyquist (real used only)
  int lm = (64 - l) & 63;
  float mr = __shfl(xr, lm);
  float mi = __shfl(xi, lm);
  if (l == 0) { mr = r64; mi = 0.f; }                // X[64] for the k=0 pair
  float Fer = 0.5f * (xr + mr), Fei = 0.5f * (xi - mi);
  float Dr  = 0.5f * (xr - mr), Di  = 0.5f * (xi + mi);
  float a = (float)l * (1.f / 64.f);
  float tr = cospif(a), ti = sinpif(a);              // e^{+2 pi i l / 128}
  float For = tr * Dr - ti * Di;
  float Foi = tr * Di + ti * Dr;
  float zr = Fer - Foi, zi = Fei + For;              // Z = Fe + i*Fo
  #pragma unroll
  for (int s = 0; s < 6; s++) {
    int d = 32 >> s;
    float pr = __shfl_xor(zr, d);
    float pi = __shfl_xor(zi, d);
    float aa = (float)(l & (d - 1)) / (float)d;
    float wr = cospif(aa), wi = sinpif(aa);
    float sr = zr + pr, si = zi + pi;
    float dr = pr - zr, di = pi - zi;
    float mr2 = dr * wr - di * wi;
    float mi2 = dr * wi + di * wr;
    bool hib = (l & d) != 0;
    zr = hib ? mr2 : sr;
    zi = hib ? mi2 : si;
  }
  int m = __brev(l) >> 26;               // lane holds u[m]
  unsigned p0 = b2u(tob(zr * (1.f / 64.f)));
  unsigned p1 = b2u(tob(zi * (1.f / 64.f)));
  ((unsigned*)(out + (size_t)row * W))[m] = p0 | (p1 << 16);
}

// ---- dual 1x1 conv: two independent (in,out,w) jobs, one launch ----
// grid = 2 * B * 256; transposed weights wt[c*wstride + o]; perb: +b*2304
__global__ void __launch_bounds__(256) conv1x1d_k(const bf16* __restrict__ in0, bf16* __restrict__ out0,
                                                  const float* __restrict__ w0,
                                                  const bf16* __restrict__ in1, bf16* __restrict__ out1,
                                                  const float* __restrict__ w1,
                                                  int wstride, int perb) {
  int blk = blockIdx.x;
  int half = blk >> 11;
  int lb = blk & 2047;
  const bf16* in = half ? in1 : in0;
  bf16* out = half ? out1 : out0;
  const float* wt = half ? w1 : w0;
  __shared__ float vs[48 * 64];
  int t = threadIdx.x;
  int b = lb >> 8;
  int p0 = (lb & 255) << 6;
  int ibase = b * 48 * HW + p0;
  #pragma unroll
  for (int i = 0; i < 12; i++) {
    int idx = i * 256 + t;
    int c = idx >> 6, p = idx & 63;
    vs[idx] = ldf(in, ibase + c * HW + p);
  }
  __syncthreads();
  int p = t & 63;
  int og = __builtin_amdgcn_readfirstlane(t >> 6);   // wave-uniform 0..3
  const float* Wcol = wt + (perb ? b * 2304 : 0) + og * 12;
  float acc[12];
  #pragma unroll
  for (int j = 0; j < 12; j++) acc[j] = 0.f;
  for (int c = 0; c < 48; c++) {
    float v = vs[c * 64 + p];
    const float* wc = Wcol + c * wstride;
    #pragma unroll
    for (int j = 0; j < 12; j++) acc[j] += wc[j] * v;
  }
  bf16* op = out + (size_t)b * 48 * HW + p0 + p;
  #pragma unroll
  for (int j = 0; j < 12; j++) op[(size_t)(og * 12 + j) * HW] = tob(acc[j]);
}

// ---- fused x->KV conv v2: 8 waves x 24 outputs, one x staging ----
// wave wid: buf = wid>>1 (HK,HV,LK,LV), 24-ch half = wid&1.
__global__ void __launch_bounds__(512) convxkv_k(const void* __restrict__ in,
                                                 bf16* __restrict__ o0, bf16* __restrict__ o1,
                                                 bf16* __restrict__ o2, bf16* __restrict__ o3,
                                                 const float* __restrict__ P,
                                                 const int* flagp) {
  int bf = flagp[0];
  __shared__ float vs[48 * 64];
  int t = threadIdx.x;
  int blk = blockIdx.x;                // B * 256
  int b = blk >> 8;
  int p0 = (blk & 255) << 6;
  int ibase = b * 48 * HW + p0;
  #pragma unroll
  for (int i = 0; i < 6; i++) {
    int idx = i * 512 + t;             // 3072 = 48*64
    int c = idx >> 6, p = idx & 63;
    vs[idx] = ldx(in, ibase + c * HW + p, bf);
  }
  __syncthreads();
  int p = t & 63;
  int wid = __builtin_amdgcn_readfirstlane(t >> 6);  // wave-uniform 0..7
  int buf = wid >> 1;
  int half24 = (wid & 1) * 24;
  const float* Wcol = P + (buf < 2 ? O_HKVW : O_LKVW) + (buf & 1) * 48 + half24;
  bf16* ob = (buf == 0 ? o0 : buf == 1 ? o1 : buf == 2 ? o2 : o3);
  bf16* op = ob + (size_t)b * 48 * HW + (size_t)half24 * HW + p0 + p;
  float acc[24];
  #pragma unroll
  for (int j = 0; j < 24; j++) acc[j] = 0.f;
  for (int c = 0; c < 48; c++) {
    float v = vs[c * 64 + p];
    const float* wc = Wcol + c * 96;
    #pragma unroll
    for (int j = 0; j < 24; j++) acc[j] += wc[j] * v;
  }
  #pragma unroll
  for (int j = 0; j < 24; j++) op[(size_t)j * HW] = tob(acc[j]);
}

// ---- depthwise 3x3 quad helper ----
DI void dw_quad(const bf16* __restrict__ p, const float* __restrict__ w,
                int c, int h, int w0, float acc[4]) {
  #pragma unroll
  for (int i = 0; i < 3; i++) {
    int hh = h + i - 1;
    if (hh < 0 || hh >= H) continue;
    const bf16* row = p + hh * W + w0;
    ushort4 u = *(const ushort4*)row;          // 8B-aligned (w0 % 4 == 0)
    float v[6];
    v[1] = u2f(u.x); v[2] = u2f(u.y); v[3] = u2f(u.z); v[4] = u2f(u.w);
    v[0] = (w0 > 0) ? ldf(row, -1) : 0.f;
    v[5] = (w0 + 4 < W) ? ldf(row, 4) : 0.f;
    #pragma unroll
    for (int j = 0; j < 3; j++) {
      float wt = w[c * 9 + i * 3 + j];
      #pragma unroll
      for (int q = 0; q < 4; q++) acc[q] += wt * v[q + j];
    }
  }
}

DI void dw_store(bf16* __restrict__ out, int idx4, const float acc[4]) {
  ushort4 o;
  o.x = b2u(tob(acc[0])); o.y = b2u(tob(acc[1]));
  o.z = b2u(tob(acc[2])); o.w = b2u(tob(acc[3]));
  *(ushort4*)(out + (size_t)idx4 * 4) = o;
}

// ---- paired depthwise 3x3: two independent plane sets, one launch ----
__global__ void dw3x3x2_k(const bf16* __restrict__ in1, bf16* __restrict__ out1,
                          const bf16* __restrict__ in2, bf16* __restrict__ out2,
                          const float* __restrict__ w1, const float* __restrict__ w2) {
  int idx4 = blockIdx.x * 256 + threadIdx.x;
  int wq = idx4 & 31;
  int h = (idx4 >> 5) & (H - 1);
  int plane = idx4 >> 12;
  int c = plane % 48;
  int w0 = wq << 2;
  float a1[4] = {0.f, 0.f, 0.f, 0.f};
  dw_quad(in1 + (size_t)plane * HW, w1, c, h, w0, a1);
  dw_store(out1, idx4, a1);
  float a2[4] = {0.f, 0.f, 0.f, 0.f};
  dw_quad(in2 + (size_t)plane * HW, w2, c, h, w0, a2);
  dw_store(out2, idx4, a2);
}

// ---- quad depthwise 3x3: four plane sets (all KV branches), one launch ----
__global__ void dw3x3q_k(const bf16* __restrict__ i1, bf16* __restrict__ u1,
                         const bf16* __restrict__ i2, bf16* __restrict__ u2,
                         const bf16* __restrict__ i3, bf16* __restrict__ u3,
                         const bf16* __restrict__ i4, bf16* __restrict__ u4,
                         const float* __restrict__ w1, const float* __restrict__ w2,
                         const float* __restrict__ w3, const float* __restrict__ w4) {
  int idx4 = blockIdx.x * 256 + threadIdx.x;
  int wq = idx4 & 31;
  int h = (idx4 >> 5) & (H - 1);
  int plane = idx4 >> 12;
  int c = plane % 48;
  int w0 = wq << 2;
  float a[4];
  a[0] = a[1] = a[2] = a[3] = 0.f;
  dw_quad(i1 + (size_t)plane * HW, w1, c, h, w0, a);
  dw_store(u1, idx4, a);
  a[0] = a[1] = a[2] = a[3] = 0.f;
  dw_quad(i2 + (size_t)plane * HW, w2, c, h, w0, a);
  dw_store(u2, idx4, a);
  a[0] = a[1] = a[2] = a[3] = 0.f;
  dw_quad(i3 + (size_t)plane * HW, w3, c, h, w0, a);
  dw_store(u3, idx4, a);
  a[0] = a[1] = a[2] = a[3] = 0.f;
  dw_quad(i4 + (size_t)plane * HW, w4, c, h, w0, a);
  dw_store(u4, idx4, a);
}

// ---- attn gram dual: grid = 2 * 32 bh * NCHUNK ----
__global__ void __launch_bounds__(256) attn_part_k(const bf16* __restrict__ q0,
                                                   const bf16* __restrict__ k0,
                                                   const bf16* __restrict__ q1,
                                                   const bf16* __restrict__ k1,
                                                   float* __restrict__ partial) {
  int blk = blockIdx.x;
  int half = blk >> 11;
  int lb = blk & 2047;
  const bf16* q = half ? q1 : q0;
  const bf16* kbuf = half ? k1 : k0;
  float* part = partial + (size_t)half * PARTSZ;
  int bh = lb >> 6, chunk = lb & (NCHUNK - 1);
  int b = bh >> 2, hd = bh & 3;
  int t = threadIdx.x;
  int l0 = chunk * 256;
  __shared__ float qs[12 * 257], ks[12 * 257];
  const bf16* qb = q + (size_t)(b * 48 + hd * 12) * HW + l0;
  const bf16* kb = kbuf + (size_t)(b * 48 + hd * 12) * HW + l0;
  #pragma unroll
  for (int m = 0; m < 12; m++) {
    qs[m * 257 + t] = ldf(qb, m * HW + t);
    ks[m * 257 + t] = ldf(kb, m * HW + t);
  }
  __syncthreads();
  float acc = 0.f;
  if (t < 144) {
    const float* qr = qs + (t / 12) * 257;
    const float* kr = ks + (t % 12) * 257;
    #pragma unroll 4
    for (int j = 0; j < 256; j++) acc += qr[j] * kr[j];
  } else if (t < 156) {
    const float* qr = qs + (t - 144) * 257;
    #pragma unroll 4
    for (int j = 0; j < 256; j++) acc += qr[j] * qr[j];
  } else if (t < 168) {
    const float* kr = ks + (t - 156) * 257;
    #pragma unroll 4
    for (int j = 0; j < 256; j++) acc += kr[j] * kr[j];
  }
  if (t < 168) part[(size_t)(chunk * 32 + bh) * 168 + t] = acc;
}

// ---- dual: reduce partials + softmax + fused projection matrix ----
// grid = 64: half = blk>>5 (high/low), bh = blk&31.
// M[half][b][dg][o] = sum_c attn_hd[c][d] * PWt[(hd*12+c)*48 + o]
__global__ void __launch_bounds__(256) attn_finM_k(const float* __restrict__ partial,
                                                   const float* __restrict__ P,
                                                   float* __restrict__ M) {
  int blk = blockIdx.x;
  int half = blk >> 5;
  int bh = blk & 31, b = bh >> 2, hd = bh & 3;
  const float* part = partial + (size_t)half * PARTSZ;
  const float* temp = P + (half ? O_LT : O_HT);
  const float* pwt = P + (half ? O_LPW : O_HPW);
  float* Mh = M + (size_t)half * 8 * 2304;
  int t = threadIdx.x;
  __shared__ float red[168];
  __shared__ float sm[144];              // sm[c*12 + d]
  if (t < 168) {
    float s = 0.f;
    for (int ch = 0; ch < NCHUNK; ch++) s += part[(size_t)(ch * 32 + bh) * 168 + t];
    red[t] = s;
  }
  __syncthreads();
  if (t < 12) {
    float tm = temp[hd];
    float rq = 1.f / fmaxf(sqrtf(red[144 + t]), 1e-12f);
    float vals[12], mx = -1e30f;
    #pragma unroll
    for (int d = 0; d < 12; d++) {
      float rk = 1.f / fmaxf(sqrtf(red[156 + d]), 1e-12f);
      vals[d] = red[t * 12 + d] * rq * rk * tm;
      mx = fmaxf(mx, vals[d]);
    }
    float s = 0.f;
    #pragma unroll
    for (int d = 0; d < 12; d++) { vals[d] = expf(vals[d] - mx); s += vals[d]; }
    float inv = 1.f / s;
    #pragma unroll
    for (int d = 0; d < 12; d++) sm[t * 12 + d] = vals[d] * inv;
  }
  __syncthreads();
  for (int e = t; e < 576; e += 256) {   // 12 d-rows x 48 outputs
    int d = e / 48, o = e - d * 48;
    float s = 0.f;
    #pragma unroll
    for (int c = 0; c < 12; c++) s += sm[c * 12 + d] * pwt[(hd * 12 + c) * 48 + o];
    Mh[(size_t)b * 2304 + (hd * 12 + d) * 48 + o] = s;
  }
}

// ---- final v2t: 64 px/block, 4 waves x 12 outputs, transposed weights ----
__global__ void __launch_bounds__(256) conv_final_k(const bf16* __restrict__ ho,
                                                    const bf16* __restrict__ lo,
                                                    const float* __restrict__ P,
                                                    const void* __restrict__ x,
                                                    void* __restrict__ out,
                                                    const int* flagp) {
  int bf = flagp[0];
  __shared__ float vs[96 * 64];
  int t = threadIdx.x;
  int blk = blockIdx.x;                // B * 256
  int b = blk >> 8;
  int p0 = (blk & 255) << 6;
  int pbase = b * 48 * HW + p0;
  #pragma unroll
  for (int i = 0; i < 12; i++) {
    int idx = i * 256 + t;
    int c = idx >> 6, p = idx & 63;
    vs[idx] = ldf(ho, pbase + c * HW + p);
    vs[48 * 64 + idx] = ldf(lo, pbase + c * HW + p);
  }
  __syncthreads();
  int p = t & 63;
  int og = __builtin_amdgcn_readfirstlane(t >> 6);   // wave-uniform 0..3
  const float* Wcol = P + O_FPW + og * 12;           // transposed: [c*48 + j]
  float acc[12];
  #pragma unroll
  for (int j = 0; j < 12; j++) acc[j] = 0.f;
  for (int c = 0; c < 96; c++) {
    float v = vs[c * 64 + p];
    const float* wc = Wcol + c * 48;
    #pragma unroll
    for (int j = 0; j < 12; j++) acc[j] += wc[j] * v;
  }
  #pragma unroll
  for (int j = 0; j < 12; j++) {
    int o = og * 12 + j;
    int oi = pbase + o * HW + p;
    float val = acc[j] + P[O_FPB + o] + ldx(x, oi, bf);
    if (bf) ((bf16*)out)[oi] = tob(val);
    else    ((float*)out)[oi] = val;
  }
}

extern "C" void kernel_launch(void* const* d_in, const int* in_sizes, int n_in,
                              void* d_out, int out_size, void* d_ws, size_t ws_size,
                              hipStream_t stream) {
  const void* x = d_in[0];

  // ws layout (fp32 units): ap@0, flag@7000, params@8192 (ends 47224),
  // wts@48000, Mbuf@50000 (2*8*2304 -> ends 86864),
  // parts@90000 (2*PARTSZ -> ends 778128), bf16 planes P0..P9 @800000
  float* ws    = (float*)d_ws;
  float* ap    = ws;
  int*   flagp = (int*)(ws + 7000);
  float* P     = ws + 8192;
  float* wts   = ws + 48000;
  float* Mbuf  = ws + 50000;
  float* parts = ws + 90000;
  bf16* base = (bf16*)(ws + 800000);
  bf16* P0 = base;                       // hf -> ho
  bf16* P1 = base + (size_t)NCHW;        // lf -> lo
  bf16* P2 = base + (size_t)2 * NCHW;    // spec / HKpre / HQpre
  bf16* P3 = base + (size_t)3 * NCHW;    // spec / HVpre / HQ
  bf16* P4 = base + (size_t)4 * NCHW;    // spec / LKpre / LQpre
  bf16* P5 = base + (size_t)5 * NCHW;    // LVpre / LQ
  bf16* P6 = base + (size_t)6 * NCHW;    // HK
  bf16* P7 = base + (size_t)7 * NCHW;    // HV
  bf16* P8 = base + (size_t)8 * NCHW;    // LK
  bf16* P9 = base + (size_t)9 * NCHW;    // LV
  float* spec = (float*)P2;

  // ---- dtype detect + param convert (matmul weights transposed) ----
  detect_k<<<1, 256, 0, stream>>>(x, flagp);
  ParamTab tab;
  const int offs[25] = {O_FDW, O_BNG, O_BNB, O_BNM, O_BNV,
                        O_FHW1, O_FHB1, O_FHW2, O_FHB2,
                        O_FLW, O_FLB,
                        O_HQW, O_HKVW, O_HQDW, O_HKVDW, O_HPW, O_HT,
                        O_LQW, O_LKVW, O_LQDW, O_LKVDW, O_LPW, O_LT,
                        O_FPW, O_FPB};
  const int cnts[25] = {3456, 72, 72, 72, 72,
                        144, 48, 144, 48,
                        9216, 96,
                        2304, 4608, 432, 864, 2304, 4,
                        2304, 4608, 432, 864, 2304, 4,
                        4608, 48};
  const int rows[25] = {0, 0, 0, 0, 0,
                        0, 0, 0, 0,
                        96, 0,
                        48, 96, 0, 0, 48, 0,
                        48, 96, 0, 0, 48, 0,
                        48, 0};
  for (int i = 0; i < 25; i++) {
    tab.src[i] = d_in[i + 1]; tab.off[i] = offs[i]; tab.cnt[i] = cnts[i]; tab.rows[i] = rows[i];
  }
  cvt_params_k<<<25, 256, 0, stream>>>(tab, flagp, P);

  // ---- fd ----
  reduce_mean_k<<<B * C, 256, 0, stream>>>(x, ap, flagp);
  fd_weights_k<<<B, 128, 0, stream>>>(ap, P, wts);
  fd_apply_k<<<NCHW / 1024, 256, 0, stream>>>(x, wts, P1, P3, flagp); // low->P1, high->P3
  // ---- fmgm_high ----
  fmgm_high_k<<<NCHW / 1024, 256, 0, stream>>>(P3, P, P0);            // hf->P0
  // ---- fmgm_low: rfft2 -> gate -> irfft2 (spec overlays P2..P4) ----
  rfft_row_k<<<B * C * H / 4, 256, 0, stream>>>(P1, spec);
  fft_col_k<<<B * C * 2, 256, 0, stream>>>(spec, -1.f, 1.f);
  freq_gate_k<<<B * (SPECHW / 64), 256, 0, stream>>>(spec, P);
  fft_col_k<<<B * C * 2, 256, 0, stream>>>(spec, 1.f, 1.f / 128.f);
  irfft_row_k<<<B * C * H / 4, 256, 0, stream>>>(spec, P1);           // lf->P1
  // ---- fused x->KV conv (spec dead) + quad depthwise ----
  convxkv_k<<<B * 256, 512, 0, stream>>>(x, P2, P3, P4, P5, P, flagp);
  dw3x3q_k<<<NCHW / 1024, 256, 0, stream>>>(P2, P6, P3, P7, P4, P8, P5, P9,
                                            P + O_HKVDW, P + O_HKVDW + 48 * 9,
                                            P + O_LKVDW, P + O_LKVDW + 48 * 9);
  // ---- both q-paths dual (P2..P5 free after dw3x3q) ----
  conv1x1d_k<<<2 * B * 256, 256, 0, stream>>>(P0, P2, P + O_HQW,
                                              P1, P4, P + O_LQW, 48, 0);
  dw3x3x2_k<<<NCHW / 1024, 256, 0, stream>>>(P2, P3, P4, P5,
                                             P + O_HQDW, P + O_LQDW);
  // ---- attention (both branches in each launch) ----
  attn_part_k<<<2 * 32 * NCHUNK, 256, 0, stream>>>(P3, P6, P5, P8, parts);
  attn_finM_k<<<64, 256, 0, stream>>>(parts, P, Mbuf);
  conv1x1d_k<<<2 * B * 256, 256, 0, stream>>>(P7, P0, Mbuf,
                                              P9, P1, Mbuf + 8 * 2304, 48, 1);
  // ---- final 1x1 + bias + residual ----
  conv_final_k<<<B * 256, 256, 0, stream>>>(P0, P1, P, x, d_out, flagp);
}

// Round 8
// 519.890 us; speedup vs baseline: 1.9411x; 1.0445x over previous
//
#include <hip/hip_runtime.h>
#include <hip/hip_bf16.h>
#include <math.h>

using bf16 = __hip_bfloat16;
#define DI __device__ __forceinline__

namespace {
constexpr int B = 8, C = 48, H = 128, W = 128;
constexpr int HW = H * W;                 // 16384
constexpr int NCHW = B * C * HW;          // 6,291,456
constexpr int C2 = 96;
constexpr int WF = 65;                    // rfft width
constexpr int SPECHW = H * WF;            // 8320 (divisible by 64)
constexpr int SPECN = B * C2 * SPECHW;    // 6,389,760 floats
// spec (fp32) overlays planes P2+P3+P4 = 3*NCHW bf16 slots
static_assert((size_t)SPECN * 4 <= (size_t)3 * NCHW * 2, "spec must fit in P2..P4 overlay");
static_assert(SPECHW % 64 == 0, "freq_gate 64-pixel blocks must not straddle batches");

// fp32 param header offsets (in floats), base = ws + 8192
// NOTE: matmul weights (FLW, *QW, *KVW, *PW, FPW) are stored TRANSPOSED
// (input-major): wt[c*rows + o]. Depthwise/BN/bias params stay plain.
constexpr int O_FDW = 0,    O_BNG = 3456, O_BNB = 3528, O_BNM = 3600, O_BNV = 3672;
constexpr int O_FHW1 = 3744, O_FHB1 = 3888, O_FHW2 = 3936, O_FHB2 = 3984;
constexpr int O_FLW = 4032,  O_FLB = 13248;
constexpr int O_HQW = 13344, O_HKVW = 15648, O_HQDW = 20256, O_HKVDW = 20688, O_HPW = 21552, O_HT = 23856;
constexpr int O_LQW = 23860, O_LKVW = 26164, O_LQDW = 30772, O_LKVDW = 31204, O_LPW = 32068, O_LT = 34372;
constexpr int O_FPW = 34376, O_FPB = 38984;  // end 39032

constexpr int NCHUNK = 64;                // L split for attn gram
constexpr int PARTSZ = 32 * NCHUNK * 168; // per-branch partials (344064 floats)
}

DI float ldf(const float* p, int i) { return p[i]; }
DI float ldf(const bf16* p, int i) { return __bfloat162float(p[i]); }
DI bf16 tob(float x) { return __float2bfloat16(x); }
DI unsigned short b2u(bf16 v) { union { bf16 b; unsigned short u; } x; x.b = v; return x.u; }
DI float u2f(unsigned short u) { return __uint_as_float((unsigned)u << 16); }
DI float ldx(const void* p, int i, int bf) {
  return bf ? __bfloat162float(((const bf16*)p)[i]) : ((const float*)p)[i];
}
DI float geluf(float x) { return 0.5f * x * (1.f + erff(x * 0.70710678118654752f)); }
DI int refl(int i, int n) { return i < 0 ? -i : (i >= n ? 2 * n - 2 - i : i); }

// ---- dtype detector: bf16 data -> even u16 slots have sane exponents ----
__global__ void detect_k(const void* x, int* flagp) {
  const unsigned short* u = (const unsigned short*)x;
  int t = threadIdx.x;
  int good = 0;
  for (int i = t; i < 1024; i += 256) {
    unsigned short v = u[2 * i];
    int e = (v >> 7) & 0xFF;
    if (e >= 100 && e <= 140) good++;
  }
  __shared__ int cnt;
  if (t == 0) cnt = 0;
  __syncthreads();
  atomicAdd(&cnt, good);
  __syncthreads();
  if (t == 0) flagp[0] = (cnt > 512) ? 1 : 0;
}

// ---- convert all params to fp32 header; matmul weights transposed ----
struct ParamTab { const void* src[25]; int off[25]; int cnt[25]; int rows[25]; };
__global__ void cvt_params_k(ParamTab tab, const int* flagp, float* dst) {
  int bf = flagp[0];
  int b = blockIdx.x;
  const void* s = tab.src[b];
  float* d = dst + tab.off[b];
  int n = tab.cnt[b];
  int rows = tab.rows[b];
  if (rows == 0) {
    for (int i = threadIdx.x; i < n; i += 256) d[i] = ldx(s, i, bf);
  } else {
    int cols = n / rows;
    for (int i = threadIdx.x; i < n; i += 256)
      d[(i % cols) * rows + (i / cols)] = ldx(s, i, bf);
  }
}

// ---- fd: channel means, v2: vector loads ----
__global__ void reduce_mean_k(const void* __restrict__ x, float* __restrict__ ap,
                              const int* flagp) {
  int bf = flagp[0];
  int bc = blockIdx.x;
  float s = 0.f;
  if (bf) {
    const ushort4* xp = (const ushort4*)((const bf16*)x + (size_t)bc * HW);
    for (int i = threadIdx.x; i < HW / 4; i += 256) {
      ushort4 u = xp[i];
      s += u2f(u.x) + u2f(u.y) + u2f(u.z) + u2f(u.w);
    }
  } else {
    const float4* xp = (const float4*)((const float*)x + (size_t)bc * HW);
    for (int i = threadIdx.x; i < HW / 4; i += 256) {
      float4 u = xp[i];
      s += u.x + u.y + u.z + u.w;
    }
  }
  #pragma unroll
  for (int o = 32; o > 0; o >>= 1) s += __shfl_down(s, o);
  __shared__ float r[4];
  if ((threadIdx.x & 63) == 0) r[threadIdx.x >> 6] = s;
  __syncthreads();
  if (threadIdx.x == 0) ap[bc] = (r[0] + r[1] + r[2] + r[3]) * (1.f / HW);
}

// ---- fd: 72-wide linear + BN + per-group softmax over 9 ----
__global__ void fd_weights_k(const float* __restrict__ ap, const float* __restrict__ P,
                             float* __restrict__ wts) {
  int n = blockIdx.x, t = threadIdx.x;
  __shared__ float vals[72], es[72];
  if (t < 72) {
    float acc = 0.f;
    for (int c = 0; c < C; c++) acc += P[O_FDW + t * C + c] * ap[n * C + c];
    acc = (acc - P[O_BNM + t]) * rsqrtf(P[O_BNV + t] + 1e-5f);
    vals[t] = acc * P[O_BNG + t] + P[O_BNB + t];
  }
  __syncthreads();
  if (t < 72) {
    int base = (t / 9) * 9;
    float mx = -1e30f;
    for (int k = 0; k < 9; k++) mx = fmaxf(mx, vals[base + k]);
    es[t] = expf(vals[t] - mx);
  }
  __syncthreads();
  if (t < 72) {
    int base = (t / 9) * 9;
    float s = 0.f;
    for (int k = 0; k < 9; k++) s += es[base + k];
    wts[n * 72 + t] = es[t] / s;
  }
}

// ---- fd v2: involution low-pass (reflect pad), 4 px/thread, vector rows ----
__global__ void fd_apply_k(const void* __restrict__ x, const float* __restrict__ wts,
                           bf16* __restrict__ low, bf16* __restrict__ high,
                           const int* flagp) {
  int bf = flagp[0];
  int idx4 = blockIdx.x * 256 + threadIdx.x;   // quad index over NCHW/4
  int w0 = (idx4 & 31) << 2;                   // W/4 = 32
  int h = (idx4 >> 5) & (H - 1);
  int plane = idx4 >> 12;                      // b*C + c
  int c = plane % C;
  int b = plane / C;
  const float* wt = wts + b * 72 + (c / 6) * 9;
  size_t pbase = (size_t)plane * HW;
  float acc[4] = {0.f, 0.f, 0.f, 0.f};
  float ctr[4];
  #pragma unroll
  for (int i = 0; i < 3; i++) {
    int hh = refl(h + i - 1, H);
    float v[6];
    if (bf) {
      const bf16* row = (const bf16*)x + pbase + hh * W + w0;
      ushort4 u = *(const ushort4*)row;        // 8B aligned
      v[1] = u2f(u.x); v[2] = u2f(u.y); v[3] = u2f(u.z); v[4] = u2f(u.w);
      v[0] = (w0 > 0) ? ldf(row, -1) : v[2];
      v[5] = (w0 + 4 < W) ? ldf(row, 4) : v[3];
    } else {
      const float* row = (const float*)x + pbase + hh * W + w0;
      float4 u = *(const float4*)row;          // 16B aligned
      v[1] = u.x; v[2] = u.y; v[3] = u.z; v[4] = u.w;
      v[0] = (w0 > 0) ? row[-1] : v[2];
      v[5] = (w0 + 4 < W) ? row[4] : v[3];
    }
    if (i == 1) { ctr[0] = v[1]; ctr[1] = v[2]; ctr[2] = v[3]; ctr[3] = v[4]; }
    #pragma unroll
    for (int j = 0; j < 3; j++) {
      float wv = wt[i * 3 + j];
      #pragma unroll
      for (int q = 0; q < 4; q++) acc[q] += wv * v[q + j];
    }
  }
  ushort4 ol, oh;
  ol.x = b2u(tob(acc[0])); ol.y = b2u(tob(acc[1]));
  ol.z = b2u(tob(acc[2])); ol.w = b2u(tob(acc[3]));
  oh.x = b2u(tob(ctr[0] - acc[0])); oh.y = b2u(tob(ctr[1] - acc[1]));
  oh.z = b2u(tob(ctr[2] - acc[2])); oh.w = b2u(tob(ctr[3] - acc[3]));
  *(ushort4*)(low + (size_t)idx4 * 4) = ol;
  *(ushort4*)(high + (size_t)idx4 * 4) = oh;
}

// ---- fmgm_high v2: fused (1x3)->(3x1) dwconv -> gelu * x, 4 px/thread ----
__global__ void fmgm_high_k(const bf16* __restrict__ hi, const float* __restrict__ P,
                            bf16* __restrict__ out) {
  int idx4 = blockIdx.x * 256 + threadIdx.x;   // quad index over NCHW/4
  int w0 = (idx4 & 31) << 2;
  int h = (idx4 >> 5) & (H - 1);
  int plane = idx4 >> 12;
  int c = plane % C;
  const bf16* p = hi + (size_t)plane * HW;
  float k1[3], k2[3];
  #pragma unroll
  for (int j = 0; j < 3; j++) { k1[j] = P[O_FHW1 + c * 3 + j]; k2[j] = P[O_FHW2 + c * 3 + j]; }
  float b1 = P[O_FHB1 + c];
  float b2 = P[O_FHB2 + c];
  float acc[4] = {b2, b2, b2, b2};
  float ctr[4];
  #pragma unroll
  for (int i = 0; i < 3; i++) {
    int hh = h + i - 1;
    if (hh < 0 || hh >= H) continue;
    const bf16* row = p + hh * W + w0;
    ushort4 u = *(const ushort4*)row;          // 8B aligned
    float v[6];
    v[1] = u2f(u.x); v[2] = u2f(u.y); v[3] = u2f(u.z); v[4] = u2f(u.w);
    v[0] = (w0 > 0) ? ldf(row, -1) : 0.f;      // zero pad
    v[5] = (w0 + 4 < W) ? ldf(row, 4) : 0.f;
    if (i == 1) { ctr[0] = v[1]; ctr[1] = v[2]; ctr[2] = v[3]; ctr[3] = v[4]; }
    float kk = k2[i];
    #pragma unroll
    for (int q = 0; q < 4; q++) {
      float y1 = b1 + k1[0] * v[q] + k1[1] * v[q + 1] + k1[2] * v[q + 2];
      acc[q] += kk * y1;
    }
  }
  ushort4 o;
  o.x = b2u(tob(geluf(acc[0]) * ctr[0]));
  o.y = b2u(tob(geluf(acc[1]) * ctr[1]));
  o.z = b2u(tob(geluf(acc[2]) * ctr[2]));
  o.w = b2u(tob(geluf(acc[3]) * ctr[3]));
  *(ushort4*)(out + (size_t)idx4 * 4) = o;
}

// ---- rfft along W, v3: lane-parallel radix-2 FFT64 (shuffle butterflies) ----
__global__ void __launch_bounds__(256) rfft_row_k(const bf16* __restrict__ low,
                                                  float* __restrict__ spec) {
  int t = threadIdx.x;
  int wid = t >> 6, l = t & 63;
  int row = blockIdx.x * 4 + wid;        // in [0, B*C*H)
  int h = row & (H - 1);
  int bc = row >> 7;
  int c = bc % C, b = bc / C;
  const unsigned* xr = (const unsigned*)(low + (size_t)row * W);
  unsigned v2 = xr[l];                   // two bf16: elems 2l, 2l+1
  float zr = __uint_as_float(v2 << 16);
  float zi = __uint_as_float(v2 & 0xFFFF0000u);
  #pragma unroll
  for (int s = 0; s < 6; s++) {
    int d = 32 >> s;
    float pr = __shfl_xor(zr, d);
    float pi = __shfl_xor(zi, d);
    float a = (float)(l & (d - 1)) / (float)d;
    float wr = cospif(a), wi = -sinpif(a);
    float sr = zr + pr, si = zi + pi;
    float dr = pr - zr, di = pi - zi;
    float mr2 = dr * wr - di * wi;
    float mi2 = dr * wi + di * wr;
    bool hib = (l & d) != 0;
    zr = hib ? mr2 : sr;
    zi = hib ? mi2 : si;
  }
  int rl = __brev(l) >> 26;
  int lm = (64 - l) & 63;
  int rm = __brev(lm) >> 26;
  float Zkr = __shfl(zr, rl), Zki = __shfl(zi, rl);
  float Zmr = __shfl(zr, rm), Zmi = __shfl(zi, rm);
  float Fer = 0.5f * (Zkr + Zmr), Fei = 0.5f * (Zki - Zmi);
  float Dr  = 0.5f * (Zkr - Zmr), Di  = 0.5f * (Zki + Zmi);
  float For = Di, Foi = -Dr;             // D / i
  float a = (float)l * (1.f / 64.f);
  float tr = cospif(a), ti = -sinpif(a); // e^{-2 pi i l / 128}
  float Xr = Fer + tr * For - ti * Foi;
  float Xi = Fei + tr * Foi + ti * For;
  size_t o = ((size_t)(b * C2 + c) * H + h) * WF + l;
  size_t ioff = (size_t)C * H * WF;
  spec[o] = Xr;
  spec[o + ioff] = Xi;
  if (l == 0) {                          // k = 64 (Nyquist)
    spec[o + 64] = Fer - For;
    spec[o + 64 + ioff] = 0.f;
  }
}

// ---- complex FFT-128 along H, v6: lane-parallel radix-2, LDS tile ----
__global__ void __launch_bounds__(256) fft_col_k(float* __restrict__ spec,
                                                 float sgn, float scale) {
  __shared__ float re_s[128 * 33], im_s[128 * 33];   // 33.8 KB, stride 33
  int t = threadIdx.x;
  int half = blockIdx.x & 1;
  int bc = blockIdx.x >> 1;
  int cc = bc % C, b = bc / C;
  size_t reb = ((size_t)(b * C2 + cc) * H) * WF;
  size_t imb = reb + (size_t)C * H * WF;
  int ncol = half ? 33 : 32;
  if (half == 0) {
    #pragma unroll
    for (int i = 0; i < 16; i++) {
      int idx = i * 256 + t;             // 4096 = 128*32
      int r = idx >> 5, c = idx & 31;
      re_s[r * 33 + c] = spec[reb + r * WF + c];
      im_s[r * 33 + c] = spec[imb + r * WF + c];
    }
  } else {
    #pragma unroll
    for (int i = 0; i < 17; i++) {
      int idx = i * 256 + t;             // 4352 >= 128*33
      if (idx < 128 * 33) {
        int r = idx / 33, c = idx - r * 33;
        re_s[r * 33 + c] = spec[reb + r * WF + 32 + c];
        im_s[r * 33 + c] = spec[imb + r * WF + 32 + c];
      }
    }
  }
  __syncthreads();
  int w = t >> 6, l = t & 63;
  float cA = cospif((float)l * (1.f / 64.f));
  float sA = sinpif((float)l * (1.f / 64.f)) * sgn;  // e^{sgn*2pi i l/128}
  float cs[6], ss[6];
  #pragma unroll
  for (int s = 0; s < 6; s++) {
    int d = 32 >> s;
    float a = (float)(l & (d - 1)) / (float)d;
    cs[s] = cospif(a); ss[s] = sinpif(a) * sgn;
  }
  int br = __brev(l) >> 26;
  for (int c = w; c < ncol; c += 4) {
    float ar = re_s[l * 33 + c],         ai = im_s[l * 33 + c];
    float xr = re_s[(l + 64) * 33 + c],  xi = im_s[(l + 64) * 33 + c];
    float ur = ar + xr, ui = ai + xi;                // -> even freqs
    float tr = ar - xr, ti = ai - xi;
    float vr = tr * cA - ti * sA;                    // -> odd freqs
    float vi = tr * sA + ti * cA;
    #pragma unroll
    for (int s = 0; s < 6; s++) {
      int d = 32 >> s;
      float pr = __shfl_xor(ur, d), pi = __shfl_xor(ui, d);
      float qr = __shfl_xor(vr, d), qi = __shfl_xor(vi, d);
      float sur = ur + pr, sui = ui + pi;
      float dur = pr - ur, dui = pi - ui;
      float svr = vr + qr, svi = vi + qi;
      float dvr = qr - vr, dvi = qi - vi;
      float mur = dur * cs[s] - dui * ss[s];
      float mui = dur * ss[s] + dui * cs[s];
      float mvr = dvr * cs[s] - dvi * ss[s];
      float mvi = dvr * ss[s] + dvi * cs[s];
      bool hib = (l & d) != 0;
      ur = hib ? mur : sur; ui = hib ? mui : sui;
      vr = hib ? mvr : svr; vi = hib ? mvi : svi;
    }
    int r0 = 2 * br;                     // X[2*br] = U-res, X[2*br+1] = V-res
    re_s[r0 * 33 + c] = ur * scale;       im_s[r0 * 33 + c] = ui * scale;
    re_s[(r0 + 1) * 33 + c] = vr * scale; im_s[(r0 + 1) * 33 + c] = vi * scale;
  }
  __syncthreads();
  if (half == 0) {
    #pragma unroll
    for (int i = 0; i < 16; i++) {
      int idx = i * 256 + t;
      int r = idx >> 5, c = idx & 31;
      spec[reb + r * WF + c] = re_s[r * 33 + c];
      spec[imb + r * WF + c] = im_s[r * 33 + c];
    }
  } else {
    #pragma unroll
    for (int i = 0; i < 17; i++) {
      int idx = i * 256 + t;
      if (idx < 128 * 33) {
        int r = idx / 33, c = idx - r * 33;
        spec[reb + r * WF + 32 + c] = re_s[r * 33 + c];
        spec[imb + r * WF + 32 + c] = im_s[r * 33 + c];
      }
    }
  }
}

// ---- freq-domain channel-mix gate: yf *= gelu(W yf + b) ----
__global__ void __launch_bounds__(256) freq_gate_k(float* __restrict__ spec,
                                                   const float* __restrict__ P) {
  __shared__ float vs[96 * 65];
  int t = threadIdx.x;
  int blk = blockIdx.x;
  int b = blk / (SPECHW / 64);
  int pp0 = (blk % (SPECHW / 64)) * 64;
  float* sb = spec + (size_t)b * C2 * SPECHW + pp0;
  #pragma unroll
  for (int i = 0; i < 24; i++) {
    int idx = i * 256 + t;
    int c = idx >> 6, p = idx & 63;
    vs[c * 65 + p] = sb[(size_t)c * SPECHW + p];
  }
  __syncthreads();
  int p = t & 63;
  int og = __builtin_amdgcn_readfirstlane(t >> 6);   // wave-uniform 0..3
  const float* Wcol = P + O_FLW + og * 24;           // transposed: [c*96 + j]
  float acc[24];
  #pragma unroll
  for (int j = 0; j < 24; j++) acc[j] = 0.f;
  for (int c = 0; c < 96; c++) {
    float vv = vs[c * 65 + p];
    const float* wc = Wcol + c * 96;
    #pragma unroll
    for (int j = 0; j < 24; j++) acc[j] += wc[j] * vv;
  }
  #pragma unroll
  for (int j = 0; j < 24; j++) {
    int o = og * 24 + j;
    float g = geluf(acc[j] + P[O_FLB + o]);
    sb[(size_t)o * SPECHW + p] = vs[o * 65 + p] * g;
  }
}

// ---- irfft along W, v3: Hermitian pack + lane-parallel inverse FFT64 ----
__global__ void __launch_bounds__(256) irfft_row_k(const float* __restrict__ spec,
                                                   bf16* __restrict__ out) {
  int t = threadIdx.x;
  int wid = t >> 6, l = t & 63;
  int row = blockIdx.x * 4 + wid;        // in [0, B*C*H)
  int h = row & (H - 1);
  int bc = row >> 7;
  int c = bc % C, b = bc / C;
  size_t rb = ((size_t)(b * C2 + c) * H + h) * WF;
  size_t ioff = (size_t)C * H * WF;
  float xr = spec[rb + l];
  float xi = (l == 0) ? 0.f : spec[rb + ioff + l];   // C2R: ignore DC imag
  float r64 = spec[rb + 64];                         // Nyquist (real used only)
  int lm = (64 - l) & 63;
  float mr = __shfl(xr, lm);
  float mi = __shfl(xi, lm);
  if (l == 0) { mr = r64; mi = 0.f; }                // X[64] for the k=0 pair
  float Fer = 0.5f * (xr + mr), Fei = 0.5f * (xi - mi);
  float Dr  = 0.5f * (xr - mr), Di  = 0.5f * (xi + mi);
  float a = (float)l * (1.f / 64.f);
  float tr = cospif(a), ti = sinpif(a);              // e^{+2 pi i l / 128}
  float For = tr * Dr - ti * Di;
  float Foi = tr * Di + ti * Dr;
  float zr = Fer - Foi, zi = Fei + For;              // Z = Fe + i*Fo
  #pragma unroll
  for (int s = 0; s < 6; s++) {
    int d = 32 >> s;
    float pr = __shfl_xor(zr, d);
    float pi = __shfl_xor(zi, d);
    float aa = (float)(l & (d - 1)) / (float)d;
    float wr = cospif(aa), wi = sinpif(aa);
    float sr = zr + pr, si = zi + pi;
    float dr = pr - zr, di = pi - zi;
    float mr2 = dr * wr - di * wi;
    float mi2 = dr * wi + di * wr;
    bool hib = (l & d) != 0;
    zr = hib ? mr2 : sr;
    zi = hib ? mi2 : si;
  }
  int m = __brev(l) >> 26;               // lane holds u[m]
  unsigned p0 = b2u(tob(zr * (1.f / 64.f)));
  unsigned p1 = b2u(tob(zi * (1.f / 64.f)));
  ((unsigned*)(out + (size_t)row * W))[m] = p0 | (p1 << 16);
}

// ---- dual 1x1 conv: two independent (in,out,w) jobs, one launch ----
// grid = 2 * B * 256; transposed weights wt[c*wstride + o]; perb: +b*2304
__global__ void __launch_bounds__(256) conv1x1d_k(const bf16* __restrict__ in0, bf16* __restrict__ out0,
                                                  const float* __restrict__ w0,
                                                  const bf16* __restrict__ in1, bf16* __restrict__ out1,
                                                  const float* __restrict__ w1,
                                                  int wstride, int perb) {
  int blk = blockIdx.x;
  int half = blk >> 11;
  int lb = blk & 2047;
  const bf16* in = half ? in1 : in0;
  bf16* out = half ? out1 : out0;
  const float* wt = half ? w1 : w0;
  __shared__ float vs[48 * 64];
  int t = threadIdx.x;
  int b = lb >> 8;
  int p0 = (lb & 255) << 6;
  int ibase = b * 48 * HW + p0;
  #pragma unroll
  for (int i = 0; i < 12; i++) {
    int idx = i * 256 + t;
    int c = idx >> 6, p = idx & 63;
    vs[idx] = ldf(in, ibase + c * HW + p);
  }
  __syncthreads();
  int p = t & 63;
  int og = __builtin_amdgcn_readfirstlane(t >> 6);   // wave-uniform 0..3
  const float* Wcol = wt + (perb ? b * 2304 : 0) + og * 12;
  float acc[12];
  #pragma unroll
  for (int j = 0; j < 12; j++) acc[j] = 0.f;
  for (int c = 0; c < 48; c++) {
    float v = vs[c * 64 + p];
    const float* wc = Wcol + c * wstride;
    #pragma unroll
    for (int j = 0; j < 12; j++) acc[j] += wc[j] * v;
  }
  bf16* op = out + (size_t)b * 48 * HW + p0 + p;
  #pragma unroll
  for (int j = 0; j < 12; j++) op[(size_t)(og * 12 + j) * HW] = tob(acc[j]);
}

// ---- fused x->KV conv v2: 8 waves x 24 outputs, one x staging ----
// wave wid: buf = wid>>1 (HK,HV,LK,LV), 24-ch half = wid&1.
__global__ void __launch_bounds__(512) convxkv_k(const void* __restrict__ in,
                                                 bf16* __restrict__ o0, bf16* __restrict__ o1,
                                                 bf16* __restrict__ o2, bf16* __restrict__ o3,
                                                 const float* __restrict__ P,
                                                 const int* flagp) {
  int bf = flagp[0];
  __shared__ float vs[48 * 64];
  int t = threadIdx.x;
  int blk = blockIdx.x;                // B * 256
  int b = blk >> 8;
  int p0 = (blk & 255) << 6;
  int ibase = b * 48 * HW + p0;
  #pragma unroll
  for (int i = 0; i < 6; i++) {
    int idx = i * 512 + t;             // 3072 = 48*64
    int c = idx >> 6, p = idx & 63;
    vs[idx] = ldx(in, ibase + c * HW + p, bf);
  }
  __syncthreads();
  int p = t & 63;
  int wid = __builtin_amdgcn_readfirstlane(t >> 6);  // wave-uniform 0..7
  int buf = wid >> 1;
  int half24 = (wid & 1) * 24;
  const float* Wcol = P + (buf < 2 ? O_HKVW : O_LKVW) + (buf & 1) * 48 + half24;
  bf16* ob = (buf == 0 ? o0 : buf == 1 ? o1 : buf == 2 ? o2 : o3);
  bf16* op = ob + (size_t)b * 48 * HW + (size_t)half24 * HW + p0 + p;
  float acc[24];
  #pragma unroll
  for (int j = 0; j < 24; j++) acc[j] = 0.f;
  for (int c = 0; c < 48; c++) {
    float v = vs[c * 64 + p];
    const float* wc = Wcol + c * 96;
    #pragma unroll
    for (int j = 0; j < 24; j++) acc[j] += wc[j] * v;
  }
  #pragma unroll
  for (int j = 0; j < 24; j++) op[(size_t)j * HW] = tob(acc[j]);
}

// ---- depthwise 3x3 octet helper: 8 px/thread, 16B row loads ----
DI void dw_oct(const bf16* __restrict__ p, const float* __restrict__ w,
               int c, int h, int w0, float acc[8]) {
  #pragma unroll
  for (int i = 0; i < 3; i++) {
    int hh = h + i - 1;
    if (hh < 0 || hh >= H) continue;
    const bf16* row = p + hh * W + w0;
    uint4 u = *(const uint4*)row;              // 16B-aligned (w0 % 8 == 0)
    float v[10];
    v[1] = u2f((unsigned short)(u.x & 0xFFFF)); v[2] = u2f((unsigned short)(u.x >> 16));
    v[3] = u2f((unsigned short)(u.y & 0xFFFF)); v[4] = u2f((unsigned short)(u.y >> 16));
    v[5] = u2f((unsigned short)(u.z & 0xFFFF)); v[6] = u2f((unsigned short)(u.z >> 16));
    v[7] = u2f((unsigned short)(u.w & 0xFFFF)); v[8] = u2f((unsigned short)(u.w >> 16));
    v[0] = (w0 > 0) ? ldf(row, -1) : 0.f;
    v[9] = (w0 + 8 < W) ? ldf(row, 8) : 0.f;
    #pragma unroll
    for (int j = 0; j < 3; j++) {
      float wt = w[c * 9 + i * 3 + j];
      #pragma unroll
      for (int q = 0; q < 8; q++) acc[q] += wt * v[q + j];
    }
  }
}

DI void dw_store8(bf16* __restrict__ out, int idx8, const float acc[8]) {
  uint4 o;
  o.x = (unsigned)b2u(tob(acc[0])) | ((unsigned)b2u(tob(acc[1])) << 16);
  o.y = (unsigned)b2u(tob(acc[2])) | ((unsigned)b2u(tob(acc[3])) << 16);
  o.z = (unsigned)b2u(tob(acc[4])) | ((unsigned)b2u(tob(acc[5])) << 16);
  o.w = (unsigned)b2u(tob(acc[6])) | ((unsigned)b2u(tob(acc[7])) << 16);
  *(uint4*)(out + (size_t)idx8 * 8) = o;
}

// ---- paired depthwise 3x3 v2: 8 px/thread, two plane sets ----
__global__ void dw3x3x2_k(const bf16* __restrict__ in1, bf16* __restrict__ out1,
                          const bf16* __restrict__ in2, bf16* __restrict__ out2,
                          const float* __restrict__ w1, const float* __restrict__ w2) {
  int idx8 = blockIdx.x * 256 + threadIdx.x;   // octet index over NCHW/8
  int w0 = (idx8 & 15) << 3;                   // W/8 = 16
  int h = (idx8 >> 4) & (H - 1);
  int plane = idx8 >> 11;                      // HW/8 = 2048
  int c = plane % 48;
  float a1[8] = {0,0,0,0,0,0,0,0};
  dw_oct(in1 + (size_t)plane * HW, w1, c, h, w0, a1);
  dw_store8(out1, idx8, a1);
  float a2[8] = {0,0,0,0,0,0,0,0};
  dw_oct(in2 + (size_t)plane * HW, w2, c, h, w0, a2);
  dw_store8(out2, idx8, a2);
}

// ---- quad depthwise 3x3 v2: 8 px/thread, four plane sets ----
__global__ void dw3x3q_k(const bf16* __restrict__ i1, bf16* __restrict__ u1,
                         const bf16* __restrict__ i2, bf16* __restrict__ u2,
                         const bf16* __restrict__ i3, bf16* __restrict__ u3,
                         const bf16* __restrict__ i4, bf16* __restrict__ u4,
                         const float* __restrict__ w1, const float* __restrict__ w2,
                         const float* __restrict__ w3, const float* __restrict__ w4) {
  int idx8 = blockIdx.x * 256 + threadIdx.x;
  int w0 = (idx8 & 15) << 3;
  int h = (idx8 >> 4) & (H - 1);
  int plane = idx8 >> 11;
  int c = plane % 48;
  float a[8];
  #pragma unroll
  for (int q = 0; q < 8; q++) a[q] = 0.f;
  dw_oct(i1 + (size_t)plane * HW, w1, c, h, w0, a);
  dw_store8(u1, idx8, a);
  #pragma unroll
  for (int q = 0; q < 8; q++) a[q] = 0.f;
  dw_oct(i2 + (size_t)plane * HW, w2, c, h, w0, a);
  dw_store8(u2, idx8, a);
  #pragma unroll
  for (int q = 0; q < 8; q++) a[q] = 0.f;
  dw_oct(i3 + (size_t)plane * HW, w3, c, h, w0, a);
  dw_store8(u3, idx8, a);
  #pragma unroll
  for (int q = 0; q < 8; q++) a[q] = 0.f;
  dw_oct(i4 + (size_t)plane * HW, w4, c, h, w0, a);
  dw_store8(u4, idx8, a);
}

// ---- attn gram dual: grid = 2 * 32 bh * NCHUNK ----
__global__ void __launch_bounds__(256) attn_part_k(const bf16* __restrict__ q0,
                                                   const bf16* __restrict__ k0,
                                                   const bf16* __restrict__ q1,
                                                   const bf16* __restrict__ k1,
                                                   float* __restrict__ partial) {
  int blk = blockIdx.x;
  int half = blk >> 11;
  int lb = blk & 2047;
  const bf16* q = half ? q1 : q0;
  const bf16* kbuf = half ? k1 : k0;
  float* part = partial + (size_t)half * PARTSZ;
  int bh = lb >> 6, chunk = lb & (NCHUNK - 1);
  int b = bh >> 2, hd = bh & 3;
  int t = threadIdx.x;
  int l0 = chunk * 256;
  __shared__ float qs[12 * 257], ks[12 * 257];
  const bf16* qb = q + (size_t)(b * 48 + hd * 12) * HW + l0;
  const bf16* kb = kbuf + (size_t)(b * 48 + hd * 12) * HW + l0;
  #pragma unroll
  for (int m = 0; m < 12; m++) {
    qs[m * 257 + t] = ldf(qb, m * HW + t);
    ks[m * 257 + t] = ldf(kb, m * HW + t);
  }
  __syncthreads();
  float acc = 0.f;
  if (t < 144) {
    const float* qr = qs + (t / 12) * 257;
    const float* kr = ks + (t % 12) * 257;
    #pragma unroll 4
    for (int j = 0; j < 256; j++) acc += qr[j] * kr[j];
  } else if (t < 156) {
    const float* qr = qs + (t - 144) * 257;
    #pragma unroll 4
    for (int j = 0; j < 256; j++) acc += qr[j] * qr[j];
  } else if (t < 168) {
    const float* kr = ks + (t - 156) * 257;
    #pragma unroll 4
    for (int j = 0; j < 256; j++) acc += kr[j] * kr[j];
  }
  if (t < 168) part[(size_t)(chunk * 32 + bh) * 168 + t] = acc;
}

// ---- dual: reduce partials + softmax + fused projection matrix ----
// grid = 64: half = blk>>5 (high/low), bh = blk&31.
// M[half][b][dg][o] = sum_c attn_hd[c][d] * PWt[(hd*12+c)*48 + o]
__global__ void __launch_bounds__(256) attn_finM_k(const float* __restrict__ partial,
                                                   const float* __restrict__ P,
                                                   float* __restrict__ M) {
  int blk = blockIdx.x;
  int half = blk >> 5;
  int bh = blk & 31, b = bh >> 2, hd = bh & 3;
  const float* part = partial + (size_t)half * PARTSZ;
  const float* temp = P + (half ? O_LT : O_HT);
  const float* pwt = P + (half ? O_LPW : O_HPW);
  float* Mh = M + (size_t)half * 8 * 2304;
  int t = threadIdx.x;
  __shared__ float red[168];
  __shared__ float sm[144];              // sm[c*12 + d]
  if (t < 168) {
    float s = 0.f;
    for (int ch = 0; ch < NCHUNK; ch++) s += part[(size_t)(ch * 32 + bh) * 168 + t];
    red[t] = s;
  }
  __syncthreads();
  if (t < 12) {
    float tm = temp[hd];
    float rq = 1.f / fmaxf(sqrtf(red[144 + t]), 1e-12f);
    float vals[12], mx = -1e30f;
    #pragma unroll
    for (int d = 0; d < 12; d++) {
      float rk = 1.f / fmaxf(sqrtf(red[156 + d]), 1e-12f);
      vals[d] = red[t * 12 + d] * rq * rk * tm;
      mx = fmaxf(mx, vals[d]);
    }
    float s = 0.f;
    #pragma unroll
    for (int d = 0; d < 12; d++) { vals[d] = expf(vals[d] - mx); s += vals[d]; }
    float inv = 1.f / s;
    #pragma unroll
    for (int d = 0; d < 12; d++) sm[t * 12 + d] = vals[d] * inv;
  }
  __syncthreads();
  for (int e = t; e < 576; e += 256) {   // 12 d-rows x 48 outputs
    int d = e / 48, o = e - d * 48;
    float s = 0.f;
    #pragma unroll
    for (int c = 0; c < 12; c++) s += sm[c * 12 + d] * pwt[(hd * 12 + c) * 48 + o];
    Mh[(size_t)b * 2304 + (hd * 12 + d) * 48 + o] = s;
  }
}

// ---- final v2t: 64 px/block, 4 waves x 12 outputs, transposed weights ----
__global__ void __launch_bounds__(256) conv_final_k(const bf16* __restrict__ ho,
                                                    const bf16* __restrict__ lo,
                                                    const float* __restrict__ P,
                                                    const void* __restrict__ x,
                                                    void* __restrict__ out,
                                                    const int* flagp) {
  int bf = flagp[0];
  __shared__ float vs[96 * 64];
  int t = threadIdx.x;
  int blk = blockIdx.x;                // B * 256
  int b = blk >> 8;
  int p0 = (blk & 255) << 6;
  int pbase = b * 48 * HW + p0;
  #pragma unroll
  for (int i = 0; i < 12; i++) {
    int idx = i * 256 + t;
    int c = idx >> 6, p = idx & 63;
    vs[idx] = ldf(ho, pbase + c * HW + p);
    vs[48 * 64 + idx] = ldf(lo, pbase + c * HW + p);
  }
  __syncthreads();
  int p = t & 63;
  int og = __builtin_amdgcn_readfirstlane(t >> 6);   // wave-uniform 0..3
  const float* Wcol = P + O_FPW + og * 12;           // transposed: [c*48 + j]
  float acc[12];
  #pragma unroll
  for (int j = 0; j < 12; j++) acc[j] = 0.f;
  for (int c = 0; c < 96; c++) {
    float v = vs[c * 64 + p];
    const float* wc = Wcol + c * 48;
    #pragma unroll
    for (int j = 0; j < 12; j++) acc[j] += wc[j] * v;
  }
  #pragma unroll
  for (int j = 0; j < 12; j++) {
    int o = og * 12 + j;
    int oi = pbase + o * HW + p;
    float val = acc[j] + P[O_FPB + o] + ldx(x, oi, bf);
    if (bf) ((bf16*)out)[oi] = tob(val);
    else    ((float*)out)[oi] = val;
  }
}

extern "C" void kernel_launch(void* const* d_in, const int* in_sizes, int n_in,
                              void* d_out, int out_size, void* d_ws, size_t ws_size,
                              hipStream_t stream) {
  const void* x = d_in[0];

  // ws layout (fp32 units): ap@0, flag@7000, params@8192 (ends 47224),
  // wts@48000, Mbuf@50000 (2*8*2304 -> ends 86864),
  // parts@90000 (2*PARTSZ -> ends 778128), bf16 planes P0..P9 @800000
  float* ws    = (float*)d_ws;
  float* ap    = ws;
  int*   flagp = (int*)(ws + 7000);
  float* P     = ws + 8192;
  float* wts   = ws + 48000;
  float* Mbuf  = ws + 50000;
  float* parts = ws + 90000;
  bf16* base = (bf16*)(ws + 800000);
  bf16* P0 = base;                       // hf -> ho
  bf16* P1 = base + (size_t)NCHW;        // lf -> lo
  bf16* P2 = base + (size_t)2 * NCHW;    // spec / HKpre / HQpre
  bf16* P3 = base + (size_t)3 * NCHW;    // spec / HVpre / HQ
  bf16* P4 = base + (size_t)4 * NCHW;    // spec / LKpre / LQpre
  bf16* P5 = base + (size_t)5 * NCHW;    // LVpre / LQ
  bf16* P6 = base + (size_t)6 * NCHW;    // HK
  bf16* P7 = base + (size_t)7 * NCHW;    // HV
  bf16* P8 = base + (size_t)8 * NCHW;    // LK
  bf16* P9 = base + (size_t)9 * NCHW;    // LV
  float* spec = (float*)P2;

  // ---- dtype detect + param convert (matmul weights transposed) ----
  detect_k<<<1, 256, 0, stream>>>(x, flagp);
  ParamTab tab;
  const int offs[25] = {O_FDW, O_BNG, O_BNB, O_BNM, O_BNV,
                        O_FHW1, O_FHB1, O_FHW2, O_FHB2,
                        O_FLW, O_FLB,
                        O_HQW, O_HKVW, O_HQDW, O_HKVDW, O_HPW, O_HT,
                        O_LQW, O_LKVW, O_LQDW, O_LKVDW, O_LPW, O_LT,
                        O_FPW, O_FPB};
  const int cnts[25] = {3456, 72, 72, 72, 72,
                        144, 48, 144, 48,
                        9216, 96,
                        2304, 4608, 432, 864, 2304, 4,
                        2304, 4608, 432, 864, 2304, 4,
                        4608, 48};
  const int rows[25] = {0, 0, 0, 0, 0,
                        0, 0, 0, 0,
                        96, 0,
                        48, 96, 0, 0, 48, 0,
                        48, 96, 0, 0, 48, 0,
                        48, 0};
  for (int i = 0; i < 25; i++) {
    tab.src[i] = d_in[i + 1]; tab.off[i] = offs[i]; tab.cnt[i] = cnts[i]; tab.rows[i] = rows[i];
  }
  cvt_params_k<<<25, 256, 0, stream>>>(tab, flagp, P);

  // ---- fd ----
  reduce_mean_k<<<B * C, 256, 0, stream>>>(x, ap, flagp);
  fd_weights_k<<<B, 128, 0, stream>>>(ap, P, wts);
  fd_apply_k<<<NCHW / 1024, 256, 0, stream>>>(x, wts, P1, P3, flagp); // low->P1, high->P3
  // ---- fmgm_high ----
  fmgm_high_k<<<NCHW / 1024, 256, 0, stream>>>(P3, P, P0);            // hf->P0
  // ---- fmgm_low: rfft2 -> gate -> irfft2 (spec overlays P2..P4) ----
  rfft_row_k<<<B * C * H / 4, 256, 0, stream>>>(P1, spec);
  fft_col_k<<<B * C * 2, 256, 0, stream>>>(spec, -1.f, 1.f);
  freq_gate_k<<<B * (SPECHW / 64), 256, 0, stream>>>(spec, P);
  fft_col_k<<<B * C * 2, 256, 0, stream>>>(spec, 1.f, 1.f / 128.f);
  irfft_row_k<<<B * C * H / 4, 256, 0, stream>>>(spec, P1);           // lf->P1
  // ---- fused x->KV conv (spec dead) + quad depthwise ----
  convxkv_k<<<B * 256, 512, 0, stream>>>(x, P2, P3, P4, P5, P, flagp);
  dw3x3q_k<<<NCHW / 2048, 256, 0, stream>>>(P2, P6, P3, P7, P4, P8, P5, P9,
                                            P + O_HKVDW, P + O_HKVDW + 48 * 9,
                                            P + O_LKVDW, P + O_LKVDW + 48 * 9);
  // ---- both q-paths dual (P2..P5 free after dw3x3q) ----
  conv1x1d_k<<<2 * B * 256, 256, 0, stream>>>(P0, P2, P + O_HQW,
                                              P1, P4, P + O_LQW, 48, 0);
  dw3x3x2_k<<<NCHW / 2048, 256, 0, stream>>>(P2, P3, P4, P5,
                                             P + O_HQDW, P + O_LQDW);
  // ---- attention (both branches in each launch) ----
  attn_part_k<<<2 * 32 * NCHUNK, 256, 0, stream>>>(P3, P6, P5, P8, parts);
  attn_finM_k<<<64, 256, 0, stream>>>(parts, P, Mbuf);
  conv1x1d_k<<<2 * B * 256, 256, 0, stream>>>(P7, P0, Mbuf,
                                              P9, P1, Mbuf + 8 * 2304, 48, 1);
  // ---- final 1x1 + bias + residual ----
  conv_final_k<<<B * 256, 256, 0, stream>>>(P0, P1, P, x, d_out, flagp);
}

// Round 9
// 486.253 us; speedup vs baseline: 2.0754x; 1.0692x over previous
//
#include <hip/hip_runtime.h>
#include <hip/hip_bf16.h>
#include <math.h>

using bf16 = __hip_bfloat16;
#define DI __device__ __forceinline__

typedef __attribute__((ext_vector_type(8))) short short8v;   // 8 bf16 (4 VGPRs)
typedef __attribute__((ext_vector_type(4))) float f32x4;

namespace {
constexpr int B = 8, C = 48, H = 128, W = 128;
constexpr int HW = H * W;                 // 16384
constexpr int NCHW = B * C * HW;          // 6,291,456
constexpr int C2 = 96;
constexpr int WF = 65;                    // rfft width
constexpr int SPECHW = H * WF;            // 8320 (divisible by 64)
constexpr int SPECN = B * C2 * SPECHW;    // 6,389,760 floats
// spec (fp32) overlays planes P2+P3+P4 = 3*NCHW bf16 slots
static_assert((size_t)SPECN * 4 <= (size_t)3 * NCHW * 2, "spec must fit in P2..P4 overlay");
static_assert(SPECHW % 64 == 0, "freq_gate 64-pixel blocks must not straddle batches");

// fp32 param header offsets (in floats), base = ws + 8192
// NOTE: matmul weights (FLW, *QW, *KVW, *PW, FPW) are stored TRANSPOSED
// (input-major): wt[c*rows + o]. Depthwise/BN/bias params stay plain.
constexpr int O_FDW = 0,    O_BNG = 3456, O_BNB = 3528, O_BNM = 3600, O_BNV = 3672;
constexpr int O_FHW1 = 3744, O_FHB1 = 3888, O_FHW2 = 3936, O_FHB2 = 3984;
constexpr int O_FLW = 4032,  O_FLB = 13248;
constexpr int O_HQW = 13344, O_HKVW = 15648, O_HQDW = 20256, O_HKVDW = 20688, O_HPW = 21552, O_HT = 23856;
constexpr int O_LQW = 23860, O_LKVW = 26164, O_LQDW = 30772, O_LKVDW = 31204, O_LPW = 32068, O_LT = 34372;
constexpr int O_FPW = 34376, O_FPB = 38984;  // end 39032

constexpr int NCHUNK = 64;                // L split for attn gram
constexpr int PARTSZ = 32 * NCHUNK * 168; // per-branch partials (344064 floats)
}

DI float ldf(const float* p, int i) { return p[i]; }
DI float ldf(const bf16* p, int i) { return __bfloat162float(p[i]); }
DI bf16 tob(float x) { return __float2bfloat16(x); }
DI unsigned short b2u(bf16 v) { union { bf16 b; unsigned short u; } x; x.b = v; return x.u; }
DI float u2f(unsigned short u) { return __uint_as_float((unsigned)u << 16); }
DI float ldx(const void* p, int i, int bf) {
  return bf ? __bfloat162float(((const bf16*)p)[i]) : ((const float*)p)[i];
}
DI float geluf(float x) { return 0.5f * x * (1.f + erff(x * 0.70710678118654752f)); }
DI int refl(int i, int n) { return i < 0 ? -i : (i >= n ? 2 * n - 2 - i : i); }

// ---- dtype detector: bf16 data -> even u16 slots have sane exponents ----
__global__ void detect_k(const void* x, int* flagp) {
  const unsigned short* u = (const unsigned short*)x;
  int t = threadIdx.x;
  int good = 0;
  for (int i = t; i < 1024; i += 256) {
    unsigned short v = u[2 * i];
    int e = (v >> 7) & 0xFF;
    if (e >= 100 && e <= 140) good++;
  }
  __shared__ int cnt;
  if (t == 0) cnt = 0;
  __syncthreads();
  atomicAdd(&cnt, good);
  __syncthreads();
  if (t == 0) flagp[0] = (cnt > 512) ? 1 : 0;
}

// ---- convert all params to fp32 header; matmul weights transposed ----
struct ParamTab { const void* src[25]; int off[25]; int cnt[25]; int rows[25]; };
__global__ void cvt_params_k(ParamTab tab, const int* flagp, float* dst) {
  int bf = flagp[0];
  int b = blockIdx.x;
  const void* s = tab.src[b];
  float* d = dst + tab.off[b];
  int n = tab.cnt[b];
  int rows = tab.rows[b];
  if (rows == 0) {
    for (int i = threadIdx.x; i < n; i += 256) d[i] = ldx(s, i, bf);
  } else {
    int cols = n / rows;
    for (int i = threadIdx.x; i < n; i += 256)
      d[(i % cols) * rows + (i / cols)] = ldx(s, i, bf);
  }
}

// ---- fd: channel means, v2: vector loads ----
__global__ void reduce_mean_k(const void* __restrict__ x, float* __restrict__ ap,
                              const int* flagp) {
  int bf = flagp[0];
  int bc = blockIdx.x;
  float s = 0.f;
  if (bf) {
    const ushort4* xp = (const ushort4*)((const bf16*)x + (size_t)bc * HW);
    for (int i = threadIdx.x; i < HW / 4; i += 256) {
      ushort4 u = xp[i];
      s += u2f(u.x) + u2f(u.y) + u2f(u.z) + u2f(u.w);
    }
  } else {
    const float4* xp = (const float4*)((const float*)x + (size_t)bc * HW);
    for (int i = threadIdx.x; i < HW / 4; i += 256) {
      float4 u = xp[i];
      s += u.x + u.y + u.z + u.w;
    }
  }
  #pragma unroll
  for (int o = 32; o > 0; o >>= 1) s += __shfl_down(s, o);
  __shared__ float r[4];
  if ((threadIdx.x & 63) == 0) r[threadIdx.x >> 6] = s;
  __syncthreads();
  if (threadIdx.x == 0) ap[bc] = (r[0] + r[1] + r[2] + r[3]) * (1.f / HW);
}

// ---- fd: 72-wide linear + BN + per-group softmax over 9 ----
__global__ void fd_weights_k(const float* __restrict__ ap, const float* __restrict__ P,
                             float* __restrict__ wts) {
  int n = blockIdx.x, t = threadIdx.x;
  __shared__ float vals[72], es[72];
  if (t < 72) {
    float acc = 0.f;
    for (int c = 0; c < C; c++) acc += P[O_FDW + t * C + c] * ap[n * C + c];
    acc = (acc - P[O_BNM + t]) * rsqrtf(P[O_BNV + t] + 1e-5f);
    vals[t] = acc * P[O_BNG + t] + P[O_BNB + t];
  }
  __syncthreads();
  if (t < 72) {
    int base = (t / 9) * 9;
    float mx = -1e30f;
    for (int k = 0; k < 9; k++) mx = fmaxf(mx, vals[base + k]);
    es[t] = expf(vals[t] - mx);
  }
  __syncthreads();
  if (t < 72) {
    int base = (t / 9) * 9;
    float s = 0.f;
    for (int k = 0; k < 9; k++) s += es[base + k];
    wts[n * 72 + t] = es[t] / s;
  }
}

// ---- fd v2: involution low-pass (reflect pad), 4 px/thread, vector rows ----
__global__ void fd_apply_k(const void* __restrict__ x, const float* __restrict__ wts,
                           bf16* __restrict__ low, bf16* __restrict__ high,
                           const int* flagp) {
  int bf = flagp[0];
  int idx4 = blockIdx.x * 256 + threadIdx.x;   // quad index over NCHW/4
  int w0 = (idx4 & 31) << 2;                   // W/4 = 32
  int h = (idx4 >> 5) & (H - 1);
  int plane = idx4 >> 12;                      // b*C + c
  int c = plane % C;
  int b = plane / C;
  const float* wt = wts + b * 72 + (c / 6) * 9;
  size_t pbase = (size_t)plane * HW;
  float acc[4] = {0.f, 0.f, 0.f, 0.f};
  float ctr[4];
  #pragma unroll
  for (int i = 0; i < 3; i++) {
    int hh = refl(h + i - 1, H);
    float v[6];
    if (bf) {
      const bf16* row = (const bf16*)x + pbase + hh * W + w0;
      ushort4 u = *(const ushort4*)row;        // 8B aligned
      v[1] = u2f(u.x); v[2] = u2f(u.y); v[3] = u2f(u.z); v[4] = u2f(u.w);
      v[0] = (w0 > 0) ? ldf(row, -1) : v[2];
      v[5] = (w0 + 4 < W) ? ldf(row, 4) : v[3];
    } else {
      const float* row = (const float*)x + pbase + hh * W + w0;
      float4 u = *(const float4*)row;          // 16B aligned
      v[1] = u.x; v[2] = u.y; v[3] = u.z; v[4] = u.w;
      v[0] = (w0 > 0) ? row[-1] : v[2];
      v[5] = (w0 + 4 < W) ? row[4] : v[3];
    }
    if (i == 1) { ctr[0] = v[1]; ctr[1] = v[2]; ctr[2] = v[3]; ctr[3] = v[4]; }
    #pragma unroll
    for (int j = 0; j < 3; j++) {
      float wv = wt[i * 3 + j];
      #pragma unroll
      for (int q = 0; q < 4; q++) acc[q] += wv * v[q + j];
    }
  }
  ushort4 ol, oh;
  ol.x = b2u(tob(acc[0])); ol.y = b2u(tob(acc[1]));
  ol.z = b2u(tob(acc[2])); ol.w = b2u(tob(acc[3]));
  oh.x = b2u(tob(ctr[0] - acc[0])); oh.y = b2u(tob(ctr[1] - acc[1]));
  oh.z = b2u(tob(ctr[2] - acc[2])); oh.w = b2u(tob(ctr[3] - acc[3]));
  *(ushort4*)(low + (size_t)idx4 * 4) = ol;
  *(ushort4*)(high + (size_t)idx4 * 4) = oh;
}

// ---- fmgm_high v2: fused (1x3)->(3x1) dwconv -> gelu * x, 4 px/thread ----
__global__ void fmgm_high_k(const bf16* __restrict__ hi, const float* __restrict__ P,
                            bf16* __restrict__ out) {
  int idx4 = blockIdx.x * 256 + threadIdx.x;   // quad index over NCHW/4
  int w0 = (idx4 & 31) << 2;
  int h = (idx4 >> 5) & (H - 1);
  int plane = idx4 >> 12;
  int c = plane % C;
  const bf16* p = hi + (size_t)plane * HW;
  float k1[3], k2[3];
  #pragma unroll
  for (int j = 0; j < 3; j++) { k1[j] = P[O_FHW1 + c * 3 + j]; k2[j] = P[O_FHW2 + c * 3 + j]; }
  float b1 = P[O_FHB1 + c];
  float b2 = P[O_FHB2 + c];
  float acc[4] = {b2, b2, b2, b2};
  float ctr[4];
  #pragma unroll
  for (int i = 0; i < 3; i++) {
    int hh = h + i - 1;
    if (hh < 0 || hh >= H) continue;
    const bf16* row = p + hh * W + w0;
    ushort4 u = *(const ushort4*)row;          // 8B aligned
    float v[6];
    v[1] = u2f(u.x); v[2] = u2f(u.y); v[3] = u2f(u.z); v[4] = u2f(u.w);
    v[0] = (w0 > 0) ? ldf(row, -1) : 0.f;      // zero pad
    v[5] = (w0 + 4 < W) ? ldf(row, 4) : 0.f;
    if (i == 1) { ctr[0] = v[1]; ctr[1] = v[2]; ctr[2] = v[3]; ctr[3] = v[4]; }
    float kk = k2[i];
    #pragma unroll
    for (int q = 0; q < 4; q++) {
      float y1 = b1 + k1[0] * v[q] + k1[1] * v[q + 1] + k1[2] * v[q + 2];
      acc[q] += kk * y1;
    }
  }
  ushort4 o;
  o.x = b2u(tob(geluf(acc[0]) * ctr[0]));
  o.y = b2u(tob(geluf(acc[1]) * ctr[1]));
  o.z = b2u(tob(geluf(acc[2]) * ctr[2]));
  o.w = b2u(tob(geluf(acc[3]) * ctr[3]));
  *(ushort4*)(out + (size_t)idx4 * 4) = o;
}

// ---- rfft along W, v3: lane-parallel radix-2 FFT64 (shuffle butterflies) ----
__global__ void __launch_bounds__(256) rfft_row_k(const bf16* __restrict__ low,
                                                  float* __restrict__ spec) {
  int t = threadIdx.x;
  int wid = t >> 6, l = t & 63;
  int row = blockIdx.x * 4 + wid;        // in [0, B*C*H)
  int h = row & (H - 1);
  int bc = row >> 7;
  int c = bc % C, b = bc / C;
  const unsigned* xr = (const unsigned*)(low + (size_t)row * W);
  unsigned v2 = xr[l];                   // two bf16: elems 2l, 2l+1
  float zr = __uint_as_float(v2 << 16);
  float zi = __uint_as_float(v2 & 0xFFFF0000u);
  #pragma unroll
  for (int s = 0; s < 6; s++) {
    int d = 32 >> s;
    float pr = __shfl_xor(zr, d);
    float pi = __shfl_xor(zi, d);
    float a = (float)(l & (d - 1)) / (float)d;
    float wr = cospif(a), wi = -sinpif(a);
    float sr = zr + pr, si = zi + pi;
    float dr = pr - zr, di = pi - zi;
    float mr2 = dr * wr - di * wi;
    float mi2 = dr * wi + di * wr;
    bool hib = (l & d) != 0;
    zr = hib ? mr2 : sr;
    zi = hib ? mi2 : si;
  }
  int rl = __brev(l) >> 26;
  int lm = (64 - l) & 63;
  int rm = __brev(lm) >> 26;
  float Zkr = __shfl(zr, rl), Zki = __shfl(zi, rl);
  float Zmr = __shfl(zr, rm), Zmi = __shfl(zi, rm);
  float Fer = 0.5f * (Zkr + Zmr), Fei = 0.5f * (Zki - Zmi);
  float Dr  = 0.5f * (Zkr - Zmr), Di  = 0.5f * (Zki + Zmi);
  float For = Di, Foi = -Dr;             // D / i
  float a = (float)l * (1.f / 64.f);
  float tr = cospif(a), ti = -sinpif(a); // e^{-2 pi i l / 128}
  float Xr = Fer + tr * For - ti * Foi;
  float Xi = Fei + tr * Foi + ti * For;
  size_t o = ((size_t)(b * C2 + c) * H + h) * WF + l;
  size_t ioff = (size_t)C * H * WF;
  spec[o] = Xr;
  spec[o + ioff] = Xi;
  if (l == 0) {                          // k = 64 (Nyquist)
    spec[o + 64] = Fer - For;
    spec[o + 64 + ioff] = 0.f;
  }
}

// ---- complex FFT-128 along H, v6: lane-parallel radix-2, LDS tile ----
__global__ void __launch_bounds__(256) fft_col_k(float* __restrict__ spec,
                                                 float sgn, float scale) {
  __shared__ float re_s[128 * 33], im_s[128 * 33];   // 33.8 KB, stride 33
  int t = threadIdx.x;
  int half = blockIdx.x & 1;
  int bc = blockIdx.x >> 1;
  int cc = bc % C, b = bc / C;
  size_t reb = ((size_t)(b * C2 + cc) * H) * WF;
  size_t imb = reb + (size_t)C * H * WF;
  int ncol = half ? 33 : 32;
  if (half == 0) {
    #pragma unroll
    for (int i = 0; i < 16; i++) {
      int idx = i * 256 + t;             // 4096 = 128*32
      int r = idx >> 5, c = idx & 31;
      re_s[r * 33 + c] = spec[reb + r * WF + c];
      im_s[r * 33 + c] = spec[imb + r * WF + c];
    }
  } else {
    #pragma unroll
    for (int i = 0; i < 17; i++) {
      int idx = i * 256 + t;             // 4352 >= 128*33
      if (idx < 128 * 33) {
        int r = idx / 33, c = idx - r * 33;
        re_s[r * 33 + c] = spec[reb + r * WF + 32 + c];
        im_s[r * 33 + c] = spec[imb + r * WF + 32 + c];
      }
    }
  }
  __syncthreads();
  int w = t >> 6, l = t & 63;
  float cA = cospif((float)l * (1.f / 64.f));
  float sA = sinpif((float)l * (1.f / 64.f)) * sgn;  // e^{sgn*2pi i l/128}
  float cs[6], ss[6];
  #pragma unroll
  for (int s = 0; s < 6; s++) {
    int d = 32 >> s;
    float a = (float)(l & (d - 1)) / (float)d;
    cs[s] = cospif(a); ss[s] = sinpif(a) * sgn;
  }
  int br = __brev(l) >> 26;
  for (int c = w; c < ncol; c += 4) {
    float ar = re_s[l * 33 + c],         ai = im_s[l * 33 + c];
    float xr = re_s[(l + 64) * 33 + c],  xi = im_s[(l + 64) * 33 + c];
    float ur = ar + xr, ui = ai + xi;                // -> even freqs
    float tr = ar - xr, ti = ai - xi;
    float vr = tr * cA - ti * sA;                    // -> odd freqs
    float vi = tr * sA + ti * cA;
    #pragma unroll
    for (int s = 0; s < 6; s++) {
      int d = 32 >> s;
      float pr = __shfl_xor(ur, d), pi = __shfl_xor(ui, d);
      float qr = __shfl_xor(vr, d), qi = __shfl_xor(vi, d);
      float sur = ur + pr, sui = ui + pi;
      float dur = pr - ur, dui = pi - ui;
      float svr = vr + qr, svi = vi + qi;
      float dvr = qr - vr, dvi = qi - vi;
      float mur = dur * cs[s] - dui * ss[s];
      float mui = dur * ss[s] + dui * cs[s];
      float mvr = dvr * cs[s] - dvi * ss[s];
      float mvi = dvr * ss[s] + dvi * cs[s];
      bool hib = (l & d) != 0;
      ur = hib ? mur : sur; ui = hib ? mui : sui;
      vr = hib ? mvr : svr; vi = hib ? mvi : svi;
    }
    int r0 = 2 * br;                     // X[2*br] = U-res, X[2*br+1] = V-res
    re_s[r0 * 33 + c] = ur * scale;       im_s[r0 * 33 + c] = ui * scale;
    re_s[(r0 + 1) * 33 + c] = vr * scale; im_s[(r0 + 1) * 33 + c] = vi * scale;
  }
  __syncthreads();
  if (half == 0) {
    #pragma unroll
    for (int i = 0; i < 16; i++) {
      int idx = i * 256 + t;
      int r = idx >> 5, c = idx & 31;
      spec[reb + r * WF + c] = re_s[r * 33 + c];
      spec[imb + r * WF + c] = im_s[r * 33 + c];
    }
  } else {
    #pragma unroll
    for (int i = 0; i < 17; i++) {
      int idx = i * 256 + t;
      if (idx < 128 * 33) {
        int r = idx / 33, c = idx - r * 33;
        spec[reb + r * WF + 32 + c] = re_s[r * 33 + c];
        spec[imb + r * WF + 32 + c] = im_s[r * 33 + c];
      }
    }
  }
}

// ---- freq-domain channel-mix gate: yf *= gelu(W yf + b) ----
__global__ void __launch_bounds__(256) freq_gate_k(float* __restrict__ spec,
                                                   const float* __restrict__ P) {
  __shared__ float vs[96 * 65];
  int t = threadIdx.x;
  int blk = blockIdx.x;
  int b = blk / (SPECHW / 64);
  int pp0 = (blk % (SPECHW / 64)) * 64;
  float* sb = spec + (size_t)b * C2 * SPECHW + pp0;
  #pragma unroll
  for (int i = 0; i < 24; i++) {
    int idx = i * 256 + t;
    int c = idx >> 6, p = idx & 63;
    vs[c * 65 + p] = sb[(size_t)c * SPECHW + p];
  }
  __syncthreads();
  int p = t & 63;
  int og = __builtin_amdgcn_readfirstlane(t >> 6);   // wave-uniform 0..3
  const float* Wcol = P + O_FLW + og * 24;           // transposed: [c*96 + j]
  float acc[24];
  #pragma unroll
  for (int j = 0; j < 24; j++) acc[j] = 0.f;
  for (int c = 0; c < 96; c++) {
    float vv = vs[c * 65 + p];
    const float* wc = Wcol + c * 96;
    #pragma unroll
    for (int j = 0; j < 24; j++) acc[j] += wc[j] * vv;
  }
  #pragma unroll
  for (int j = 0; j < 24; j++) {
    int o = og * 24 + j;
    float g = geluf(acc[j] + P[O_FLB + o]);
    sb[(size_t)o * SPECHW + p] = vs[o * 65 + p] * g;
  }
}

// ---- irfft along W, v3: Hermitian pack + lane-parallel inverse FFT64 ----
__global__ void __launch_bounds__(256) irfft_row_k(const float* __restrict__ spec,
                                                   bf16* __restrict__ out) {
  int t = threadIdx.x;
  int wid = t >> 6, l = t & 63;
  int row = blockIdx.x * 4 + wid;        // in [0, B*C*H)
  int h = row & (H - 1);
  int bc = row >> 7;
  int c = bc % C, b = bc / C;
  size_t rb = ((size_t)(b * C2 + c) * H + h) * WF;
  size_t ioff = (size_t)C * H * WF;
  float xr = spec[rb + l];
  float xi = (l == 0) ? 0.f : spec[rb + ioff + l];   // C2R: ignore DC imag
  float r64 = spec[rb + 64];                         // Nyquist (real used only)
  int lm = (64 - l) & 63;
  float mr = __shfl(xr, lm);
  float mi = __shfl(xi, lm);
  if (l == 0) { mr = r64; mi = 0.f; }                // X[64] for the k=0 pair
  float Fer = 0.5f * (xr + mr), Fei = 0.5f * (xi - mi);
  float Dr  = 0.5f * (xr - mr), Di  = 0.5f * (xi + mi);
  float a = (float)l * (1.f / 64.f);
  float tr = cospif(a), ti = sinpif(a);              // e^{+2 pi i l / 128}
  float For = tr * Dr - ti * Di;
  float Foi = tr * Di + ti * Dr;
  float zr = Fer - Foi, zi = Fei + For;              // Z = Fe + i*Fo
  #pragma unroll
  for (int s = 0; s < 6; s++) {
    int d = 32 >> s;
    float pr = __shfl_xor(zr, d);
    float pi = __shfl_xor(zi, d);
    float aa = (float)(l & (d - 1)) / (float)d;
    float wr = cospif(aa), wi = sinpif(aa);
    float sr = zr + pr, si = zi + pi;
    float dr = pr - zr, di = pi - zi;
    float mr2 = dr * wr - di * wi;
    float mi2 = dr * wi + di * wr;
    bool hib = (l & d) != 0;
    zr = hib ? mr2 : sr;
    zi = hib ? mi2 : si;
  }
  int m = __brev(l) >> 26;               // lane holds u[m]
  unsigned p0 = b2u(tob(zr * (1.f / 64.f)));
  unsigned p1 = b2u(tob(zi * (1.f / 64.f)));
  ((unsigned*)(out + (size_t)row * W))[m] = p0 | (p1 << 16);
}

// ---- dual 1x1 conv: two independent (in,out,w) jobs, one launch ----
// grid = 2 * B * 256; transposed weights wt[c*wstride + o]; perb: +b*2304
__global__ void __launch_bounds__(256) conv1x1d_k(const bf16* __restrict__ in0, bf16* __restrict__ out0,
                                                  const float* __restrict__ w0,
                                                  const bf16* __restrict__ in1, bf16* __restrict__ out1,
                                                  const float* __restrict__ w1,
                                                  int wstride, int perb) {
  int blk = blockIdx.x;
  int half = blk >> 11;
  int lb = blk & 2047;
  const bf16* in = half ? in1 : in0;
  bf16* out = half ? out1 : out0;
  const float* wt = half ? w1 : w0;
  __shared__ float vs[48 * 64];
  int t = threadIdx.x;
  int b = lb >> 8;
  int p0 = (lb & 255) << 6;
  int ibase = b * 48 * HW + p0;
  #pragma unroll
  for (int i = 0; i < 12; i++) {
    int idx = i * 256 + t;
    int c = idx >> 6, p = idx & 63;
    vs[idx] = ldf(in, ibase + c * HW + p);
  }
  __syncthreads();
  int p = t & 63;
  int og = __builtin_amdgcn_readfirstlane(t >> 6);   // wave-uniform 0..3
  const float* Wcol = wt + (perb ? b * 2304 : 0) + og * 12;
  float acc[12];
  #pragma unroll
  for (int j = 0; j < 12; j++) acc[j] = 0.f;
  for (int c = 0; c < 48; c++) {
    float v = vs[c * 64 + p];
    const float* wc = Wcol + c * wstride;
    #pragma unroll
    for (int j = 0; j < 12; j++) acc[j] += wc[j] * v;
  }
  bf16* op = out + (size_t)b * 48 * HW + p0 + p;
  #pragma unroll
  for (int j = 0; j < 12; j++) op[(size_t)(og * 12 + j) * HW] = tob(acc[j]);
}

// ---- fused x->KV conv v2: 8 waves x 24 outputs, one x staging ----
// wave wid: buf = wid>>1 (HK,HV,LK,LV), 24-ch half = wid&1.
__global__ void __launch_bounds__(512) convxkv_k(const void* __restrict__ in,
                                                 bf16* __restrict__ o0, bf16* __restrict__ o1,
                                                 bf16* __restrict__ o2, bf16* __restrict__ o3,
                                                 const float* __restrict__ P,
                                                 const int* flagp) {
  int bf = flagp[0];
  __shared__ float vs[48 * 64];
  int t = threadIdx.x;
  int blk = blockIdx.x;                // B * 256
  int b = blk >> 8;
  int p0 = (blk & 255) << 6;
  int ibase = b * 48 * HW + p0;
  #pragma unroll
  for (int i = 0; i < 6; i++) {
    int idx = i * 512 + t;             // 3072 = 48*64
    int c = idx >> 6, p = idx & 63;
    vs[idx] = ldx(in, ibase + c * HW + p, bf);
  }
  __syncthreads();
  int p = t & 63;
  int wid = __builtin_amdgcn_readfirstlane(t >> 6);  // wave-uniform 0..7
  int buf = wid >> 1;
  int half24 = (wid & 1) * 24;
  const float* Wcol = P + (buf < 2 ? O_HKVW : O_LKVW) + (buf & 1) * 48 + half24;
  bf16* ob = (buf == 0 ? o0 : buf == 1 ? o1 : buf == 2 ? o2 : o3);
  bf16* op = ob + (size_t)b * 48 * HW + (size_t)half24 * HW + p0 + p;
  float acc[24];
  #pragma unroll
  for (int j = 0; j < 24; j++) acc[j] = 0.f;
  for (int c = 0; c < 48; c++) {
    float v = vs[c * 64 + p];
    const float* wc = Wcol + c * 96;
    #pragma unroll
    for (int j = 0; j < 24; j++) acc[j] += wc[j] * v;
  }
  #pragma unroll
  for (int j = 0; j < 24; j++) op[(size_t)j * HW] = tob(acc[j]);
}

// ---- depthwise 3x3 octet helper: 8 px/thread, 16B row loads ----
DI void dw_oct(const bf16* __restrict__ p, const float* __restrict__ w,
               int c, int h, int w0, float acc[8]) {
  #pragma unroll
  for (int i = 0; i < 3; i++) {
    int hh = h + i - 1;
    if (hh < 0 || hh >= H) continue;
    const bf16* row = p + hh * W + w0;
    uint4 u = *(const uint4*)row;              // 16B-aligned (w0 % 8 == 0)
    float v[10];
    v[1] = u2f((unsigned short)(u.x & 0xFFFF)); v[2] = u2f((unsigned short)(u.x >> 16));
    v[3] = u2f((unsigned short)(u.y & 0xFFFF)); v[4] = u2f((unsigned short)(u.y >> 16));
    v[5] = u2f((unsigned short)(u.z & 0xFFFF)); v[6] = u2f((unsigned short)(u.z >> 16));
    v[7] = u2f((unsigned short)(u.w & 0xFFFF)); v[8] = u2f((unsigned short)(u.w >> 16));
    v[0] = (w0 > 0) ? ldf(row, -1) : 0.f;
    v[9] = (w0 + 8 < W) ? ldf(row, 8) : 0.f;
    #pragma unroll
    for (int j = 0; j < 3; j++) {
      float wt = w[c * 9 + i * 3 + j];
      #pragma unroll
      for (int q = 0; q < 8; q++) acc[q] += wt * v[q + j];
    }
  }
}

DI void dw_store8(bf16* __restrict__ out, int idx8, const float acc[8]) {
  uint4 o;
  o.x = (unsigned)b2u(tob(acc[0])) | ((unsigned)b2u(tob(acc[1])) << 16);
  o.y = (unsigned)b2u(tob(acc[2])) | ((unsigned)b2u(tob(acc[3])) << 16);
  o.z = (unsigned)b2u(tob(acc[4])) | ((unsigned)b2u(tob(acc[5])) << 16);
  o.w = (unsigned)b2u(tob(acc[6])) | ((unsigned)b2u(tob(acc[7])) << 16);
  *(uint4*)(out + (size_t)idx8 * 8) = o;
}

// ---- paired depthwise 3x3 v2: 8 px/thread, two plane sets ----
__global__ void dw3x3x2_k(const bf16* __restrict__ in1, bf16* __restrict__ out1,
                          const bf16* __restrict__ in2, bf16* __restrict__ out2,
                          const float* __restrict__ w1, const float* __restrict__ w2) {
  int idx8 = blockIdx.x * 256 + threadIdx.x;   // octet index over NCHW/8
  int w0 = (idx8 & 15) << 3;                   // W/8 = 16
  int h = (idx8 >> 4) & (H - 1);
  int plane = idx8 >> 11;                      // HW/8 = 2048
  int c = plane % 48;
  float a1[8] = {0,0,0,0,0,0,0,0};
  dw_oct(in1 + (size_t)plane * HW, w1, c, h, w0, a1);
  dw_store8(out1, idx8, a1);
  float a2[8] = {0,0,0,0,0,0,0,0};
  dw_oct(in2 + (size_t)plane * HW, w2, c, h, w0, a2);
  dw_store8(out2, idx8, a2);
}

// ---- quad depthwise 3x3 v2: 8 px/thread, four plane sets ----
__global__ void dw3x3q_k(const bf16* __restrict__ i1, bf16* __restrict__ u1,
                         const bf16* __restrict__ i2, bf16* __restrict__ u2,
                         const bf16* __restrict__ i3, bf16* __restrict__ u3,
                         const bf16* __restrict__ i4, bf16* __restrict__ u4,
                         const float* __restrict__ w1, const float* __restrict__ w2,
                         const float* __restrict__ w3, const float* __restrict__ w4) {
  int idx8 = blockIdx.x * 256 + threadIdx.x;
  int w0 = (idx8 & 15) << 3;
  int h = (idx8 >> 4) & (H - 1);
  int plane = idx8 >> 11;
  int c = plane % 48;
  float a[8];
  #pragma unroll
  for (int q = 0; q < 8; q++) a[q] = 0.f;
  dw_oct(i1 + (size_t)plane * HW, w1, c, h, w0, a);
  dw_store8(u1, idx8, a);
  #pragma unroll
  for (int q = 0; q < 8; q++) a[q] = 0.f;
  dw_oct(i2 + (size_t)plane * HW, w2, c, h, w0, a);
  dw_store8(u2, idx8, a);
  #pragma unroll
  for (int q = 0; q < 8; q++) a[q] = 0.f;
  dw_oct(i3 + (size_t)plane * HW, w3, c, h, w0, a);
  dw_store8(u3, idx8, a);
  #pragma unroll
  for (int q = 0; q < 8; q++) a[q] = 0.f;
  dw_oct(i4 + (size_t)plane * HW, w4, c, h, w0, a);
  dw_store8(u4, idx8, a);
}

// ---- attn gram v3: MFMA 16x16x32 bf16, no LDS ----
// grid = 2 * 32 bh * 16 splits; 4 waves/block, wave handles L-chunk of 256
// (8 k-steps). Lane l loads row (l&15, clamp 11) 8 bf16 at koff=(l>>4)*8 —
// identical pattern serves as A-frag (Q) and B-frag (K => B holds K^T), so
// G += mfma(fq,fk) = Q.K^T; Nq/Nk diagonals give the norms (transpose-safe).
// C/D layout (verified): col n = l&15, row m = (l>>4)*4 + reg.
__global__ void __launch_bounds__(256) attn_part_k(const bf16* __restrict__ q0,
                                                   const bf16* __restrict__ k0,
                                                   const bf16* __restrict__ q1,
                                                   const bf16* __restrict__ k1,
                                                   float* __restrict__ partial) {
  int blk = blockIdx.x;
  int half = blk >> 9;                  // grid = 2 * 512
  int lb = blk & 511;
  const bf16* q = half ? q1 : q0;
  const bf16* kbuf = half ? k1 : k0;
  float* part = partial + (size_t)half * PARTSZ;
  int bh = lb >> 4;                     // 0..31
  int split = lb & 15;                  // 0..15
  int b = bh >> 2, hd = bh & 3;
  int t = threadIdx.x;
  int wid = t >> 6, l = t & 63;
  int chunk = split * 4 + wid;          // 0..63 (matches finM NCHUNK layout)
  int n = l & 15;
  int row = n < 12 ? n : 11;            // rows 12-15: dup row 11, discarded
  int koff = (l >> 4) * 8;
  size_t rb = (size_t)(b * 48 + hd * 12) * HW + (size_t)row * HW + chunk * 256 + koff;
  const bf16* qb = q + rb;
  const bf16* kb = kbuf + rb;
  f32x4 G = {0.f, 0.f, 0.f, 0.f};
  f32x4 Nq = {0.f, 0.f, 0.f, 0.f};
  f32x4 Nk = {0.f, 0.f, 0.f, 0.f};
  #pragma unroll
  for (int s = 0; s < 8; s++) {
    short8v fq = *(const short8v*)(qb + s * 32);
    short8v fk = *(const short8v*)(kb + s * 32);
    G  = __builtin_amdgcn_mfma_f32_16x16x32_bf16(fq, fk, G, 0, 0, 0);
    Nq = __builtin_amdgcn_mfma_f32_16x16x32_bf16(fq, fq, Nq, 0, 0, 0);
    Nk = __builtin_amdgcn_mfma_f32_16x16x32_bf16(fk, fk, Nk, 0, 0, 0);
  }
  int mb = (l >> 4) * 4;
  float* pp = part + (size_t)(chunk * 32 + bh) * 168;
  if (n < 12 && mb < 12) {
    pp[(mb + 0) * 12 + n] = G[0];
    pp[(mb + 1) * 12 + n] = G[1];
    pp[(mb + 2) * 12 + n] = G[2];
    pp[(mb + 3) * 12 + n] = G[3];
  }
  if (n < 12 && n >= mb && n < mb + 4) {
    int r = n - mb;
    float nq = (r == 0) ? Nq[0] : (r == 1) ? Nq[1] : (r == 2) ? Nq[2] : Nq[3];
    float nk = (r == 0) ? Nk[0] : (r == 1) ? Nk[1] : (r == 2) ? Nk[2] : Nk[3];
    pp[144 + n] = nq;
    pp[156 + n] = nk;
  }
}

// ---- dual: reduce partials + softmax + fused projection matrix ----
// grid = 64: half = blk>>5 (high/low), bh = blk&31.
// M[half][b][dg][o] = sum_c attn_hd[c][d] * PWt[(hd*12+c)*48 + o]
__global__ void __launch_bounds__(256) attn_finM_k(const float* __restrict__ partial,
                                                   const float* __restrict__ P,
                                                   float* __restrict__ M) {
  int blk = blockIdx.x;
  int half = blk >> 5;
  int bh = blk & 31, b = bh >> 2, hd = bh & 3;
  const float* part = partial + (size_t)half * PARTSZ;
  const float* temp = P + (half ? O_LT : O_HT);
  const float* pwt = P + (half ? O_LPW : O_HPW);
  float* Mh = M + (size_t)half * 8 * 2304;
  int t = threadIdx.x;
  __shared__ float red[168];
  __shared__ float sm[144];              // sm[c*12 + d]
  if (t < 168) {
    float s = 0.f;
    for (int ch = 0; ch < NCHUNK; ch++) s += part[(size_t)(ch * 32 + bh) * 168 + t];
    red[t] = s;
  }
  __syncthreads();
  if (t < 12) {
    float tm = temp[hd];
    float rq = 1.f / fmaxf(sqrtf(red[144 + t]), 1e-12f);
    float vals[12], mx = -1e30f;
    #pragma unroll
    for (int d = 0; d < 12; d++) {
      float rk = 1.f / fmaxf(sqrtf(red[156 + d]), 1e-12f);
      vals[d] = red[t * 12 + d] * rq * rk * tm;
      mx = fmaxf(mx, vals[d]);
    }
    float s = 0.f;
    #pragma unroll
    for (int d = 0; d < 12; d++) { vals[d] = expf(vals[d] - mx); s += vals[d]; }
    float inv = 1.f / s;
    #pragma unroll
    for (int d = 0; d < 12; d++) sm[t * 12 + d] = vals[d] * inv;
  }
  __syncthreads();
  for (int e = t; e < 576; e += 256) {   // 12 d-rows x 48 outputs
    int d = e / 48, o = e - d * 48;
    float s = 0.f;
    #pragma unroll
    for (int c = 0; c < 12; c++) s += sm[c * 12 + d] * pwt[(hd * 12 + c) * 48 + o];
    Mh[(size_t)b * 2304 + (hd * 12 + d) * 48 + o] = s;
  }
}

// ---- final v2t: 64 px/block, 4 waves x 12 outputs, transposed weights ----
__global__ void __launch_bounds__(256) conv_final_k(const bf16* __restrict__ ho,
                                                    const bf16* __restrict__ lo,
                                                    const float* __restrict__ P,
                                                    const void* __restrict__ x,
                                                    void* __restrict__ out,
                                                    const int* flagp) {
  int bf = flagp[0];
  __shared__ float vs[96 * 64];
  int t = threadIdx.x;
  int blk = blockIdx.x;                // B * 256
  int b = blk >> 8;
  int p0 = (blk & 255) << 6;
  int pbase = b * 48 * HW + p0;
  #pragma unroll
  for (int i = 0; i < 12; i++) {
    int idx = i * 256 + t;
    int c = idx >> 6, p = idx & 63;
    vs[idx] = ldf(ho, pbase + c * HW + p);
    vs[48 * 64 + idx] = ldf(lo, pbase + c * HW + p);
  }
  __syncthreads();
  int p = t & 63;
  int og = __builtin_amdgcn_readfirstlane(t >> 6);   // wave-uniform 0..3
  const float* Wcol = P + O_FPW + og * 12;           // transposed: [c*48 + j]
  float acc[12];
  #pragma unroll
  for (int j = 0; j < 12; j++) acc[j] = 0.f;
  for (int c = 0; c < 96; c++) {
    float v = vs[c * 64 + p];
    const float* wc = Wcol + c * 48;
    #pragma unroll
    for (int j = 0; j < 12; j++) acc[j] += wc[j] * v;
  }
  #pragma unroll
  for (int j = 0; j < 12; j++) {
    int o = og * 12 + j;
    int oi = pbase + o * HW + p;
    float val = acc[j] + P[O_FPB + o] + ldx(x, oi, bf);
    if (bf) ((bf16*)out)[oi] = tob(val);
    else    ((float*)out)[oi] = val;
  }
}

extern "C" void kernel_launch(void* const* d_in, const int* in_sizes, int n_in,
                              void* d_out, int out_size, void* d_ws, size_t ws_size,
                              hipStream_t stream) {
  const void* x = d_in[0];

  // ws layout (fp32 units): ap@0, flag@7000, params@8192 (ends 47224),
  // wts@48000, Mbuf@50000 (2*8*2304 -> ends 86864),
  // parts@90000 (2*PARTSZ -> ends 778128), bf16 planes P0..P9 @800000
  float* ws    = (float*)d_ws;
  float* ap    = ws;
  int*   flagp = (int*)(ws + 7000);
  float* P     = ws + 8192;
  float* wts   = ws + 48000;
  float* Mbuf  = ws + 50000;
  float* parts = ws + 90000;
  bf16* base = (bf16*)(ws + 800000);
  bf16* P0 = base;                       // hf -> ho
  bf16* P1 = base + (size_t)NCHW;        // lf -> lo
  bf16* P2 = base + (size_t)2 * NCHW;    // spec / HKpre / HQpre
  bf16* P3 = base + (size_t)3 * NCHW;    // spec / HVpre / HQ
  bf16* P4 = base + (size_t)4 * NCHW;    // spec / LKpre / LQpre
  bf16* P5 = base + (size_t)5 * NCHW;    // LVpre / LQ
  bf16* P6 = base + (size_t)6 * NCHW;    // HK
  bf16* P7 = base + (size_t)7 * NCHW;    // HV
  bf16* P8 = base + (size_t)8 * NCHW;    // LK
  bf16* P9 = base + (size_t)9 * NCHW;    // LV
  float* spec = (float*)P2;

  // ---- dtype detect + param convert (matmul weights transposed) ----
  detect_k<<<1, 256, 0, stream>>>(x, flagp);
  ParamTab tab;
  const int offs[25] = {O_FDW, O_BNG, O_BNB, O_BNM, O_BNV,
                        O_FHW1, O_FHB1, O_FHW2, O_FHB2,
                        O_FLW, O_FLB,
                        O_HQW, O_HKVW, O_HQDW, O_HKVDW, O_HPW, O_HT,
                        O_LQW, O_LKVW, O_LQDW, O_LKVDW, O_LPW, O_LT,
                        O_FPW, O_FPB};
  const int cnts[25] = {3456, 72, 72, 72, 72,
                        144, 48, 144, 48,
                        9216, 96,
                        2304, 4608, 432, 864, 2304, 4,
                        2304, 4608, 432, 864, 2304, 4,
                        4608, 48};
  const int rows[25] = {0, 0, 0, 0, 0,
                        0, 0, 0, 0,
                        96, 0,
                        48, 96, 0, 0, 48, 0,
                        48, 96, 0, 0, 48, 0,
                        48, 0};
  for (int i = 0; i < 25; i++) {
    tab.src[i] = d_in[i + 1]; tab.off[i] = offs[i]; tab.cnt[i] = cnts[i]; tab.rows[i] = rows[i];
  }
  cvt_params_k<<<25, 256, 0, stream>>>(tab, flagp, P);

  // ---- fd ----
  reduce_mean_k<<<B * C, 256, 0, stream>>>(x, ap, flagp);
  fd_weights_k<<<B, 128, 0, stream>>>(ap, P, wts);
  fd_apply_k<<<NCHW / 1024, 256, 0, stream>>>(x, wts, P1, P3, flagp); // low->P1, high->P3
  // ---- fmgm_high ----
  fmgm_high_k<<<NCHW / 1024, 256, 0, stream>>>(P3, P, P0);            // hf->P0
  // ---- fmgm_low: rfft2 -> gate -> irfft2 (spec overlays P2..P4) ----
  rfft_row_k<<<B * C * H / 4, 256, 0, stream>>>(P1, spec);
  fft_col_k<<<B * C * 2, 256, 0, stream>>>(spec, -1.f, 1.f);
  freq_gate_k<<<B * (SPECHW / 64), 256, 0, stream>>>(spec, P);
  fft_col_k<<<B * C * 2, 256, 0, stream>>>(spec, 1.f, 1.f / 128.f);
  irfft_row_k<<<B * C * H / 4, 256, 0, stream>>>(spec, P1);           // lf->P1
  // ---- fused x->KV conv (spec dead) + quad depthwise ----
  convxkv_k<<<B * 256, 512, 0, stream>>>(x, P2, P3, P4, P5, P, flagp);
  dw3x3q_k<<<NCHW / 2048, 256, 0, stream>>>(P2, P6, P3, P7, P4, P8, P5, P9,
                                            P + O_HKVDW, P + O_HKVDW + 48 * 9,
                                            P + O_LKVDW, P + O_LKVDW + 48 * 9);
  // ---- both q-paths dual (P2..P5 free after dw3x3q) ----
  conv1x1d_k<<<2 * B * 256, 256, 0, stream>>>(P0, P2, P + O_HQW,
                                              P1, P4, P + O_LQW, 48, 0);
  dw3x3x2_k<<<NCHW / 2048, 256, 0, stream>>>(P2, P3, P4, P5,
                                             P + O_HQDW, P + O_LQDW);
  // ---- attention (both branches in each launch) ----
  attn_part_k<<<2 * 32 * 16, 256, 0, stream>>>(P3, P6, P5, P8, parts);
  attn_finM_k<<<64, 256, 0, stream>>>(parts, P, Mbuf);
  conv1x1d_k<<<2 * B * 256, 256, 0, stream>>>(P7, P0, Mbuf,
                                              P9, P1, Mbuf + 8 * 2304, 48, 1);
  // ---- final 1x1 + bias + residual ----
  conv_final_k<<<B * 256, 256, 0, stream>>>(P0, P1, P, x, d_out, flagp);
}

// Round 10
// 456.780 us; speedup vs baseline: 2.2093x; 1.0645x over previous
//
#include <hip/hip_runtime.h>
#include <hip/hip_bf16.h>
#include <math.h>

using bf16 = __hip_bfloat16;
#define DI __device__ __forceinline__

typedef __attribute__((ext_vector_type(8))) short short8v;   // 8 bf16 (4 VGPRs)
typedef __attribute__((ext_vector_type(4))) float f32x4;

namespace {
constexpr int B = 8, C = 48, H = 128, W = 128;
constexpr int HW = H * W;                 // 16384
constexpr int NCHW = B * C * HW;          // 6,291,456
constexpr int C2 = 96;
constexpr int WF = 65;                    // rfft width
constexpr int SPECHW = H * WF;            // 8320 (divisible by 64)
constexpr int SPECN = B * C2 * SPECHW;    // 6,389,760 floats
// spec (fp32) overlays planes P2+P3+P4 = 3*NCHW bf16 slots
static_assert((size_t)SPECN * 4 <= (size_t)3 * NCHW * 2, "spec must fit in P2..P4 overlay");
static_assert(SPECHW % 64 == 0, "freq_gate 64-pixel blocks must not straddle batches");

// fp32 param header offsets (in floats), base = ws + 8192
// NOTE: matmul weights (FLW, *QW, *KVW, *PW, FPW) are stored TRANSPOSED
// (input-major): wt[c*rows + o]. Depthwise/BN/bias params stay plain.
constexpr int O_FDW = 0,    O_BNG = 3456, O_BNB = 3528, O_BNM = 3600, O_BNV = 3672;
constexpr int O_FHW1 = 3744, O_FHB1 = 3888, O_FHW2 = 3936, O_FHB2 = 3984;
constexpr int O_FLW = 4032,  O_FLB = 13248;
constexpr int O_HQW = 13344, O_HKVW = 15648, O_HQDW = 20256, O_HKVDW = 20688, O_HPW = 21552, O_HT = 23856;
constexpr int O_LQW = 23860, O_LKVW = 26164, O_LQDW = 30772, O_LKVDW = 31204, O_LPW = 32068, O_LT = 34372;
constexpr int O_FPW = 34376, O_FPB = 38984;  // end 39032

constexpr int NCHUNK = 64;                // L split for attn gram
constexpr int PARTSZ = 32 * NCHUNK * 168; // per-branch partials (344064 floats)
}

DI float ldf(const float* p, int i) { return p[i]; }
DI float ldf(const bf16* p, int i) { return __bfloat162float(p[i]); }
DI bf16 tob(float x) { return __float2bfloat16(x); }
DI unsigned short b2u(bf16 v) { union { bf16 b; unsigned short u; } x; x.b = v; return x.u; }
DI float u2f(unsigned short u) { return __uint_as_float((unsigned)u << 16); }
DI float ldx(const void* p, int i, int bf) {
  return bf ? __bfloat162float(((const bf16*)p)[i]) : ((const float*)p)[i];
}
DI float geluf(float x) { return 0.5f * x * (1.f + erff(x * 0.70710678118654752f)); }
DI int refl(int i, int n) { return i < 0 ? -i : (i >= n ? 2 * n - 2 - i : i); }

// ---- dtype detector: bf16 data -> even u16 slots have sane exponents ----
__global__ void detect_k(const void* x, int* flagp) {
  const unsigned short* u = (const unsigned short*)x;
  int t = threadIdx.x;
  int good = 0;
  for (int i = t; i < 1024; i += 256) {
    unsigned short v = u[2 * i];
    int e = (v >> 7) & 0xFF;
    if (e >= 100 && e <= 140) good++;
  }
  __shared__ int cnt;
  if (t == 0) cnt = 0;
  __syncthreads();
  atomicAdd(&cnt, good);
  __syncthreads();
  if (t == 0) flagp[0] = (cnt > 512) ? 1 : 0;
}

// ---- convert all params to fp32 header; matmul weights transposed ----
struct ParamTab { const void* src[25]; int off[25]; int cnt[25]; int rows[25]; };
__global__ void cvt_params_k(ParamTab tab, const int* flagp, float* dst) {
  int bf = flagp[0];
  int b = blockIdx.x;
  const void* s = tab.src[b];
  float* d = dst + tab.off[b];
  int n = tab.cnt[b];
  int rows = tab.rows[b];
  if (rows == 0) {
    for (int i = threadIdx.x; i < n; i += 256) d[i] = ldx(s, i, bf);
  } else {
    int cols = n / rows;
    for (int i = threadIdx.x; i < n; i += 256)
      d[(i % cols) * rows + (i / cols)] = ldx(s, i, bf);
  }
}

// ---- fd: channel means, v2: vector loads ----
__global__ void reduce_mean_k(const void* __restrict__ x, float* __restrict__ ap,
                              const int* flagp) {
  int bf = flagp[0];
  int bc = blockIdx.x;
  float s = 0.f;
  if (bf) {
    const ushort4* xp = (const ushort4*)((const bf16*)x + (size_t)bc * HW);
    for (int i = threadIdx.x; i < HW / 4; i += 256) {
      ushort4 u = xp[i];
      s += u2f(u.x) + u2f(u.y) + u2f(u.z) + u2f(u.w);
    }
  } else {
    const float4* xp = (const float4*)((const float*)x + (size_t)bc * HW);
    for (int i = threadIdx.x; i < HW / 4; i += 256) {
      float4 u = xp[i];
      s += u.x + u.y + u.z + u.w;
    }
  }
  #pragma unroll
  for (int o = 32; o > 0; o >>= 1) s += __shfl_down(s, o);
  __shared__ float r[4];
  if ((threadIdx.x & 63) == 0) r[threadIdx.x >> 6] = s;
  __syncthreads();
  if (threadIdx.x == 0) ap[bc] = (r[0] + r[1] + r[2] + r[3]) * (1.f / HW);
}

// ---- fd: 72-wide linear + BN + per-group softmax over 9 ----
__global__ void fd_weights_k(const float* __restrict__ ap, const float* __restrict__ P,
                             float* __restrict__ wts) {
  int n = blockIdx.x, t = threadIdx.x;
  __shared__ float vals[72], es[72];
  if (t < 72) {
    float acc = 0.f;
    for (int c = 0; c < C; c++) acc += P[O_FDW + t * C + c] * ap[n * C + c];
    acc = (acc - P[O_BNM + t]) * rsqrtf(P[O_BNV + t] + 1e-5f);
    vals[t] = acc * P[O_BNG + t] + P[O_BNB + t];
  }
  __syncthreads();
  if (t < 72) {
    int base = (t / 9) * 9;
    float mx = -1e30f;
    for (int k = 0; k < 9; k++) mx = fmaxf(mx, vals[base + k]);
    es[t] = expf(vals[t] - mx);
  }
  __syncthreads();
  if (t < 72) {
    int base = (t / 9) * 9;
    float s = 0.f;
    for (int k = 0; k < 9; k++) s += es[base + k];
    wts[n * 72 + t] = es[t] / s;
  }
}

// ---- fd v2: involution low-pass (reflect pad), 4 px/thread, vector rows ----
__global__ void fd_apply_k(const void* __restrict__ x, const float* __restrict__ wts,
                           bf16* __restrict__ low, bf16* __restrict__ high,
                           const int* flagp) {
  int bf = flagp[0];
  int idx4 = blockIdx.x * 256 + threadIdx.x;   // quad index over NCHW/4
  int w0 = (idx4 & 31) << 2;                   // W/4 = 32
  int h = (idx4 >> 5) & (H - 1);
  int plane = idx4 >> 12;                      // b*C + c
  int c = plane % C;
  int b = plane / C;
  const float* wt = wts + b * 72 + (c / 6) * 9;
  size_t pbase = (size_t)plane * HW;
  float acc[4] = {0.f, 0.f, 0.f, 0.f};
  float ctr[4];
  #pragma unroll
  for (int i = 0; i < 3; i++) {
    int hh = refl(h + i - 1, H);
    float v[6];
    if (bf) {
      const bf16* row = (const bf16*)x + pbase + hh * W + w0;
      ushort4 u = *(const ushort4*)row;        // 8B aligned
      v[1] = u2f(u.x); v[2] = u2f(u.y); v[3] = u2f(u.z); v[4] = u2f(u.w);
      v[0] = (w0 > 0) ? ldf(row, -1) : v[2];
      v[5] = (w0 + 4 < W) ? ldf(row, 4) : v[3];
    } else {
      const float* row = (const float*)x + pbase + hh * W + w0;
      float4 u = *(const float4*)row;          // 16B aligned
      v[1] = u.x; v[2] = u.y; v[3] = u.z; v[4] = u.w;
      v[0] = (w0 > 0) ? row[-1] : v[2];
      v[5] = (w0 + 4 < W) ? row[4] : v[3];
    }
    if (i == 1) { ctr[0] = v[1]; ctr[1] = v[2]; ctr[2] = v[3]; ctr[3] = v[4]; }
    #pragma unroll
    for (int j = 0; j < 3; j++) {
      float wv = wt[i * 3 + j];
      #pragma unroll
      for (int q = 0; q < 4; q++) acc[q] += wv * v[q + j];
    }
  }
  ushort4 ol, oh;
  ol.x = b2u(tob(acc[0])); ol.y = b2u(tob(acc[1]));
  ol.z = b2u(tob(acc[2])); ol.w = b2u(tob(acc[3]));
  oh.x = b2u(tob(ctr[0] - acc[0])); oh.y = b2u(tob(ctr[1] - acc[1]));
  oh.z = b2u(tob(ctr[2] - acc[2])); oh.w = b2u(tob(ctr[3] - acc[3]));
  *(ushort4*)(low + (size_t)idx4 * 4) = ol;
  *(ushort4*)(high + (size_t)idx4 * 4) = oh;
}

// ---- fmgm_high v2: fused (1x3)->(3x1) dwconv -> gelu * x, 4 px/thread ----
__global__ void fmgm_high_k(const bf16* __restrict__ hi, const float* __restrict__ P,
                            bf16* __restrict__ out) {
  int idx4 = blockIdx.x * 256 + threadIdx.x;   // quad index over NCHW/4
  int w0 = (idx4 & 31) << 2;
  int h = (idx4 >> 5) & (H - 1);
  int plane = idx4 >> 12;
  int c = plane % C;
  const bf16* p = hi + (size_t)plane * HW;
  float k1[3], k2[3];
  #pragma unroll
  for (int j = 0; j < 3; j++) { k1[j] = P[O_FHW1 + c * 3 + j]; k2[j] = P[O_FHW2 + c * 3 + j]; }
  float b1 = P[O_FHB1 + c];
  float b2 = P[O_FHB2 + c];
  float acc[4] = {b2, b2, b2, b2};
  float ctr[4];
  #pragma unroll
  for (int i = 0; i < 3; i++) {
    int hh = h + i - 1;
    if (hh < 0 || hh >= H) continue;
    const bf16* row = p + hh * W + w0;
    ushort4 u = *(const ushort4*)row;          // 8B aligned
    float v[6];
    v[1] = u2f(u.x); v[2] = u2f(u.y); v[3] = u2f(u.z); v[4] = u2f(u.w);
    v[0] = (w0 > 0) ? ldf(row, -1) : 0.f;      // zero pad
    v[5] = (w0 + 4 < W) ? ldf(row, 4) : 0.f;
    if (i == 1) { ctr[0] = v[1]; ctr[1] = v[2]; ctr[2] = v[3]; ctr[3] = v[4]; }
    float kk = k2[i];
    #pragma unroll
    for (int q = 0; q < 4; q++) {
      float y1 = b1 + k1[0] * v[q] + k1[1] * v[q + 1] + k1[2] * v[q + 2];
      acc[q] += kk * y1;
    }
  }
  ushort4 o;
  o.x = b2u(tob(geluf(acc[0]) * ctr[0]));
  o.y = b2u(tob(geluf(acc[1]) * ctr[1]));
  o.z = b2u(tob(geluf(acc[2]) * ctr[2]));
  o.w = b2u(tob(geluf(acc[3]) * ctr[3]));
  *(ushort4*)(out + (size_t)idx4 * 4) = o;
}

// ---- rfft along W, v3: lane-parallel radix-2 FFT64 (shuffle butterflies) ----
__global__ void __launch_bounds__(256) rfft_row_k(const bf16* __restrict__ low,
                                                  float* __restrict__ spec) {
  int t = threadIdx.x;
  int wid = t >> 6, l = t & 63;
  int row = blockIdx.x * 4 + wid;        // in [0, B*C*H)
  int h = row & (H - 1);
  int bc = row >> 7;
  int c = bc % C, b = bc / C;
  const unsigned* xr = (const unsigned*)(low + (size_t)row * W);
  unsigned v2 = xr[l];                   // two bf16: elems 2l, 2l+1
  float zr = __uint_as_float(v2 << 16);
  float zi = __uint_as_float(v2 & 0xFFFF0000u);
  #pragma unroll
  for (int s = 0; s < 6; s++) {
    int d = 32 >> s;
    float pr = __shfl_xor(zr, d);
    float pi = __shfl_xor(zi, d);
    float a = (float)(l & (d - 1)) / (float)d;
    float wr = cospif(a), wi = -sinpif(a);
    float sr = zr + pr, si = zi + pi;
    float dr = pr - zr, di = pi - zi;
    float mr2 = dr * wr - di * wi;
    float mi2 = dr * wi + di * wr;
    bool hib = (l & d) != 0;
    zr = hib ? mr2 : sr;
    zi = hib ? mi2 : si;
  }
  int rl = __brev(l) >> 26;
  int lm = (64 - l) & 63;
  int rm = __brev(lm) >> 26;
  float Zkr = __shfl(zr, rl), Zki = __shfl(zi, rl);
  float Zmr = __shfl(zr, rm), Zmi = __shfl(zi, rm);
  float Fer = 0.5f * (Zkr + Zmr), Fei = 0.5f * (Zki - Zmi);
  float Dr  = 0.5f * (Zkr - Zmr), Di  = 0.5f * (Zki + Zmi);
  float For = Di, Foi = -Dr;             // D / i
  float a = (float)l * (1.f / 64.f);
  float tr = cospif(a), ti = -sinpif(a); // e^{-2 pi i l / 128}
  float Xr = Fer + tr * For - ti * Foi;
  float Xi = Fei + tr * Foi + ti * For;
  size_t o = ((size_t)(b * C2 + c) * H + h) * WF + l;
  size_t ioff = (size_t)C * H * WF;
  spec[o] = Xr;
  spec[o + ioff] = Xi;
  if (l == 0) {                          // k = 64 (Nyquist)
    spec[o + 64] = Fer - For;
    spec[o + 64 + ioff] = 0.f;
  }
}

// ---- complex FFT-128 along H, v6: lane-parallel radix-2, LDS tile ----
__global__ void __launch_bounds__(256) fft_col_k(float* __restrict__ spec,
                                                 float sgn, float scale) {
  __shared__ float re_s[128 * 33], im_s[128 * 33];   // 33.8 KB, stride 33
  int t = threadIdx.x;
  int half = blockIdx.x & 1;
  int bc = blockIdx.x >> 1;
  int cc = bc % C, b = bc / C;
  size_t reb = ((size_t)(b * C2 + cc) * H) * WF;
  size_t imb = reb + (size_t)C * H * WF;
  int ncol = half ? 33 : 32;
  if (half == 0) {
    #pragma unroll
    for (int i = 0; i < 16; i++) {
      int idx = i * 256 + t;             // 4096 = 128*32
      int r = idx >> 5, c = idx & 31;
      re_s[r * 33 + c] = spec[reb + r * WF + c];
      im_s[r * 33 + c] = spec[imb + r * WF + c];
    }
  } else {
    #pragma unroll
    for (int i = 0; i < 17; i++) {
      int idx = i * 256 + t;             // 4352 >= 128*33
      if (idx < 128 * 33) {
        int r = idx / 33, c = idx - r * 33;
        re_s[r * 33 + c] = spec[reb + r * WF + 32 + c];
        im_s[r * 33 + c] = spec[imb + r * WF + 32 + c];
      }
    }
  }
  __syncthreads();
  int w = t >> 6, l = t & 63;
  float cA = cospif((float)l * (1.f / 64.f));
  float sA = sinpif((float)l * (1.f / 64.f)) * sgn;  // e^{sgn*2pi i l/128}
  float cs[6], ss[6];
  #pragma unroll
  for (int s = 0; s < 6; s++) {
    int d = 32 >> s;
    float a = (float)(l & (d - 1)) / (float)d;
    cs[s] = cospif(a); ss[s] = sinpif(a) * sgn;
  }
  int br = __brev(l) >> 26;
  for (int c = w; c < ncol; c += 4) {
    float ar = re_s[l * 33 + c],         ai = im_s[l * 33 + c];
    float xr = re_s[(l + 64) * 33 + c],  xi = im_s[(l + 64) * 33 + c];
    float ur = ar + xr, ui = ai + xi;                // -> even freqs
    float tr = ar - xr, ti = ai - xi;
    float vr = tr * cA - ti * sA;                    // -> odd freqs
    float vi = tr * sA + ti * cA;
    #pragma unroll
    for (int s = 0; s < 6; s++) {
      int d = 32 >> s;
      float pr = __shfl_xor(ur, d), pi = __shfl_xor(ui, d);
      float qr = __shfl_xor(vr, d), qi = __shfl_xor(vi, d);
      float sur = ur + pr, sui = ui + pi;
      float dur = pr - ur, dui = pi - ui;
      float svr = vr + qr, svi = vi + qi;
      float dvr = qr - vr, dvi = qi - vi;
      float mur = dur * cs[s] - dui * ss[s];
      float mui = dur * ss[s] + dui * cs[s];
      float mvr = dvr * cs[s] - dvi * ss[s];
      float mvi = dvr * ss[s] + dvi * cs[s];
      bool hib = (l & d) != 0;
      ur = hib ? mur : sur; ui = hib ? mui : sui;
      vr = hib ? mvr : svr; vi = hib ? mvi : svi;
    }
    int r0 = 2 * br;                     // X[2*br] = U-res, X[2*br+1] = V-res
    re_s[r0 * 33 + c] = ur * scale;       im_s[r0 * 33 + c] = ui * scale;
    re_s[(r0 + 1) * 33 + c] = vr * scale; im_s[(r0 + 1) * 33 + c] = vi * scale;
  }
  __syncthreads();
  if (half == 0) {
    #pragma unroll
    for (int i = 0; i < 16; i++) {
      int idx = i * 256 + t;
      int r = idx >> 5, c = idx & 31;
      spec[reb + r * WF + c] = re_s[r * 33 + c];
      spec[imb + r * WF + c] = im_s[r * 33 + c];
    }
  } else {
    #pragma unroll
    for (int i = 0; i < 17; i++) {
      int idx = i * 256 + t;
      if (idx < 128 * 33) {
        int r = idx / 33, c = idx - r * 33;
        spec[reb + r * WF + 32 + c] = re_s[r * 33 + c];
        spec[imb + r * WF + 32 + c] = im_s[r * 33 + c];
      }
    }
  }
}

// ---- freq-domain channel-mix gate: yf *= gelu(W yf + b) ----
__global__ void __launch_bounds__(256) freq_gate_k(float* __restrict__ spec,
                                                   const float* __restrict__ P) {
  __shared__ float vs[96 * 65];
  int t = threadIdx.x;
  int blk = blockIdx.x;
  int b = blk / (SPECHW / 64);
  int pp0 = (blk % (SPECHW / 64)) * 64;
  float* sb = spec + (size_t)b * C2 * SPECHW + pp0;
  #pragma unroll
  for (int i = 0; i < 24; i++) {
    int idx = i * 256 + t;
    int c = idx >> 6, p = idx & 63;
    vs[c * 65 + p] = sb[(size_t)c * SPECHW + p];
  }
  __syncthreads();
  int p = t & 63;
  int og = __builtin_amdgcn_readfirstlane(t >> 6);   // wave-uniform 0..3
  const float* Wcol = P + O_FLW + og * 24;           // transposed: [c*96 + j]
  float acc[24];
  #pragma unroll
  for (int j = 0; j < 24; j++) acc[j] = 0.f;
  for (int c = 0; c < 96; c++) {
    float vv = vs[c * 65 + p];
    const float* wc = Wcol + c * 96;
    #pragma unroll
    for (int j = 0; j < 24; j++) acc[j] += wc[j] * vv;
  }
  #pragma unroll
  for (int j = 0; j < 24; j++) {
    int o = og * 24 + j;
    float g = geluf(acc[j] + P[O_FLB + o]);
    sb[(size_t)o * SPECHW + p] = vs[o * 65 + p] * g;
  }
}

// ---- irfft along W, v3: Hermitian pack + lane-parallel inverse FFT64 ----
__global__ void __launch_bounds__(256) irfft_row_k(const float* __restrict__ spec,
                                                   bf16* __restrict__ out) {
  int t = threadIdx.x;
  int wid = t >> 6, l = t & 63;
  int row = blockIdx.x * 4 + wid;        // in [0, B*C*H)
  int h = row & (H - 1);
  int bc = row >> 7;
  int c = bc % C, b = bc / C;
  size_t rb = ((size_t)(b * C2 + c) * H + h) * WF;
  size_t ioff = (size_t)C * H * WF;
  float xr = spec[rb + l];
  float xi = (l == 0) ? 0.f : spec[rb + ioff + l];   // C2R: ignore DC imag
  float r64 = spec[rb + 64];                         // Nyquist (real used only)
  int lm = (64 - l) & 63;
  float mr = __shfl(xr, lm);
  float mi = __shfl(xi, lm);
  if (l == 0) { mr = r64; mi = 0.f; }                // X[64] for the k=0 pair
  float Fer = 0.5f * (xr + mr), Fei = 0.5f * (xi - mi);
  float Dr  = 0.5f * (xr - mr), Di  = 0.5f * (xi + mi);
  float a = (float)l * (1.f / 64.f);
  float tr = cospif(a), ti = sinpif(a);              // e^{+2 pi i l / 128}
  float For = tr * Dr - ti * Di;
  float Foi = tr * Di + ti * Dr;
  float zr = Fer - Foi, zi = Fei + For;              // Z = Fe + i*Fo
  #pragma unroll
  for (int s = 0; s < 6; s++) {
    int d = 32 >> s;
    float pr = __shfl_xor(zr, d);
    float pi = __shfl_xor(zi, d);
    float aa = (float)(l & (d - 1)) / (float)d;
    float wr = cospif(aa), wi = sinpif(aa);
    float sr = zr + pr, si = zi + pi;
    float dr = pr - zr, di = pi - zi;
    float mr2 = dr * wr - di * wi;
    float mi2 = dr * wi + di * wr;
    bool hib = (l & d) != 0;
    zr = hib ? mr2 : sr;
    zi = hib ? mi2 : si;
  }
  int m = __brev(l) >> 26;               // lane holds u[m]
  unsigned p0 = b2u(tob(zr * (1.f / 64.f)));
  unsigned p1 = b2u(tob(zi * (1.f / 64.f)));
  ((unsigned*)(out + (size_t)row * W))[m] = p0 | (p1 << 16);
}

// ---- dual 1x1 conv: two independent (in,out,w) jobs, one launch ----
// grid = 2 * B * 256; transposed weights wt[c*wstride + o]; perb: +b*2304
__global__ void __launch_bounds__(256) conv1x1d_k(const bf16* __restrict__ in0, bf16* __restrict__ out0,
                                                  const float* __restrict__ w0,
                                                  const bf16* __restrict__ in1, bf16* __restrict__ out1,
                                                  const float* __restrict__ w1,
                                                  int wstride, int perb) {
  int blk = blockIdx.x;
  int half = blk >> 11;
  int lb = blk & 2047;
  const bf16* in = half ? in1 : in0;
  bf16* out = half ? out1 : out0;
  const float* wt = half ? w1 : w0;
  __shared__ float vs[48 * 64];
  int t = threadIdx.x;
  int b = lb >> 8;
  int p0 = (lb & 255) << 6;
  int ibase = b * 48 * HW + p0;
  #pragma unroll
  for (int i = 0; i < 12; i++) {
    int idx = i * 256 + t;
    int c = idx >> 6, p = idx & 63;
    vs[idx] = ldf(in, ibase + c * HW + p);
  }
  __syncthreads();
  int p = t & 63;
  int og = __builtin_amdgcn_readfirstlane(t >> 6);   // wave-uniform 0..3
  const float* Wcol = wt + (perb ? b * 2304 : 0) + og * 12;
  float acc[12];
  #pragma unroll
  for (int j = 0; j < 12; j++) acc[j] = 0.f;
  for (int c = 0; c < 48; c++) {
    float v = vs[c * 64 + p];
    const float* wc = Wcol + c * wstride;
    #pragma unroll
    for (int j = 0; j < 12; j++) acc[j] += wc[j] * v;
  }
  bf16* op = out + (size_t)b * 48 * HW + p0 + p;
  #pragma unroll
  for (int j = 0; j < 12; j++) op[(size_t)(og * 12 + j) * HW] = tob(acc[j]);
}

// ---- fused x->KV conv v2: 8 waves x 24 outputs, one x staging ----
// wave wid: buf = wid>>1 (HK,HV,LK,LV), 24-ch half = wid&1.
__global__ void __launch_bounds__(512) convxkv_k(const void* __restrict__ in,
                                                 bf16* __restrict__ o0, bf16* __restrict__ o1,
                                                 bf16* __restrict__ o2, bf16* __restrict__ o3,
                                                 const float* __restrict__ P,
                                                 const int* flagp) {
  int bf = flagp[0];
  __shared__ float vs[48 * 64];
  int t = threadIdx.x;
  int blk = blockIdx.x;                // B * 256
  int b = blk >> 8;
  int p0 = (blk & 255) << 6;
  int ibase = b * 48 * HW + p0;
  #pragma unroll
  for (int i = 0; i < 6; i++) {
    int idx = i * 512 + t;             // 3072 = 48*64
    int c = idx >> 6, p = idx & 63;
    vs[idx] = ldx(in, ibase + c * HW + p, bf);
  }
  __syncthreads();
  int p = t & 63;
  int wid = __builtin_amdgcn_readfirstlane(t >> 6);  // wave-uniform 0..7
  int buf = wid >> 1;
  int half24 = (wid & 1) * 24;
  const float* Wcol = P + (buf < 2 ? O_HKVW : O_LKVW) + (buf & 1) * 48 + half24;
  bf16* ob = (buf == 0 ? o0 : buf == 1 ? o1 : buf == 2 ? o2 : o3);
  bf16* op = ob + (size_t)b * 48 * HW + (size_t)half24 * HW + p0 + p;
  float acc[24];
  #pragma unroll
  for (int j = 0; j < 24; j++) acc[j] = 0.f;
  for (int c = 0; c < 48; c++) {
    float v = vs[c * 64 + p];
    const float* wc = Wcol + c * 96;
    #pragma unroll
    for (int j = 0; j < 24; j++) acc[j] += wc[j] * v;
  }
  #pragma unroll
  for (int j = 0; j < 24; j++) op[(size_t)j * HW] = tob(acc[j]);
}

// ---- depthwise 3x3 octet helper v3: halo via lane shuffles, 16B loads only --
// 16 consecutive lanes cover one full 128-px row: left halo = lane l-1's last
// elem (hi of u.w), right halo = lane l+1's first elem (lo of u.x). Row
// boundaries (l&15 == 0 / 15) coincide with zero-pad, masking any value from
// an out-of-group or inactive source lane.
DI void dw_oct(const bf16* __restrict__ p, const float* __restrict__ w,
               int c, int h, int w0, int l, float acc[8]) {
  #pragma unroll
  for (int i = 0; i < 3; i++) {
    int hh = h + i - 1;
    if (hh < 0 || hh >= H) continue;
    const bf16* row = p + hh * W + w0;
    uint4 u = *(const uint4*)row;              // 16B-aligned (w0 % 8 == 0)
    unsigned lw = __shfl(u.w, l - 1);          // left neighbor's last pair
    unsigned rx = __shfl(u.x, l + 1);          // right neighbor's first pair
    float v[10];
    v[1] = u2f((unsigned short)(u.x & 0xFFFF)); v[2] = u2f((unsigned short)(u.x >> 16));
    v[3] = u2f((unsigned short)(u.y & 0xFFFF)); v[4] = u2f((unsigned short)(u.y >> 16));
    v[5] = u2f((unsigned short)(u.z & 0xFFFF)); v[6] = u2f((unsigned short)(u.z >> 16));
    v[7] = u2f((unsigned short)(u.w & 0xFFFF)); v[8] = u2f((unsigned short)(u.w >> 16));
    v[0] = ((l & 15) == 0) ? 0.f : u2f((unsigned short)(lw >> 16));
    v[9] = ((l & 15) == 15) ? 0.f : u2f((unsigned short)(rx & 0xFFFF));
    #pragma unroll
    for (int j = 0; j < 3; j++) {
      float wt = w[c * 9 + i * 3 + j];
      #pragma unroll
      for (int q = 0; q < 8; q++) acc[q] += wt * v[q + j];
    }
  }
}

DI void dw_store8(bf16* __restrict__ out, int idx8, const float acc[8]) {
  uint4 o;
  o.x = (unsigned)b2u(tob(acc[0])) | ((unsigned)b2u(tob(acc[1])) << 16);
  o.y = (unsigned)b2u(tob(acc[2])) | ((unsigned)b2u(tob(acc[3])) << 16);
  o.z = (unsigned)b2u(tob(acc[4])) | ((unsigned)b2u(tob(acc[5])) << 16);
  o.w = (unsigned)b2u(tob(acc[6])) | ((unsigned)b2u(tob(acc[7])) << 16);
  *(uint4*)(out + (size_t)idx8 * 8) = o;
}

// ---- paired depthwise 3x3 v3: 8 px/thread, two plane sets ----
__global__ void dw3x3x2_k(const bf16* __restrict__ in1, bf16* __restrict__ out1,
                          const bf16* __restrict__ in2, bf16* __restrict__ out2,
                          const float* __restrict__ w1, const float* __restrict__ w2) {
  int idx8 = blockIdx.x * 256 + threadIdx.x;   // octet index over NCHW/8
  int l = threadIdx.x & 63;
  int w0 = (idx8 & 15) << 3;                   // W/8 = 16
  int h = (idx8 >> 4) & (H - 1);
  int plane = idx8 >> 11;                      // HW/8 = 2048
  int c = plane % 48;
  float a1[8] = {0,0,0,0,0,0,0,0};
  dw_oct(in1 + (size_t)plane * HW, w1, c, h, w0, l, a1);
  dw_store8(out1, idx8, a1);
  float a2[8] = {0,0,0,0,0,0,0,0};
  dw_oct(in2 + (size_t)plane * HW, w2, c, h, w0, l, a2);
  dw_store8(out2, idx8, a2);
}

// ---- quad depthwise 3x3 v3: 8 px/thread, four plane sets ----
__global__ void dw3x3q_k(const bf16* __restrict__ i1, bf16* __restrict__ u1,
                         const bf16* __restrict__ i2, bf16* __restrict__ u2,
                         const bf16* __restrict__ i3, bf16* __restrict__ u3,
                         const bf16* __restrict__ i4, bf16* __restrict__ u4,
                         const float* __restrict__ w1, const float* __restrict__ w2,
                         const float* __restrict__ w3, const float* __restrict__ w4) {
  int idx8 = blockIdx.x * 256 + threadIdx.x;
  int l = threadIdx.x & 63;
  int w0 = (idx8 & 15) << 3;
  int h = (idx8 >> 4) & (H - 1);
  int plane = idx8 >> 11;
  int c = plane % 48;
  float a[8];
  #pragma unroll
  for (int q = 0; q < 8; q++) a[q] = 0.f;
  dw_oct(i1 + (size_t)plane * HW, w1, c, h, w0, l, a);
  dw_store8(u1, idx8, a);
  #pragma unroll
  for (int q = 0; q < 8; q++) a[q] = 0.f;
  dw_oct(i2 + (size_t)plane * HW, w2, c, h, w0, l, a);
  dw_store8(u2, idx8, a);
  #pragma unroll
  for (int q = 0; q < 8; q++) a[q] = 0.f;
  dw_oct(i3 + (size_t)plane * HW, w3, c, h, w0, l, a);
  dw_store8(u3, idx8, a);
  #pragma unroll
  for (int q = 0; q < 8; q++) a[q] = 0.f;
  dw_oct(i4 + (size_t)plane * HW, w4, c, h, w0, l, a);
  dw_store8(u4, idx8, a);
}

// ---- attn gram v3: MFMA 16x16x32 bf16, no LDS ----
// grid = 2 * 32 bh * 16 splits; 4 waves/block, wave handles L-chunk of 256
// (8 k-steps). Lane l loads row (l&15, clamp 11) 8 bf16 at koff=(l>>4)*8 —
// identical pattern serves as A-frag (Q) and B-frag (K => B holds K^T), so
// G += mfma(fq,fk) = Q.K^T; Nq/Nk diagonals give the norms (transpose-safe).
// C/D layout (verified): col n = l&15, row m = (l>>4)*4 + reg.
__global__ void __launch_bounds__(256) attn_part_k(const bf16* __restrict__ q0,
                                                   const bf16* __restrict__ k0,
                                                   const bf16* __restrict__ q1,
                                                   const bf16* __restrict__ k1,
                                                   float* __restrict__ partial) {
  int blk = blockIdx.x;
  int half = blk >> 9;                  // grid = 2 * 512
  int lb = blk & 511;
  const bf16* q = half ? q1 : q0;
  const bf16* kbuf = half ? k1 : k0;
  float* part = partial + (size_t)half * PARTSZ;
  int bh = lb >> 4;                     // 0..31
  int split = lb & 15;                  // 0..15
  int b = bh >> 2, hd = bh & 3;
  int t = threadIdx.x;
  int wid = t >> 6, l = t & 63;
  int chunk = split * 4 + wid;          // 0..63 (matches finM NCHUNK layout)
  int n = l & 15;
  int row = n < 12 ? n : 11;            // rows 12-15: dup row 11, discarded
  int koff = (l >> 4) * 8;
  size_t rb = (size_t)(b * 48 + hd * 12) * HW + (size_t)row * HW + chunk * 256 + koff;
  const bf16* qb = q + rb;
  const bf16* kb = kbuf + rb;
  f32x4 G = {0.f, 0.f, 0.f, 0.f};
  f32x4 Nq = {0.f, 0.f, 0.f, 0.f};
  f32x4 Nk = {0.f, 0.f, 0.f, 0.f};
  #pragma unroll
  for (int s = 0; s < 8; s++) {
    short8v fq = *(const short8v*)(qb + s * 32);
    short8v fk = *(const short8v*)(kb + s * 32);
    G  = __builtin_amdgcn_mfma_f32_16x16x32_bf16(fq, fk, G, 0, 0, 0);
    Nq = __builtin_amdgcn_mfma_f32_16x16x32_bf16(fq, fq, Nq, 0, 0, 0);
    Nk = __builtin_amdgcn_mfma_f32_16x16x32_bf16(fk, fk, Nk, 0, 0, 0);
  }
  int mb = (l >> 4) * 4;
  float* pp = part + (size_t)(chunk * 32 + bh) * 168;
  if (n < 12 && mb < 12) {
    pp[(mb + 0) * 12 + n] = G[0];
    pp[(mb + 1) * 12 + n] = G[1];
    pp[(mb + 2) * 12 + n] = G[2];
    pp[(mb + 3) * 12 + n] = G[3];
  }
  if (n < 12 && n >= mb && n < mb + 4) {
    int r = n - mb;
    float nq = (r == 0) ? Nq[0] : (r == 1) ? Nq[1] : (r == 2) ? Nq[2] : Nq[3];
    float nk = (r == 0) ? Nk[0] : (r == 1) ? Nk[1] : (r == 2) ? Nk[2] : Nk[3];
    pp[144 + n] = nq;
    pp[156 + n] = nk;
  }
}

// ---- dual: reduce partials + softmax + fused projection matrix ----
// grid = 64: half = blk>>5 (high/low), bh = blk&31.
// M[half][b][dg][o] = sum_c attn_hd[c][d] * PWt[(hd*12+c)*48 + o]
__global__ void __launch_bounds__(256) attn_finM_k(const float* __restrict__ partial,
                                                   const float* __restrict__ P,
                                                   float* __restrict__ M) {
  int blk = blockIdx.x;
  int half = blk >> 5;
  int bh = blk & 31, b = bh >> 2, hd = bh & 3;
  const float* part = partial + (size_t)half * PARTSZ;
  const float* temp = P + (half ? O_LT : O_HT);
  const float* pwt = P + (half ? O_LPW : O_HPW);
  float* Mh = M + (size_t)half * 8 * 2304;
  int t = threadIdx.x;
  __shared__ float red[168];
  __shared__ float sm[144];              // sm[c*12 + d]
  if (t < 168) {
    float s = 0.f;
    for (int ch = 0; ch < NCHUNK; ch++) s += part[(size_t)(ch * 32 + bh) * 168 + t];
    red[t] = s;
  }
  __syncthreads();
  if (t < 12) {
    float tm = temp[hd];
    float rq = 1.f / fmaxf(sqrtf(red[144 + t]), 1e-12f);
    float vals[12], mx = -1e30f;
    #pragma unroll
    for (int d = 0; d < 12; d++) {
      float rk = 1.f / fmaxf(sqrtf(red[156 + d]), 1e-12f);
      vals[d] = red[t * 12 + d] * rq * rk * tm;
      mx = fmaxf(mx, vals[d]);
    }
    float s = 0.f;
    #pragma unroll
    for (int d = 0; d < 12; d++) { vals[d] = expf(vals[d] - mx); s += vals[d]; }
    float inv = 1.f / s;
    #pragma unroll
    for (int d = 0; d < 12; d++) sm[t * 12 + d] = vals[d] * inv;
  }
  __syncthreads();
  for (int e = t; e < 576; e += 256) {   // 12 d-rows x 48 outputs
    int d = e / 48, o = e - d * 48;
    float s = 0.f;
    #pragma unroll
    for (int c = 0; c < 12; c++) s += sm[c * 12 + d] * pwt[(hd * 12 + c) * 48 + o];
    Mh[(size_t)b * 2304 + (hd * 12 + d) * 48 + o] = s;
  }
}

// ---- final v2t: 64 px/block, 4 waves x 12 outputs, transposed weights ----
__global__ void __launch_bounds__(256) conv_final_k(const bf16* __restrict__ ho,
                                                    const bf16* __restrict__ lo,
                                                    const float* __restrict__ P,
                                                    const void* __restrict__ x,
                                                    void* __restrict__ out,
                                                    const int* flagp) {
  int bf = flagp[0];
  __shared__ float vs[96 * 64];
  int t = threadIdx.x;
  int blk = blockIdx.x;                // B * 256
  int b = blk >> 8;
  int p0 = (blk & 255) << 6;
  int pbase = b * 48 * HW + p0;
  #pragma unroll
  for (int i = 0; i < 12; i++) {
    int idx = i * 256 + t;
    int c = idx >> 6, p = idx & 63;
    vs[idx] = ldf(ho, pbase + c * HW + p);
    vs[48 * 64 + idx] = ldf(lo, pbase + c * HW + p);
  }
  __syncthreads();
  int p = t & 63;
  int og = __builtin_amdgcn_readfirstlane(t >> 6);   // wave-uniform 0..3
  const float* Wcol = P + O_FPW + og * 12;           // transposed: [c*48 + j]
  float acc[12];
  #pragma unroll
  for (int j = 0; j < 12; j++) acc[j] = 0.f;
  for (int c = 0; c < 96; c++) {
    float v = vs[c * 64 + p];
    const float* wc = Wcol + c * 48;
    #pragma unroll
    for (int j = 0; j < 12; j++) acc[j] += wc[j] * v;
  }
  #pragma unroll
  for (int j = 0; j < 12; j++) {
    int o = og * 12 + j;
    int oi = pbase + o * HW + p;
    float val = acc[j] + P[O_FPB + o] + ldx(x, oi, bf);
    if (bf) ((bf16*)out)[oi] = tob(val);
    else    ((float*)out)[oi] = val;
  }
}

extern "C" void kernel_launch(void* const* d_in, const int* in_sizes, int n_in,
                              void* d_out, int out_size, void* d_ws, size_t ws_size,
                              hipStream_t stream) {
  const void* x = d_in[0];

  // ws layout (fp32 units): ap@0, flag@7000, params@8192 (ends 47224),
  // wts@48000, Mbuf@50000 (2*8*2304 -> ends 86864),
  // parts@90000 (2*PARTSZ -> ends 778128), bf16 planes P0..P9 @800000
  float* ws    = (float*)d_ws;
  float* ap    = ws;
  int*   flagp = (int*)(ws + 7000);
  float* P     = ws + 8192;
  float* wts   = ws + 48000;
  float* Mbuf  = ws + 50000;
  float* parts = ws + 90000;
  bf16* base = (bf16*)(ws + 800000);
  bf16* P0 = base;                       // hf -> ho
  bf16* P1 = base + (size_t)NCHW;        // lf -> lo
  bf16* P2 = base + (size_t)2 * NCHW;    // spec / HKpre / HQpre
  bf16* P3 = base + (size_t)3 * NCHW;    // spec / HVpre / HQ
  bf16* P4 = base + (size_t)4 * NCHW;    // spec / LKpre / LQpre
  bf16* P5 = base + (size_t)5 * NCHW;    // LVpre / LQ
  bf16* P6 = base + (size_t)6 * NCHW;    // HK
  bf16* P7 = base + (size_t)7 * NCHW;    // HV
  bf16* P8 = base + (size_t)8 * NCHW;    // LK
  bf16* P9 = base + (size_t)9 * NCHW;    // LV
  float* spec = (float*)P2;

  // ---- dtype detect + param convert (matmul weights transposed) ----
  detect_k<<<1, 256, 0, stream>>>(x, flagp);
  ParamTab tab;
  const int offs[25] = {O_FDW, O_BNG, O_BNB, O_BNM, O_BNV,
                        O_FHW1, O_FHB1, O_FHW2, O_FHB2,
                        O_FLW, O_FLB,
                        O_HQW, O_HKVW, O_HQDW, O_HKVDW, O_HPW, O_HT,
                        O_LQW, O_LKVW, O_LQDW, O_LKVDW, O_LPW, O_LT,
                        O_FPW, O_FPB};
  const int cnts[25] = {3456, 72, 72, 72, 72,
                        144, 48, 144, 48,
                        9216, 96,
                        2304, 4608, 432, 864, 2304, 4,
                        2304, 4608, 432, 864, 2304, 4,
                        4608, 48};
  const int rows[25] = {0, 0, 0, 0, 0,
                        0, 0, 0, 0,
                        96, 0,
                        48, 96, 0, 0, 48, 0,
                        48, 96, 0, 0, 48, 0,
                        48, 0};
  for (int i = 0; i < 25; i++) {
    tab.src[i] = d_in[i + 1]; tab.off[i] = offs[i]; tab.cnt[i] = cnts[i]; tab.rows[i] = rows[i];
  }
  cvt_params_k<<<25, 256, 0, stream>>>(tab, flagp, P);

  // ---- fd ----
  reduce_mean_k<<<B * C, 256, 0, stream>>>(x, ap, flagp);
  fd_weights_k<<<B, 128, 0, stream>>>(ap, P, wts);
  fd_apply_k<<<NCHW / 1024, 256, 0, stream>>>(x, wts, P1, P3, flagp); // low->P1, high->P3
  // ---- fmgm_high ----
  fmgm_high_k<<<NCHW / 1024, 256, 0, stream>>>(P3, P, P0);            // hf->P0
  // ---- fmgm_low: rfft2 -> gate -> irfft2 (spec overlays P2..P4) ----
  rfft_row_k<<<B * C * H / 4, 256, 0, stream>>>(P1, spec);
  fft_col_k<<<B * C * 2, 256, 0, stream>>>(spec, -1.f, 1.f);
  freq_gate_k<<<B * (SPECHW / 64), 256, 0, stream>>>(spec, P);
  fft_col_k<<<B * C * 2, 256, 0, stream>>>(spec, 1.f, 1.f / 128.f);
  irfft_row_k<<<B * C * H / 4, 256, 0, stream>>>(spec, P1);           // lf->P1
  // ---- fused x->KV conv (spec dead) + quad depthwise ----
  convxkv_k<<<B * 256, 512, 0, stream>>>(x, P2, P3, P4, P5, P, flagp);
  dw3x3q_k<<<NCHW / 2048, 256, 0, stream>>>(P2, P6, P3, P7, P4, P8, P5, P9,
                                            P + O_HKVDW, P + O_HKVDW + 48 * 9,
                                            P + O_LKVDW, P + O_LKVDW + 48 * 9);
  // ---- both q-paths dual (P2..P5 free after dw3x3q) ----
  conv1x1d_k<<<2 * B * 256, 256, 0, stream>>>(P0, P2, P + O_HQW,
                                              P1, P4, P + O_LQW, 48, 0);
  dw3x3x2_k<<<NCHW / 2048, 256, 0, stream>>>(P2, P3, P4, P5,
                                             P + O_HQDW, P + O_LQDW);
  // ---- attention (both branches in each launch) ----
  attn_part_k<<<2 * 32 * 16, 256, 0, stream>>>(P3, P6, P5, P8, parts);
  attn_finM_k<<<64, 256, 0, stream>>>(parts, P, Mbuf);
  conv1x1d_k<<<2 * B * 256, 256, 0, stream>>>(P7, P0, Mbuf,
                                              P9, P1, Mbuf + 8 * 2304, 48, 1);
  // ---- final 1x1 + bias + residual ----
  conv_final_k<<<B * 256, 256, 0, stream>>>(P0, P1, P, x, d_out, flagp);
}